// Round 4
// baseline (1075.318 us; speedup 1.0000x reference)
//
#include <hip/hip_runtime.h>
#include <cmath>
#include <cstring>
#include <vector>
#include <algorithm>

// ============================================================================
// Spherical CNN (s2conv -> 4x so3conv -> integrate -> MLP), MI355X gfx950.
// Round 4: slab-major streaming GEMM passes for stages 1-2 synthesis:
//   scatter (per-(m,n) GEMM, full K-reuse) -> dftA (alpha iDFT) ->
//   dftB (gamma fold + ReLU + gamma fwd DFT fused) -> dftC (alpha fwd DFT).
// Exact host-built twiddle matrices; coalesced everything; chunked workspace.
// ============================================================================

#define DPI 3.14159265358979323846

static constexpr int OQh(int l) { return l*(4*l*l - 1)/3; }
static_assert(OQh(30) == 35990, "oq30");
static_assert(OQh(17) == 6545,  "oq17");
static_assert(OQh(9)  == 969,   "oq9");
static_assert(OQh(5)  == 165,   "oq5");
static_assert(OQh(3)  == 35,    "oq3");

static constexpr int T1SUM = 18445;   // packed synth terms, stage 1 (BQ=30)
static constexpr int T2SUM = 3417;    // packed synth terms, stage 2 (BQ=17)

// ---------------- workspace layout (bytes) ----------------
static constexpr size_t al256(size_t x){ return (x + 255) & ~(size_t)255; }
static constexpr size_t WS_XF1  = 0;
static constexpr size_t WS_XH1  = WS_XF1  + al256(32ull*60*30*8);
static constexpr size_t WS_KH1  = WS_XH1  + al256(32ull*900*8);
static constexpr size_t WS_YH1T = WS_KH1  + al256(1800ull*8);
static constexpr size_t WS_XH2  = WS_YH1T + al256(35990ull*64*8);
static constexpr size_t WS_KH2  = WS_XH2  + al256(64ull*6545*8);
static constexpr size_t WS_YH2T = WS_KH2  + al256(6545ull*10*8);
static constexpr size_t WS_XH3  = WS_YH2T + al256(6545ull*160*8);
static constexpr size_t WS_KH3  = WS_XH3  + al256(160ull*969*8);
static constexpr size_t WS_YH3T = WS_KH3  + al256(969ull*60*8);
static constexpr size_t WS_XT4  = WS_YH3T + al256(969ull*384*8);
static constexpr size_t WS_XH4  = WS_XT4  + al256(384ull*18*45*8);
static constexpr size_t WS_KH4  = WS_XH4  + al256(384ull*165*8);
static constexpr size_t WS_YH4T = WS_KH4  + al256(165ull*336*8);
static constexpr size_t WS_XT5  = WS_YH4T + al256(165ull*896*8);
static constexpr size_t WS_XH5  = WS_XT5  + al256(896ull*10*15*8);
static constexpr size_t WS_KH5  = WS_XH5  + al256(896ull*35*8);
static constexpr size_t WS_YH5T = WS_KH5  + al256(35ull*1792*8);
static constexpr size_t WS_S5P  = WS_YH5T + al256(35ull*2048*8);
static constexpr size_t WS_XT2  = WS_S5P  + al256(2048ull*6*4);
static constexpr size_t WS_XT3  = WS_XT2  + al256(561ull*3840*8);
static constexpr size_t WS_RX   = WS_XT3  + al256(153ull*5440*8);
static constexpr size_t WS_RY   = WS_RX   + al256(1770ull*960*8);
static constexpr size_t WS_TOTAL= WS_RY   + al256(1728000ull*8);

// ---------------- constant-table offsets ----------------
struct ConstOffs {
  size_t A1, dAT2, dAT3, A4, A5;
  size_t dT1, dT2;
  size_t S3, S4, S5;
  size_t WInt;
  size_t nF;
  size_t Fs2, Fso3;
  size_t Tw60, Tw18, Tw10, Tw6;
  size_t Wn1, Wn2o, Wn4, Wn5;
  size_t Wg1, Wg2, Wg4;
  size_t WA1t, WA2t, WC1, WC2;
  size_t nC;
};
static ConstOffs CO;
static float*  g_devF = nullptr;
static float2* g_devC = nullptr;
static int*    g_devI = nullptr;

// ============================================================================
// Host: symmetric-tridiagonal eigensolver + Wigner-d builder
// ============================================================================
static void tqli(double* d, double* e, int n, double* z) {
  e[n-1] = 0.0;
  for (int l = 0; l < n; l++) {
    int iter = 0;
    int m;
    do {
      for (m = l; m < n-1; m++) {
        double dd = fabs(d[m]) + fabs(d[m+1]);
        if (fabs(e[m]) <= 1e-300 + 1e-14*dd) break;
      }
      if (m != l) {
        if (iter++ == 80) break;
        double g = (d[l+1]-d[l])/(2.0*e[l]);
        double r = hypot(g, 1.0);
        g = d[m]-d[l]+e[l]/(g + (g >= 0.0 ? fabs(r) : -fabs(r)));
        double s = 1.0, c = 1.0, p = 0.0;
        int i;
        r = 1.0;
        for (i = m-1; i >= l; i--) {
          double f = s*e[i], b = c*e[i];
          r = hypot(f, g);
          e[i+1] = r;
          if (r == 0.0) { d[i+1] -= p; e[m] = 0.0; break; }
          s = f/r; c = g/r;
          g = d[i+1]-p;
          r = (d[i]-g)*s + 2.0*c*b;
          p = s*r;
          d[i+1] = g+p;
          g = c*r-b;
          for (int k = 0; k < n; k++) {
            f = z[(size_t)k*n+i+1];
            z[(size_t)k*n+i+1] = s*z[(size_t)k*n+i] + c*f;
            z[(size_t)k*n+i]   = c*z[(size_t)k*n+i] - s*f;
          }
        }
        if (r == 0.0 && i >= l) continue;
        d[l] -= p; e[l] = g; e[m] = 0.0;
      }
    } while (m != l);
  }
}

struct Builder {
  std::vector<std::vector<double>> V, Lam;
  bool useExpm[30];

  Builder() {
    V.resize(30); Lam.resize(30);
    for (int l = 0; l < 30; l++) {
      int n = 2*l+1;
      std::vector<double> d(n, 0.0), e(n, 0.0), z((size_t)n*n, 0.0);
      for (int i = 0; i < n; i++) z[(size_t)i*n+i] = 1.0;
      for (int i = 0; i+1 < n; i++) {
        double m = (double)i - l;
        e[i] = -0.5*sqrt((double)l*(l+1) - m*(m+1.0));
      }
      if (n > 1) tqli(d.data(), e.data(), n, z.data());
      V[l] = std::move(z); Lam[l] = std::move(d);
    }
    std::vector<double> t((size_t)59*59);
    for (int l = 0; l < 30; l++) {
      useExpm[l] = false;
      if (l == 0) continue;
      int n = 2*l+1;
      eigD(l, 0.77, t.data());
      double corner = pow(cos(0.385), 2.0*l);
      double err = fabs(t[0] - corner) + fabs(t[(size_t)(n-1)*n + (n-1)] - corner);
      double s = 0.0;
      for (int c = 0; c < n; c++) s += t[c]*t[c];
      err += fabs(s - 1.0);
      if (!(err < 1e-8)) useExpm[l] = true;
    }
  }

  void eigD(int l, double beta, double* out) {
    int n = 2*l+1;
    const double* Vp = V[l].data();
    const double* lam = Lam[l].data();
    double ck[64], sk[64];
    for (int k = 0; k < n; k++) { ck[k] = cos(beta*lam[k]); sk[k] = sin(beta*lam[k]); }
    for (int a = 0; a < n; a++) {
      const double* va = Vp + (size_t)a*n;
      for (int c = 0; c < n; c++) {
        const double* vc = Vp + (size_t)c*n;
        int r = ((a - c) % 4 + 4) % 4;
        const double* f = (r & 1) ? sk : ck;
        double s = 0.0;
        for (int k = 0; k < n; k++) s += va[k]*vc[k]*f[k];
        out[(size_t)a*n + c] = (r >= 2) ? -s : s;
      }
    }
  }

  void expmD(int l, double beta, double* out) {
    int n = 2*l+1;
    int s = 0; double bl = fabs(beta)*(double)l + 1e-12;
    while (bl > 0.25) { bl *= 0.5; s++; }
    double sc = ldexp(beta, -s);
    std::vector<double> sup(n > 1 ? n-1 : 0);
    for (int i = 0; i+1 < n; i++) {
      double m = (double)i - l;
      sup[i] = 0.5*sqrt((double)l*(l+1) - m*(m+1.0))*sc;
    }
    std::vector<double> term((size_t)n*n, 0.0), acc((size_t)n*n, 0.0), t2((size_t)n*n);
    for (int i = 0; i < n; i++) { term[(size_t)i*n+i] = 1.0; acc[(size_t)i*n+i] = 1.0; }
    for (int k = 1; k <= 16; k++) {
      for (int r = 0; r < n; r++)
        for (int c = 0; c < n; c++) {
          double v = 0.0;
          if (c > 0)   v += term[(size_t)r*n + c-1]*sup[c-1];
          if (c+1 < n) v -= term[(size_t)r*n + c+1]*sup[c];
          t2[(size_t)r*n+c] = v/(double)k;
        }
      term.swap(t2);
      for (size_t i2 = 0; i2 < (size_t)n*n; i2++) acc[i2] += term[i2];
    }
    for (int t = 0; t < s; t++) {
      for (int r = 0; r < n; r++)
        for (int c = 0; c < n; c++) {
          double v = 0.0;
          for (int k = 0; k < n; k++) v += acc[(size_t)r*n+k]*acc[(size_t)k*n+c];
          t2[(size_t)r*n+c] = v;
        }
      acc.swap(t2);
    }
    std::memcpy(out, acc.data(), sizeof(double)*(size_t)n*n);
  }

  void buildD(int l, double beta, double* out) {
    if (useExpm[l]) expmD(l, beta, out); else eigD(l, beta, out);
  }
};

static std::vector<double> quadw_h(int b) {
  std::vector<double> w(2*b);
  for (int j = 0; j < 2*b; j++) {
    double s = 0;
    for (int k = 0; k < b; k++)
      s += sin(DPI*(2*j+1)*(2*k+1)/(4.0*b))/(double)(2*k+1);
    w[j] = (2.0/b)*sin(DPI*(2*j+1)/(4.0*b))*s;
  }
  return w;
}

static void build_all() {
  size_t o = 0;
  CO.A1   = o; o += 60ull*900;
  CO.dAT2 = o; o += (size_t)OQh(17)*60;
  CO.dAT3 = o; o += (size_t)OQh(9)*34;
  CO.A4   = o; o += 18ull*OQh(5);
  CO.A5   = o; o += 10ull*OQh(3);
  CO.dT1  = o; o += (size_t)T1SUM*60;
  CO.dT2  = o; o += (size_t)T2SUM*34;
  CO.S3   = o; o += 18ull*OQh(9);
  CO.S4   = o; o += 10ull*OQh(5);
  CO.S5   = o; o +=  6ull*OQh(3);
  CO.WInt = o; o += 8;
  CO.nF = o;
  size_t c = 0;
  CO.Fs2  = c; c += 6ull*900;
  CO.Fso3 = c; c += 36ull*OQh(17);
  CO.Tw60 = c; c += 60; CO.Tw18 = c; c += 18; CO.Tw10 = c; c += 10; CO.Tw6 = c; c += 6;
  CO.Wn1  = c; c += 30*60; CO.Wn2o = c; c += 17*34;
  CO.Wn4  = c; c += 5*10;  CO.Wn5  = c; c += 3*6;
  CO.Wg1  = c; c += 60*17; CO.Wg2  = c; c += 34*9; CO.Wg4 = c; c += 10*3;
  CO.WA1t = c; c += 59*60;
  CO.WA2t = c; c += 33*34;
  CO.WC1  = c; c += 33*60;
  CO.WC2  = c; c += 17*34;
  CO.nC = c;

  std::vector<float> HF(CO.nF, 0.f);
  std::vector<float> HC(2*CO.nC, 0.f);

  // packed-term prefix offsets
  std::vector<int> HI(1770 + 561);
  { int acc = 0;
    for (int pm = 0; pm < 59; pm++) for (int n = 0; n < 30; n++) {
      int m = pm - 29, am = m < 0 ? -m : m;
      int lm = am > n ? am : n;
      HI[pm*30 + n] = acc; acc += 30 - lm;
    } }
  { int acc = 0;
    for (int pm = 0; pm < 33; pm++) for (int n = 0; n < 17; n++) {
      int m = pm - 16, am = m < 0 ? -m : m;
      int lm = am > n ? am : n;
      HI[1770 + pm*17 + n] = acc; acc += 17 - lm;
    } }

  Builder B;
  auto betas = [](int b){ std::vector<double> v(2*b);
    for (int j = 0; j < 2*b; j++) v[j] = DPI*(2*j+1)/(4.0*b); return v; };
  auto w30 = quadw_h(30), w17 = quadw_h(17), w9 = quadw_h(9), w5 = quadw_h(5), w3 = quadw_h(3);
  std::vector<double> tmp((size_t)59*59);

  // grid betas_of(30): dT1 (synth l<30), dAT2 (analysis l<17), dA1 (l<30, col l)
  { auto bs = betas(30);
    for (int l = 0; l < 30; l++) { int W = 2*l+1;
      for (int j = 0; j < 60; j++) {
        B.buildD(l, bs[j], tmp.data());
        for (int mm = -l; mm <= l; mm++)
          for (int nn = 0; nn <= l; nn++) {
            int am = mm < 0 ? -mm : mm;
            int lmin = am > nn ? am : nn;
            int term = HI[(mm+29)*30 + nn] + (l - lmin);
            HF[CO.dT1 + (size_t)term*60 + j] =
              (float)((2*l+1)*tmp[(size_t)(mm+l)*W + (nn+l)]);
          }
        if (l < 17) {
          for (int rem = 0; rem < W*W; rem++)
            HF[CO.dAT2 + (size_t)(OQh(l)+rem)*60 + j] = (float)(tmp[rem]*w30[j]);
        }
        float* dA1 = HF.data() + CO.A1 + 60ull*l*l + (size_t)j*W;
        for (int mi = 0; mi < W; mi++) dA1[mi] = (float)(tmp[(size_t)mi*W + l]*w30[j]);
      } } }
  // grid betas_of(17): dT2 (synth l<17), dAT3 (analysis l<9)
  { auto bs = betas(17);
    for (int l = 0; l < 17; l++) { int W = 2*l+1;
      for (int j = 0; j < 34; j++) {
        B.buildD(l, bs[j], tmp.data());
        for (int mm = -l; mm <= l; mm++)
          for (int nn = 0; nn <= l; nn++) {
            int am = mm < 0 ? -mm : mm;
            int lmin = am > nn ? am : nn;
            int term = HI[1770 + (mm+16)*17 + nn] + (l - lmin);
            HF[CO.dT2 + (size_t)term*34 + j] =
              (float)((2*l+1)*tmp[(size_t)(mm+l)*W + (nn+l)]);
          }
        if (l < 9) {
          for (int rem = 0; rem < W*W; rem++)
            HF[CO.dAT3 + (size_t)(OQh(l)+rem)*34 + j] = (float)(tmp[rem]*w17[j]);
        } } } }
  // grid betas_of(9): dS3 (old synth), dA4 (old coef)
  { auto bs = betas(9);
    for (int l = 0; l < 9; l++) { int W = 2*l+1;
      for (int j = 0; j < 18; j++) {
        B.buildD(l, bs[j], tmp.data());
        float* dst = HF.data() + CO.S3 + 18ull*OQh(l) + (size_t)j*W*W;
        for (int i2 = 0; i2 < W*W; i2++) dst[i2] = (float)((2*l+1)*tmp[i2]);
        if (l < 5) {
          float* dA = HF.data() + CO.A4 + 18ull*OQh(l) + (size_t)j*W*W;
          for (int i2 = 0; i2 < W*W; i2++) dA[i2] = (float)(tmp[i2]*w9[j]);
        } } } }
  { auto bs = betas(5);
    for (int l = 0; l < 5; l++) { int W = 2*l+1;
      for (int j = 0; j < 10; j++) {
        B.buildD(l, bs[j], tmp.data());
        float* dst = HF.data() + CO.S4 + 10ull*OQh(l) + (size_t)j*W*W;
        for (int i2 = 0; i2 < W*W; i2++) dst[i2] = (float)((2*l+1)*tmp[i2]);
        if (l < 3) {
          float* dA = HF.data() + CO.A5 + 10ull*OQh(l) + (size_t)j*W*W;
          for (int i2 = 0; i2 < W*W; i2++) dA[i2] = (float)(tmp[i2]*w5[j]);
        } } } }
  { auto bs = betas(3);
    for (int l = 0; l < 3; l++) { int W = 2*l+1;
      for (int j = 0; j < 6; j++) {
        B.buildD(l, bs[j], tmp.data());
        float* dst = HF.data() + CO.S5 + 6ull*OQh(l) + (size_t)j*W*W;
        for (int i2 = 0; i2 < W*W; i2++) dst[i2] = (float)((2*l+1)*tmp[i2]);
      } } }
  // beta = pi/16 kernel-FT matrices
  { double beta = DPI/16.0;
    for (int l = 0; l < 30; l++) { int n = 2*l+1;
      B.buildD(l, beta, tmp.data());
      for (int p = 0; p < 6; p++) {
        double al = 2.0*DPI*p/6.0;
        for (int mi = 0; mi < n; mi++) {
          double ph = al*(double)(mi - l);
          double dr = tmp[(size_t)mi*n + l];
          size_t off = CO.Fs2 + 6ull*l*l + (size_t)p*n + mi;
          HC[2*off]   = (float)(dr*cos(ph));
          HC[2*off+1] = (float)(dr*sin(ph));
        } }
      if (l < 17) {
        for (int p = 0; p < 36; p++) {
          double al = 2.0*DPI*(p/6)/6.0, ga = 2.0*DPI*(p%6)/6.0;
          for (int mi = 0; mi < n; mi++)
            for (int ni = 0; ni < n; ni++) {
              double ph = al*(double)(mi - l) + ga*(double)(ni - l);
              double dr = tmp[(size_t)mi*n + ni];
              size_t off = CO.Fso3 + 36ull*OQh(l) + (size_t)p*n*n + (size_t)mi*n + ni;
              HC[2*off]   = (float)(dr*cos(ph));
              HC[2*off+1] = (float)(dr*sin(ph));
            } } } } }
  auto fillTw = [&](size_t ofs, int N){
    for (int t = 0; t < N; t++) {
      HC[2*(ofs+t)]   = (float)cos(2.0*DPI*t/N);
      HC[2*(ofs+t)+1] = (float)sin(2.0*DPI*t/N);
    } };
  fillTw(CO.Tw60, 60); fillTw(CO.Tw18, 18); fillTw(CO.Tw10, 10); fillTw(CO.Tw6, 6);
  auto fillWn = [&](size_t ofs, int BQ, int N){
    for (int n = 0; n < BQ; n++)
      for (int cc2 = 0; cc2 < N; cc2++) {
        double f = (n == 0) ? 1.0 : 2.0;
        HC[2*(ofs + (size_t)n*N + cc2)]   = (float)(f*cos(2.0*DPI*n*cc2/N));
        HC[2*(ofs + (size_t)n*N + cc2)+1] = (float)(f*sin(2.0*DPI*n*cc2/N));
      } };
  auto fillWg = [&](size_t ofs, int N, int KT){
    for (int cc2 = 0; cc2 < N; cc2++)
      for (int k = 0; k < KT; k++) {
        HC[2*(ofs + (size_t)cc2*KT + k)]   = (float)cos(2.0*DPI*k*cc2/N);
        HC[2*(ofs + (size_t)cc2*KT + k)+1] = (float)(-sin(2.0*DPI*k*cc2/N));
      } };
  fillWn(CO.Wn1, 30, 60); fillWn(CO.Wn2o, 17, 34);
  fillWn(CO.Wn4, 5, 10);  fillWn(CO.Wn5, 3, 6);
  fillWg(CO.Wg1, 60, 17); fillWg(CO.Wg2, 34, 9); fillWg(CO.Wg4, 10, 3);
  // alpha-iDFT matrices, [pm][a] layout (transposed for contiguous a)
  for (int pm = 0; pm < 59; pm++)
    for (int a = 0; a < 60; a++) {
      double th = 2.0*DPI*a*(pm-29)/60.0;
      HC[2*(CO.WA1t + (size_t)pm*60 + a)]   = (float)cos(th);
      HC[2*(CO.WA1t + (size_t)pm*60 + a)+1] = (float)sin(th);
    }
  for (int pm = 0; pm < 33; pm++)
    for (int a = 0; a < 34; a++) {
      double th = 2.0*DPI*a*(pm-16)/34.0;
      HC[2*(CO.WA2t + (size_t)pm*34 + a)]   = (float)cos(th);
      HC[2*(CO.WA2t + (size_t)pm*34 + a)+1] = (float)sin(th);
    }
  // alpha fwd-DFT matrices, [p][a] (kernel conj-multiplies)
  for (int p = 0; p < 33; p++)
    for (int a = 0; a < 60; a++) {
      double th = 2.0*DPI*(p-16)*a/60.0;
      HC[2*(CO.WC1 + (size_t)p*60 + a)]   = (float)cos(th);
      HC[2*(CO.WC1 + (size_t)p*60 + a)+1] = (float)sin(th);
    }
  for (int p = 0; p < 17; p++)
    for (int a = 0; a < 34; a++) {
      double th = 2.0*DPI*(p-8)*a/34.0;
      HC[2*(CO.WC2 + (size_t)p*34 + a)]   = (float)cos(th);
      HC[2*(CO.WC2 + (size_t)p*34 + a)+1] = (float)sin(th);
    }
  for (int j = 0; j < 6; j++) HF[CO.WInt + j] = (float)(w3[j]/36.0);

  size_t fb  = CO.nF * sizeof(float);
  size_t fbA = al256(fb);
  size_t cb  = CO.nC * sizeof(float2);
  size_t cbA = al256(cb);
  size_t ib  = HI.size() * sizeof(int);
  void* base = nullptr;
  if (hipMalloc(&base, fbA + cbA + ib) != hipSuccess || !base) return;
  if (hipMemcpy(base, HF.data(), fb, hipMemcpyHostToDevice) != hipSuccess) return;
  if (hipMemcpy((char*)base + fbA, HC.data(), cb, hipMemcpyHostToDevice) != hipSuccess) return;
  if (hipMemcpy((char*)base + fbA + cbA, HI.data(), ib, hipMemcpyHostToDevice) != hipSuccess) return;
  (void)hipDeviceSynchronize();
  g_devF = (float*)base;
  g_devC = (float2*)((char*)base + fbA);
  g_devI = (int*)((char*)base + fbA + cbA);
}
namespace { struct InitOnce { InitOnce(){ build_all(); } } g_once; }

// ============================================================================
// Device helpers
// ============================================================================
__device__ __forceinline__ int OQ(int l) { return l*(4*l*l - 1)/3; }
__device__ __forceinline__ int lFromQ(int q, int L) {
  int l = 0;
  while (l+1 < L && OQ(l+1) <= q) l++;
  return l;
}
__device__ __forceinline__ int lsq(int q) {
  int l = (int)sqrtf((float)q);
  while ((l+1)*(l+1) <= q) l++;
  while (l*l > q) l--;
  return l;
}
__device__ __forceinline__ void rotf(float2& r, float2 s) {
  float t = r.x*s.x - r.y*s.y;
  r.y = r.x*s.y + r.y*s.x;
  r.x = t;
}

// ---------------- kernel FT: s2 ----------------
__global__ __launch_bounds__(256) void k_kh_s2(
    const float* __restrict__ ks2, const float2* __restrict__ F, float2* __restrict__ kh)
{
  int id = blockIdx.x*blockDim.x + threadIdx.x;
  if (id >= 1800) return;
  int q = id >> 1, o = id & 1;
  int l = lsq(q); int W = 2*l+1; int mi = q - l*l;
  const float2* Fb = F + 6ull*l*l;
  float ax = 0.f, ay = 0.f;
  for (int p = 0; p < 6; p++) {
    float kv = ks2[o*6 + p];
    float2 f = Fb[p*W + mi];
    ax += kv*f.x; ay += kv*f.y;
  }
  kh[(size_t)q*2 + o] = make_float2(ax, ay);
}

// ---------------- kernel FT: so3 ----------------
__global__ __launch_bounds__(256) void k_kh_so3(
    const float* __restrict__ kk, const float2* __restrict__ F,
    float2* __restrict__ kh, int L, int fi, int fo)
{
  int id = blockIdx.x*blockDim.x + threadIdx.x;
  int ff = fi*fo;
  if (id >= OQ(L)*ff) return;
  int q = id / ff, r = id - q*ff;
  int i = r / fo, o = r - i*fo;
  int l = lFromQ(q, L); int W = 2*l+1; int W21 = W*W;
  int rem = q - OQ(l);
  const float2* Fb = F + 36ull*OQ(l) + rem;
  const float* kb = kk + (size_t)(i*fo + o)*36;
  float ax = 0.f, ay = 0.f;
  for (int p = 0; p < 36; p++) {
    float kv = kb[p];
    float2 f = Fb[(size_t)p*W21];
    ax += kv*f.x; ay += kv*f.y;
  }
  kh[(size_t)q*ff + r] = make_float2(ax, ay);
}

// ---------------- stage-1 analysis: alpha DFT ----------------
__global__ __launch_bounds__(64) void k_s1_fftA(
    const float* __restrict__ x, const float2* __restrict__ tw, float2* __restrict__ XF1)
{
  __shared__ float row[60];
  int b = blockIdx.x / 60, j = blockIdx.x - b*60;
  int t = threadIdx.x;
  if (t < 60) row[t] = x[((size_t)b*60 + j)*60 + t];
  __syncthreads();
  if (t < 30) {
    float ax = 0.f, ay = 0.f;
    int ti = 0;
    for (int a = 0; a < 60; a++) {
      float2 w = tw[ti];
      ax += row[a]*w.x; ay -= row[a]*w.y;
      ti += t; if (ti >= 60) ti -= 60;
    }
    XF1[((size_t)b*60 + j)*30 + t] = make_float2(ax, ay);
  }
}

// ---------------- stage-1 beta contraction ----------------
__global__ __launch_bounds__(256) void k_s1_coef(
    const float2* __restrict__ XF1, const float* __restrict__ dA1, float2* __restrict__ xh1)
{
  int id = blockIdx.x*blockDim.x + threadIdx.x;
  if (id >= 32*900) return;
  int b = id / 900, q = id - b*900;
  int l = lsq(q); int W = 2*l+1; int mi = q - l*l; int m = mi - l;
  const float* dp = dA1 + 60ull*l*l + mi;
  const float2* xb = XF1 + (size_t)b*60*30;
  int ma = m >= 0 ? m : -m;
  float sg = m >= 0 ? 1.f : -1.f;
  float ax = 0.f, ay = 0.f;
  for (int j = 0; j < 60; j++) {
    float2 xf = xb[j*30 + ma];
    float d = dp[(size_t)j*W];
    ax += d*xf.x; ay += sg*d*xf.y;
  }
  xh1[id] = make_float2(ax, ay);
}

// ---------------- stage-1 spectral product -> transposed yh ----------------
__global__ __launch_bounds__(256) void k_s1_yh_t(
    const float2* __restrict__ xh1, const float2* __restrict__ kh1, float2* __restrict__ yht)
{
  int id = blockIdx.x*256 + threadIdx.x;
  if (id >= 35990*64) return;
  int q = id >> 6, bo = id & 63;
  int b = bo >> 1, o = bo & 1;
  int l = lFromQ(q, 30); int W = 2*l+1;
  int rem = q - OQ(l); int mi = rem / W, ni = rem - mi*W;
  float2 xv = xh1[(size_t)b*900 + l*l + mi];
  float2 kv = kh1[(size_t)(l*l + ni)*2 + o];
  yht[id] = make_float2(xv.x*kv.x + xv.y*kv.y, xv.y*kv.x - xv.x*kv.y);
}

// ---------------- generic spectral product -> transposed yh ----------------
__global__ __launch_bounds__(256) void k_yh_t(
    const float2* __restrict__ xh, const float2* __restrict__ kh,
    float2* __restrict__ yht, int L, int fi, int fo, int Qtot)
{
  int id = blockIdx.x*256 + threadIdx.x;
  int BOF = 32*fo;
  if (id >= Qtot*BOF) return;
  int q = id / BOF, bo = id - q*BOF;
  int b = bo / fo, o = bo - b*fo;
  int l = lFromQ(q, L); int W = 2*l+1;
  int rem = q - OQ(l); int mi = rem / W, ni = rem - mi*W;
  int ff = fi*fo;
  const float2* xb = xh + ((size_t)b*fi)*Qtot + OQ(l) + mi*W;
  const float2* kb = kh + ((size_t)(OQ(l) + ni*W))*ff + o;
  float ax = 0.f, ay = 0.f;
  for (int i = 0; i < fi; i++) {
    const float2* xrow = xb + (size_t)i*Qtot;
    const float2* krow = kb + (size_t)i*fo;
    for (int k = 0; k < W; k++) {
      float2 xv = xrow[k];
      float2 kv = krow[(size_t)k*ff];
      ax += xv.x*kv.x + xv.y*kv.y;
      ay += xv.y*kv.x - xv.x*kv.y;
    }
  }
  yht[id] = make_float2(ax, ay);
}

// ---------------- transposed-layout beta contraction (stages 2,3) ----------
template<int L, int NJ, int KT, int TPB>
__global__ __launch_bounds__(TPB) void k_coef_t(
    const float2* __restrict__ xtN, const float* __restrict__ dAT,
    float2* __restrict__ xh, int Qtot, int nbi, int SLfull)
{
  int id = blockIdx.x*TPB + threadIdx.x;
  if (id >= nbi*Qtot) return;
  int bi = id / Qtot, q = id - bi*Qtot;
  int l = lFromQ(q, L); int W = 2*l+1;
  int rem = q - OQ(l); int mi = rem / W, ki = rem - mi*W;
  int m = mi - l, ks = ki - l;
  int pidx; float sgn;
  if (ks >= 0) { pidx = (m + (KT-1))*KT + ks;  sgn =  1.f; }
  else         { pidx = (-m + (KT-1))*KT - ks; sgn = -1.f; }
  const float2* xb = xtN + (size_t)pidx*SLfull + (size_t)bi*NJ;
  const float* dp = dAT + (size_t)q*NJ;
  float ax = 0.f, ay = 0.f;
  #pragma unroll 4
  for (int j = 0; j < NJ; j += 2) {
    float2 d2 = *(const float2*)&dp[j];
    float2 xa = xb[j], xc = xb[j+1];
    ax += d2.x*xa.x + d2.y*xc.x;
    ay += d2.x*xa.y + d2.y*xc.y;
  }
  xh[id] = make_float2(ax, sgn*ay);
}

// ---------------- old-layout beta contraction (stages 4,5) -----------------
__global__ __launch_bounds__(256) void k_coef(
    const float2* __restrict__ xt, const float* __restrict__ dA,
    float2* __restrict__ xh, int L, int nj, int KT, int MT, int Qtot, int nbi)
{
  int id = blockIdx.x*blockDim.x + threadIdx.x;
  if (id >= nbi*Qtot) return;
  int bi = id / Qtot, q = id - bi*Qtot;
  int l = lFromQ(q, L); int W = 2*l+1; int W21 = W*W;
  int rem = q - OQ(l); int mi = rem / W, ki = rem - mi*W;
  int m = mi - l, ks = ki - l;
  const float* dAp = dA + (size_t)nj*OQ(l) + rem;
  int MTKT = MT*KT;
  int pidx; float sgn;
  if (ks >= 0) { pidx = (m + (KT-1))*KT + ks;  sgn =  1.f; }
  else         { pidx = (-m + (KT-1))*KT - ks; sgn = -1.f; }
  const float2* xb = xt + (size_t)bi*nj*MTKT + pidx;
  float ax = 0.f, ay = 0.f;
  for (int j = 0; j < nj; j++) {
    float2 xv = xb[(size_t)j*MTKT];
    float d = dAp[(size_t)j*W21];
    ax += d*xv.x; ay += sgn*d*xv.y;
  }
  xh[id] = make_float2(ax, ay);
}

// ============================================================================
// GEMM-pass synthesis (stages 1-2), slab-major layouts (sl fastest).
// ============================================================================

// scatter: P[mn][slhat] = sum_k yht[q(k)][boLo+bo] * dT[toff[mn]+k][j]
template<int BQ, int NJ, int BOC, int TPB>
__global__ __launch_bounds__(TPB) void k_scat(
    const float2* __restrict__ yht, const float* __restrict__ dT,
    const int* __restrict__ toff, float2* __restrict__ P,
    int boLo, int BO)
{
  constexpr int CH = BOC*NJ;
  __shared__ float2 Ys[BQ*BOC];
  __shared__ float  Ds[BQ*NJ];
  const int mn = blockIdx.x;
  const int pm = mn / BQ, n = mn - pm*BQ;
  const int m = pm - (BQ-1);
  const int am = m < 0 ? -m : m;
  const int lmin = am > n ? am : n;
  const int K = BQ - lmin;
  const int tof = toff[mn];
  for (int idx = threadIdx.x; idx < K*BOC; idx += TPB) {
    int kk = idx / BOC, bo = idx - kk*BOC;
    int l = lmin + kk;
    int q = OQ(l) + (m+l)*(2*l+1) + (n+l);
    Ys[idx] = yht[(size_t)q*BO + boLo + bo];
  }
  for (int idx = threadIdx.x; idx < K*NJ; idx += TPB)
    Ds[idx] = dT[(size_t)tof*NJ + idx];
  __syncthreads();
  float2* Pb = P + (size_t)mn*CH;
  for (int o = threadIdx.x; o < CH; o += TPB) {
    int bo = o / NJ, j = o - bo*NJ;
    float ax = 0.f, ay = 0.f;
    for (int kk = 0; kk < K; kk++) {
      float2 y = Ys[kk*BOC + bo];
      float d = Ds[kk*NJ + j];
      ax = fmaf(d, y.x, ax); ay = fmaf(d, y.y, ay);
    }
    Pb[o] = make_float2(ax, ay);
  }
}

// dftA: Tm[a][n][sl] = sum_pm WA[a][pm] * P[pm][n][sl]     (alpha iDFT)
template<int NPM, int NN, int AROWS, int NAH, int NAT, int CHSL, int TPB>
__global__ __launch_bounds__(TPB) void k_dftA(
    const float2* __restrict__ P, const float2* __restrict__ WA,
    float2* __restrict__ Tm)
{
  constexpr int SLT = (CHSL + TPB - 1)/TPB;
  __shared__ float2 Wl[NPM*AROWS];
  int b = blockIdx.x;
  int t = b % SLT; int rest = b / SLT;
  int ah = rest % NAH; int n = rest / NAH;
  int aBase = ah*AROWS;
  for (int i = threadIdx.x; i < NPM*AROWS; i += TPB) {
    int pm = i / AROWS, al = i - pm*AROWS;
    Wl[i] = WA[(size_t)pm*NAT + aBase + al];
  }
  __syncthreads();
  int sl = t*TPB + threadIdx.x;
  if (sl >= CHSL) return;
  float2 acc[AROWS];
  #pragma unroll
  for (int a = 0; a < AROWS; a++) acc[a] = make_float2(0.f, 0.f);
  for (int pm = 0; pm < NPM; pm++) {
    float2 p = P[((size_t)pm*NN + n)*CHSL + sl];
    const float2* wr = &Wl[pm*AROWS];
    #pragma unroll
    for (int a = 0; a < AROWS; a++) {
      float2 w = wr[a];
      acc[a].x = fmaf(p.x, w.x, fmaf(-p.y, w.y, acc[a].x));
      acc[a].y = fmaf(p.x, w.y, fmaf( p.y, w.x, acc[a].y));
    }
  }
  #pragma unroll
  for (int a = 0; a < AROWS; a++)
    Tm[((size_t)(aBase + a)*NN + n)*CHSL + sl] = acc[a];
}

// dftB: S = Re(Tm . Wn) (Hermitian gamma fold), ReLU, U = S . Wg (gamma DFT)
template<int NN, int NC, int KT, int CHSL, int TPB>
__global__ __launch_bounds__(TPB) void k_dftB(
    const float2* __restrict__ Tm, const float2* __restrict__ Wn,
    const float2* __restrict__ Wg, float2* __restrict__ U)
{
  constexpr int SLT = (CHSL + TPB - 1)/TPB;
  __shared__ float2 WnL[NN*NC];
  __shared__ float2 WgT[KT*NC];
  int b = blockIdx.x;
  int t = b % SLT; int a = b / SLT;
  for (int i = threadIdx.x; i < NN*NC; i += TPB) WnL[i] = Wn[i];
  for (int i = threadIdx.x; i < KT*NC; i += TPB) {
    int k = i / NC, c = i - k*NC;
    WgT[i] = Wg[(size_t)c*KT + k];
  }
  __syncthreads();
  int sl = t*TPB + threadIdx.x;
  if (sl >= CHSL) return;
  float S[NC];
  #pragma unroll
  for (int c = 0; c < NC; c++) S[c] = 0.f;
  for (int n = 0; n < NN; n++) {
    float2 tv = Tm[((size_t)a*NN + n)*CHSL + sl];
    const float2* wr = &WnL[n*NC];
    #pragma unroll
    for (int c = 0; c < NC; c++)
      S[c] = fmaf(tv.x, wr[c].x, fmaf(-tv.y, wr[c].y, S[c]));
  }
  #pragma unroll
  for (int c = 0; c < NC; c++) S[c] = fmaxf(S[c], 0.f);
  for (int k = 0; k < KT; k++) {
    const float2* wr = &WgT[k*NC];
    float ux = 0.f, uy = 0.f;
    #pragma unroll
    for (int c = 0; c < NC; c++) {
      ux = fmaf(S[c], wr[c].x, ux);
      uy = fmaf(S[c], wr[c].y, uy);
    }
    U[((size_t)a*KT + k)*CHSL + sl] = make_float2(ux, uy);
  }
}

// dftC: xt[p][k][slfull] = sum_a U[a][k][sl] * conj(WC[p][a])   (alpha DFT)
template<int MT, int KT, int NA, int CHSL, int TPB>
__global__ __launch_bounds__(TPB) void k_dftC(
    const float2* __restrict__ U, const float2* __restrict__ WC,
    float2* __restrict__ xt, int slOff, int SLfull)
{
  constexpr int SLT = (CHSL + TPB - 1)/TPB;
  __shared__ float2 WcT[NA*MT];
  int b = blockIdx.x;
  int t = b % SLT; int k = b / SLT;
  for (int i = threadIdx.x; i < NA*MT; i += TPB) {
    int aa = i / MT, p = i - aa*MT;
    WcT[i] = WC[(size_t)p*NA + aa];
  }
  __syncthreads();
  int sl = t*TPB + threadIdx.x;
  if (sl >= CHSL) return;
  float2 acc[MT];
  #pragma unroll
  for (int p = 0; p < MT; p++) acc[p] = make_float2(0.f, 0.f);
  for (int aa = 0; aa < NA; aa++) {
    float2 u = U[((size_t)aa*KT + k)*CHSL + sl];
    const float2* wr = &WcT[aa*MT];
    #pragma unroll
    for (int p = 0; p < MT; p++) {
      float2 w = wr[p];
      acc[p].x = fmaf(u.x, w.x, fmaf( u.y, w.y, acc[p].x));
      acc[p].y = fmaf(u.y, w.x, fmaf(-u.x, w.y, acc[p].y));
    }
  }
  #pragma unroll
  for (int p = 0; p < MT; p++)
    xt[((size_t)(p*KT + k))*SLfull + slOff + sl] = acc[p];
}

// ============================================================================
// Old fused synthesis (stages 3-5; tiny FLOP). yh read is transposed [e][bo].
// ============================================================================
template<int BQ, int N, int KT, int MT, int TPB, int BO>
__global__ __launch_bounds__(TPB) void k_synth3(
    const float2* __restrict__ yh, const float* __restrict__ dS,
    const float2* __restrict__ twN, float2* __restrict__ xt)
{
  constexpr int W2  = 2*BQ - 1;
  constexpr int NH  = N/2;
  constexpr int CP  = (BQ+3) & ~3;
  constexpr int KTP = (KT+1) & ~1;
  constexpr int R3  = (N%4 == 0) ? 4 : 2;
  constexpr int RP  = (NH%2 == 0) ? 2 : 1;
  constexpr int SZA0 = (W2*CP*8 > 2*N*NH*4) ? W2*CP*8 : 2*N*NH*4;
  constexpr int SZA  = (SZA0 + 15) & ~15;
  constexpr int SZB0 = (N*CP*8 > 2*NH*KTP*8) ? N*CP*8 : 2*NH*KTP*8;
  constexpr int SZB  = (SZB0 + 15) & ~15;
  __shared__ __align__(16) char smem[SZA + SZB + N*8];
  float2* P   = (float2*)smem;
  float*  SS  = (float*)smem;
  float*  SD  = SS + N*NH;
  float2* Tm  = (float2*)(smem + SZA);
  float2* USS = (float2*)(smem + SZA);
  float2* USD = USS + NH*KTP;
  float2* twl = (float2*)(smem + SZA + SZB);

  const int tid = threadIdx.x;
  int nwg = gridDim.x, bidx = blockIdx.x;
  int per = nwg >> 3;
  int swz = (bidx & 7)*per + (bidx >> 3);
  int bo = swz / N, j = swz - bo*N;

  for (int t = tid; t < N; t += TPB) twl[t] = twN[t];

  for (int idx = tid; idx < W2*CP; idx += TPB) {
    int pm = idx / CP, n = idx - pm*CP;
    float ax = 0.f, ay = 0.f;
    if (n < BQ) {
      int m = pm - (BQ-1);
      int am = m < 0 ? -m : m;
      int lmin = am > n ? am : n;
      int base = lmin*(4*lmin*lmin - 1)/3;
      for (int l = lmin; l < BQ; l++) {
        int Wl = 2*l+1;
        int e = base + (m+l)*Wl + (n+l);
        float2 y = yh[(size_t)e*BO + bo];
        float d = dS[(size_t)N*base + (size_t)j*Wl*Wl + (m+l)*Wl + (n+l)];
        ax += d*y.x; ay += d*y.y;
        base += Wl*Wl;
      }
    }
    P[idx] = make_float2(ax, ay);
  }
  __syncthreads();

  {
    constexpr int CG = CP/4;
    constexpr float SGN = ((BQ-1) & 1) ? -1.f : 1.f;
    const float4* P4 = (const float4*)P;
    for (int it = tid; it < NH*CG; it += TPB) {
      int a = it / CG, cg = it - a*CG;
      float2 s2 = twl[2*a];
      float2 r = make_float2(1.f, 0.f);
      float4 E0 = {0,0,0,0}, E1 = {0,0,0,0}, O0 = {0,0,0,0}, O1 = {0,0,0,0};
      for (int jj = 0; jj < BQ-1; jj++) {
        float4 e0 = P4[(2*jj)*(CP/2) + 2*cg];
        float4 e1 = P4[(2*jj)*(CP/2) + 2*cg + 1];
        float4 o0 = P4[(2*jj+1)*(CP/2) + 2*cg];
        float4 o1 = P4[(2*jj+1)*(CP/2) + 2*cg + 1];
        E0.x += e0.x*r.x - e0.y*r.y; E0.y += e0.x*r.y + e0.y*r.x;
        E0.z += e0.z*r.x - e0.w*r.y; E0.w += e0.z*r.y + e0.w*r.x;
        E1.x += e1.x*r.x - e1.y*r.y; E1.y += e1.x*r.y + e1.y*r.x;
        E1.z += e1.z*r.x - e1.w*r.y; E1.w += e1.z*r.y + e1.w*r.x;
        O0.x += o0.x*r.x - o0.y*r.y; O0.y += o0.x*r.y + o0.y*r.x;
        O0.z += o0.z*r.x - o0.w*r.y; O0.w += o0.z*r.y + o0.w*r.x;
        O1.x += o1.x*r.x - o1.y*r.y; O1.y += o1.x*r.y + o1.y*r.x;
        O1.z += o1.z*r.x - o1.w*r.y; O1.w += o1.z*r.y + o1.w*r.x;
        rotf(r, s2);
      }
      {
        float4 e0 = P4[(2*(BQ-1))*(CP/2) + 2*cg];
        float4 e1 = P4[(2*(BQ-1))*(CP/2) + 2*cg + 1];
        E0.x += e0.x*r.x - e0.y*r.y; E0.y += e0.x*r.y + e0.y*r.x;
        E0.z += e0.z*r.x - e0.w*r.y; E0.w += e0.z*r.y + e0.w*r.x;
        E1.x += e1.x*r.x - e1.y*r.y; E1.y += e1.x*r.y + e1.y*r.x;
        E1.z += e1.z*r.x - e1.w*r.y; E1.w += e1.z*r.y + e1.w*r.x;
      }
      float2 wa = twl[a];
      int pidx = (N - (a*(BQ-1)) % N) % N;
      float2 ph = twl[pidx];
      int c0 = 4*cg;
      auto doCol = [&](float ex, float ey, float ox, float oy, int col) {
        float gx = ox*wa.x - oy*wa.y, gy = ox*wa.y + oy*wa.x;
        float px = ex + gx, py = ey + gy;
        float qx = ex - gx, qy = ey - gy;
        Tm[a*CP + col]        = make_float2(px*ph.x - py*ph.y, px*ph.y + py*ph.x);
        Tm[(a+NH)*CP + col]   = make_float2(SGN*(qx*ph.x - qy*ph.y), SGN*(qx*ph.y + qy*ph.x));
      };
      doCol(E0.x, E0.y, O0.x, O0.y, c0+0);
      doCol(E0.z, E0.w, O0.z, O0.w, c0+1);
      doCol(E1.x, E1.y, O1.x, O1.y, c0+2);
      doCol(E1.z, E1.w, O1.z, O1.w, c0+3);
    }
  }
  __syncthreads();

  {
    constexpr int NO3 = BQ/2;
    constexpr int NRG = N/R3;
    for (int it = tid; it < NRG*NH; it += TPB) {
      int rg = it / NH, c = it - rg*NH;
      int a0 = rg*R3;
      float2 se = twl[2*c];
      float2 re = make_float2(1.f, 0.f);
      float2 ro = twl[c];
      float er[R3], orr[R3];
      #pragma unroll
      for (int rr = 0; rr < R3; rr++) { er[rr] = 0.f; orr[rr] = 0.f; }
      for (int jj = 0; jj < NO3; jj++) {
        #pragma unroll
        for (int rr = 0; rr < R3; rr++) {
          float4 tv = *(const float4*)&Tm[(a0+rr)*CP + 2*jj];
          er[rr]  += tv.x*re.x - tv.y*re.y;
          orr[rr] += tv.z*ro.x - tv.w*ro.y;
        }
        rotf(re, se); rotf(ro, se);
      }
      if constexpr ((BQ & 1) != 0) {
        #pragma unroll
        for (int rr = 0; rr < R3; rr++) {
          float2 tv = Tm[(a0+rr)*CP + (BQ-1)];
          er[rr] += tv.x*re.x - tv.y*re.y;
        }
      }
      #pragma unroll
      for (int rr = 0; rr < R3; rr++) {
        float t0x = Tm[(a0+rr)*CP].x;
        float s0 = fmaxf(2.f*(er[rr] + orr[rr]) - t0x, 0.f);
        float s1 = fmaxf(2.f*(er[rr] - orr[rr]) - t0x, 0.f);
        SS[(a0+rr)*NH + c] = s0 + s1;
        SD[(a0+rr)*NH + c] = s0 - s1;
      }
    }
  }
  __syncthreads();

  {
    for (int it = tid; it < (NH/RP)*KT; it += TPB) {
      int g = it / KT, k = it - g*KT;
      int a0 = g*RP;
      const float* Sp = (k & 1) ? SD : SS;
      float2 st = twl[k]; st.y = -st.y;
      float2 r = make_float2(1.f, 0.f);
      float ux[2*RP], uy[2*RP];
      #pragma unroll
      for (int q2 = 0; q2 < 2*RP; q2++) { ux[q2] = 0.f; uy[q2] = 0.f; }
      for (int c = 0; c < NH; c++) {
        #pragma unroll
        for (int pp = 0; pp < RP; pp++) {
          float sl = Sp[(a0+pp)*NH + c];
          float sh = Sp[(a0+pp+NH)*NH + c];
          ux[2*pp]   += sl*r.x; uy[2*pp]   += sl*r.y;
          ux[2*pp+1] += sh*r.x; uy[2*pp+1] += sh*r.y;
        }
        rotf(r, st);
      }
      #pragma unroll
      for (int pp = 0; pp < RP; pp++) {
        USS[(a0+pp)*KTP + k] = make_float2(ux[2*pp] + ux[2*pp+1], uy[2*pp] + uy[2*pp+1]);
        USD[(a0+pp)*KTP + k] = make_float2(ux[2*pp] - ux[2*pp+1], uy[2*pp] - uy[2*pp+1]);
      }
    }
  }
  __syncthreads();

  {
    float2* xtb = xt + ((size_t)bo*N + j)*(MT*KT);
    constexpr int KG = KTP/2;
    for (int it = tid; it < MT*KG; it += TPB) {
      int pm2 = it / KG, kg = it - pm2*KG;
      int m = pm2 - (KT-1);
      int mm = m < 0 ? m + N : m;
      const float2* Up = (m & 1) ? USD : USS;
      float2 st = twl[mm];
      float2 r = make_float2(1.f, 0.f);
      float a0x = 0.f, a0y = 0.f, a1x = 0.f, a1y = 0.f;
      for (int a = 0; a < NH; a++) {
        float4 u = *(const float4*)&Up[a*KTP + 2*kg];
        a0x += u.x*r.x + u.y*r.y;  a0y += u.y*r.x - u.x*r.y;
        a1x += u.z*r.x + u.w*r.y;  a1y += u.w*r.x - u.z*r.y;
        rotf(r, st);
      }
      int k0 = 2*kg;
      xtb[pm2*KT + k0] = make_float2(a0x, a0y);
      if (k0 + 1 < KT) xtb[pm2*KT + k0 + 1] = make_float2(a1x, a1y);
    }
  }
}

template<int BQ, int N, int KT, int MT, int INTEG, int NPAIR, int TPB, int BO>
__global__ __launch_bounds__(TPB) void k_synth2(
    const float2* __restrict__ yh, const float* __restrict__ dS,
    const float2* __restrict__ twN, const float2* __restrict__ Wn2,
    const float2* __restrict__ Wg, float2* __restrict__ xt,
    float* __restrict__ s5p, const float* __restrict__ wInt)
{
  constexpr int W2 = 2*BQ - 1;
  constexpr int SZA = (((W2*BQ*8 > N*N*4) ? W2*BQ*8 : N*N*4) + 15) & ~15;
  constexpr int SZB0 = (N*BQ*8 > N*KT*8) ? N*BQ*8 : N*KT*8;
  constexpr int SZB1 = (SZB0 > TPB*4) ? SZB0 : TPB*4;
  constexpr int SZB = (SZB1 + 15) & ~15;
  __shared__ __align__(16) char smem[SZA + SZB + N*8];
  float2* P   = (float2*)smem;
  float*  S   = (float*)smem;
  float2* Tm  = (float2*)(smem + SZA);
  float2* U   = (float2*)(smem + SZA);
  float*  red = (float*)(smem + SZA);
  float2* twl = (float2*)(smem + SZA + SZB);

  const int tid = threadIdx.x;
  int bidx = blockIdx.x, nwg = gridDim.x;
  int per = nwg >> 3;
  int swz = (bidx & 7)*per + (bidx >> 3);
  int bo = swz / N, j = swz - bo*N;

  for (int t = tid; t < N; t += TPB) twl[t] = twN[t];
  __syncthreads();

  for (int idx = tid; idx < W2*BQ; idx += TPB) {
    int pm = idx / BQ, n = idx - pm*BQ;
    int m = pm - (BQ-1);
    int am = m < 0 ? -m : m;
    int lmin = am > n ? am : n;
    int base = lmin*(4*lmin*lmin - 1)/3;
    float ax = 0.f, ay = 0.f;
    for (int l = lmin; l < BQ; l++) {
      int Wl = 2*l+1;
      int e = base + (m+l)*Wl + (n+l);
      float2 y = yh[(size_t)e*BO + bo];
      float d = dS[(size_t)N*base + (size_t)j*Wl*Wl + (m+l)*Wl + (n+l)];
      ax += d*y.x; ay += d*y.y;
      base += Wl*Wl;
    }
    P[idx] = make_float2(ax, ay);
  }
  __syncthreads();

  for (int idx = tid; idx < (N/2)*BQ; idx += TPB) {
    int ag = idx / BQ, n = idx - ag*BQ;
    int a0 = 2*ag, a1 = a0 + 1;
    int t0 = (N - (a0*(BQ-1)) % N) % N;
    int t1 = (N - (a1*(BQ-1)) % N) % N;
    float2 A0 = {0,0}, A1 = {0,0};
    for (int pm = 0; pm < W2; pm++) {
      float2 p = P[pm*BQ + n];
      float2 w0 = twl[t0], w1 = twl[t1];
      A0.x += p.x*w0.x - p.y*w0.y; A0.y += p.x*w0.y + p.y*w0.x;
      A1.x += p.x*w1.x - p.y*w1.y; A1.y += p.x*w1.y + p.y*w1.x;
      t0 += a0; if (t0 >= N) t0 -= N;
      t1 += a1; if (t1 >= N) t1 -= N;
    }
    Tm[a0*BQ + n] = A0;
    Tm[a1*BQ + n] = A1;
  }
  __syncthreads();

  {
    constexpr int CG = N/2;
    const float4* WnR = (const float4*)Wn2;
    for (int idx = tid; idx < N*CG; idx += TPB) {
      int a = idx / CG, cg = idx - a*CG;
      float s0 = 0.f, s1 = 0.f;
      const float2* TmA = Tm + a*BQ;
      for (int n = 0; n < BQ; n++) {
        float2 T = TmA[n];
        float4 w = WnR[n*CG + cg];
        s0 += T.x*w.x - T.y*w.y;
        s1 += T.x*w.z - T.y*w.w;
      }
      s0 = fmaxf(s0, 0.f); s1 = fmaxf(s1, 0.f);
      *(float2*)&S[a*N + 2*cg] = make_float2(s0, s1);
    }
  }
  __syncthreads();

  if constexpr (!INTEG) {
    for (int idx = tid; idx < (N/2)*KT; idx += TPB) {
      int ag = idx / KT, k = idx - ag*KT;
      int a0 = 2*ag, a1 = a0 + 1;
      float u0x=0.f,u0y=0.f,u1x=0.f,u1y=0.f;
      const float* S0 = S + a0*N;
      const float* S1 = S + a1*N;
      for (int c = 0; c < N; c++) {
        float2 w = Wg[c*KT + k];
        u0x += S0[c]*w.x; u0y += S0[c]*w.y;
        u1x += S1[c]*w.x; u1y += S1[c]*w.y;
      }
      U[a0*KT + k] = make_float2(u0x, u0y);
      U[a1*KT + k] = make_float2(u1x, u1y);
    }
    __syncthreads();

    float2* xtb = xt + ((size_t)bo*N + j)*(MT*KT);
    for (int idx = tid; idx < MT*KT; idx += TPB) {
      int pm2 = idx / KT, k = idx - pm2*KT;
      int m = pm2 - (KT-1);
      float ax = 0.f, ay = 0.f;
      int t = 0;
      for (int a = 0; a < N; a++) {
        float2 u = U[a*KT + k];
        float2 w = twl[t];
        ax += u.x*w.x + u.y*w.y;
        ay += u.y*w.x - u.x*w.y;
        t += m; if (t < 0) t += N; else if (t >= N) t -= N;
      }
      xtb[idx] = make_float2(ax, ay);
    }
  } else {
    float part = 0.f;
    for (int idx = tid; idx < N*N; idx += TPB) part += S[idx];
    red[tid] = part;
    __syncthreads();
    for (int off2 = TPB >> 1; off2 > 0; off2 >>= 1) {
      if (tid < off2) red[tid] += red[tid + off2];
      __syncthreads();
    }
    if (tid == 0) s5p[bo*N + j] = red[0]*wInt[j];
  }
}

// ---------------- head: integrate-reduce + 3x (batchnorm, linear) ----------
__global__ __launch_bounds__(256) void k_mlp(
    const float* __restrict__ s5p,
    const float* __restrict__ g1, const float* __restrict__ be1,
    const float* __restrict__ w1, const float* __restrict__ b1,
    const float* __restrict__ g2, const float* __restrict__ be2,
    const float* __restrict__ w2, const float* __restrict__ b2,
    const float* __restrict__ g3, const float* __restrict__ be3,
    const float* __restrict__ w3, const float* __restrict__ b3,
    float* __restrict__ out)
{
  __shared__ float A[2048], Bs[2048], C[1024], mu[64], iv[64];
  int tid = threadIdx.x;
  for (int idx = tid; idx < 2048; idx += 256) {
    float s = 0.f;
    #pragma unroll
    for (int j = 0; j < 6; j++) s += s5p[idx*6 + j];
    A[idx] = s;
  }
  __syncthreads();
  if (tid < 64) {
    float m = 0.f; for (int b = 0; b < 32; b++) m += A[b*64 + tid]; m *= (1.f/32);
    float v = 0.f; for (int b = 0; b < 32; b++) { float d = A[b*64+tid]-m; v += d*d; } v *= (1.f/32);
    mu[tid] = m; iv[tid] = rsqrtf(v + 1e-5f)*g1[tid];
  }
  __syncthreads();
  for (int idx = tid; idx < 2048; idx += 256) {
    int f = idx & 63;
    A[idx] = (A[idx]-mu[f])*iv[f] + be1[f];
  }
  __syncthreads();
  for (int idx = tid; idx < 2048; idx += 256) {
    int b = idx >> 6, fo = idx & 63;
    float s = b1[fo];
    for (int f = 0; f < 64; f++) s += A[b*64+f]*w1[f*64+fo];
    Bs[idx] = fmaxf(s, 0.f);
  }
  __syncthreads();
  if (tid < 64) {
    float m = 0.f; for (int b = 0; b < 32; b++) m += Bs[b*64+tid]; m *= (1.f/32);
    float v = 0.f; for (int b = 0; b < 32; b++) { float d = Bs[b*64+tid]-m; v += d*d; } v *= (1.f/32);
    mu[tid] = m; iv[tid] = rsqrtf(v + 1e-5f)*g2[tid];
  }
  __syncthreads();
  for (int idx = tid; idx < 2048; idx += 256) {
    int f = idx & 63;
    Bs[idx] = (Bs[idx]-mu[f])*iv[f] + be2[f];
  }
  __syncthreads();
  for (int idx = tid; idx < 1024; idx += 256) {
    int b = idx >> 5, fo = idx & 31;
    float s = b2[fo];
    for (int f = 0; f < 64; f++) s += Bs[b*64+f]*w2[f*32+fo];
    C[idx] = fmaxf(s, 0.f);
  }
  __syncthreads();
  if (tid < 32) {
    float m = 0.f; for (int b = 0; b < 32; b++) m += C[b*32+tid]; m *= (1.f/32);
    float v = 0.f; for (int b = 0; b < 32; b++) { float d = C[b*32+tid]-m; v += d*d; } v *= (1.f/32);
    mu[tid] = m; iv[tid] = rsqrtf(v + 1e-5f)*g3[tid];
  }
  __syncthreads();
  for (int idx = tid; idx < 1024; idx += 256) {
    int f = idx & 31;
    C[idx] = (C[idx]-mu[f])*iv[f] + be3[f];
  }
  __syncthreads();
  for (int idx = tid; idx < 320; idx += 256) {
    int b = idx/10, cc = idx - b*10;
    float s = b3[cc];
    for (int f = 0; f < 32; f++) s += C[b*32+f]*w3[f*10+cc];
    out[idx] = s;
  }
}

// ============================================================================
// launch
// ============================================================================
static inline int cdiv_h(int a, int b) { return (a + b - 1)/b; }

extern "C" void kernel_launch(void* const* d_in, const int* in_sizes, int n_in,
                              void* d_out, int out_size, void* d_ws, size_t ws_size,
                              hipStream_t stream) {
  (void)in_sizes; (void)n_in; (void)out_size;
  if (!g_devF || !g_devC || !g_devI || ws_size < WS_TOTAL) return;

  const float* x    = (const float*)d_in[0];
  const float* ks2  = (const float*)d_in[1];
  const float* k1   = (const float*)d_in[2];
  const float* k2   = (const float*)d_in[3];
  const float* k3   = (const float*)d_in[4];
  const float* k4   = (const float*)d_in[5];
  const float* g1   = (const float*)d_in[6],  *be1 = (const float*)d_in[7];
  const float* w1   = (const float*)d_in[8],  *b1  = (const float*)d_in[9];
  const float* g2   = (const float*)d_in[10], *be2 = (const float*)d_in[11];
  const float* w2   = (const float*)d_in[12], *b2  = (const float*)d_in[13];
  const float* g3   = (const float*)d_in[14], *be3 = (const float*)d_in[15];
  const float* w3   = (const float*)d_in[16], *b3  = (const float*)d_in[17];
  float* out = (float*)d_out;
  char* ws = (char*)d_ws;

  float2* XF1  = (float2*)(ws + WS_XF1);
  float2* xh1  = (float2*)(ws + WS_XH1);
  float2* kh1  = (float2*)(ws + WS_KH1);
  float2* yh1t = (float2*)(ws + WS_YH1T);
  float2* xh2  = (float2*)(ws + WS_XH2);
  float2* kh2  = (float2*)(ws + WS_KH2);
  float2* yh2t = (float2*)(ws + WS_YH2T);
  float2* xh3  = (float2*)(ws + WS_XH3);
  float2* kh3  = (float2*)(ws + WS_KH3);
  float2* yh3t = (float2*)(ws + WS_YH3T);
  float2* xt4  = (float2*)(ws + WS_XT4);
  float2* xh4  = (float2*)(ws + WS_XH4);
  float2* kh4  = (float2*)(ws + WS_KH4);
  float2* yh4t = (float2*)(ws + WS_YH4T);
  float2* xt5  = (float2*)(ws + WS_XT5);
  float2* xh5  = (float2*)(ws + WS_XH5);
  float2* kh5  = (float2*)(ws + WS_KH5);
  float2* yh5t = (float2*)(ws + WS_YH5T);
  float*  s5p  = (float*) (ws + WS_S5P);
  float2* xt2  = (float2*)(ws + WS_XT2);
  float2* xt3  = (float2*)(ws + WS_XT3);
  float2* RX   = (float2*)(ws + WS_RX);
  float2* RY   = (float2*)(ws + WS_RY);

  const float* dA1p  = g_devF + CO.A1;
  const float* dAT2p = g_devF + CO.dAT2;
  const float* dAT3p = g_devF + CO.dAT3;
  const float* dA4p  = g_devF + CO.A4;
  const float* dA5p  = g_devF + CO.A5;
  const float* dT1p  = g_devF + CO.dT1;
  const float* dT2p  = g_devF + CO.dT2;
  const float* dS3p  = g_devF + CO.S3;
  const float* dS4p  = g_devF + CO.S4;
  const float* dS5p  = g_devF + CO.S5;
  const float* wIntp = g_devF + CO.WInt;
  const float2* Fs2p  = g_devC + CO.Fs2;
  const float2* Fso3p = g_devC + CO.Fso3;
  const float2* tw60p = g_devC + CO.Tw60;
  const float2* tw18p = g_devC + CO.Tw18;
  const float2* tw10p = g_devC + CO.Tw10;
  const float2* tw6p  = g_devC + CO.Tw6;
  const float2* Wn1p  = g_devC + CO.Wn1;
  const float2* Wn2p  = g_devC + CO.Wn2o;
  const float2* Wn4p  = g_devC + CO.Wn4;
  const float2* Wn5p  = g_devC + CO.Wn5;
  const float2* Wg1p  = g_devC + CO.Wg1;
  const float2* Wg2p  = g_devC + CO.Wg2;
  const float2* Wg4p  = g_devC + CO.Wg4;
  const float2* WA1p  = g_devC + CO.WA1t;
  const float2* WA2p  = g_devC + CO.WA2t;
  const float2* WC1p  = g_devC + CO.WC1;
  const float2* WC2p  = g_devC + CO.WC2;
  const int* toff1p = g_devI;
  const int* toff2p = g_devI + 1770;

  constexpr int Q30 = OQh(30), Q17 = OQh(17), Q9 = OQh(9), Q5 = OQh(5), Q3 = OQh(3);

  // kernel FTs
  k_kh_s2 <<<cdiv_h(1800,256),    256, 0, stream>>>(ks2, Fs2p,  kh1);
  k_kh_so3<<<cdiv_h(Q17*10,256),  256, 0, stream>>>(k1, Fso3p, kh2, 17, 2, 5);
  k_kh_so3<<<cdiv_h(Q9*60,256),   256, 0, stream>>>(k2, Fso3p, kh3, 9, 5, 12);
  k_kh_so3<<<cdiv_h(Q5*336,256),  256, 0, stream>>>(k3, Fso3p, kh4, 5, 12, 28);
  k_kh_so3<<<cdiv_h(Q3*1792,256), 256, 0, stream>>>(k4, Fso3p, kh5, 3, 28, 64);

  // stage 1 analysis + spectral product
  k_s1_fftA<<<32*60, 64, 0, stream>>>(x, tw60p, XF1);
  k_s1_coef<<<cdiv_h(32*900,256), 256, 0, stream>>>(XF1, dA1p, xh1);
  k_s1_yh_t<<<cdiv_h(64*Q30,256), 256, 0, stream>>>(xh1, kh1, yh1t);

  // stage-1 synthesis GEMM passes (SL=3840, 4 chunks of 960)
  for (int c = 0; c < 4; c++) {
    int slOff = c*960;
    k_scat<30,60,16,256><<<1770, 256, 0, stream>>>(yh1t, dT1p, toff1p, RX, c*16, 64);
    k_dftA<59,30,30,2,60,960,256><<<240, 256, 0, stream>>>(RX, WA1p, RY);
    k_dftB<30,60,17,960,256><<<240, 256, 0, stream>>>(RY, Wn1p, Wg1p, RX);
    k_dftC<33,17,60,960,256><<<68, 256, 0, stream>>>(RX, WC1p, xt2, slOff, 3840);
  }
  k_coef_t<17,60,17,256><<<cdiv_h(64*Q17,256), 256, 0, stream>>>(xt2, dAT2p, xh2, Q17, 64, 3840);
  k_yh_t<<<cdiv_h(Q17*160,256), 256, 0, stream>>>(xh2, kh2, yh2t, 17, 2, 5, Q17);

  // stage-2 synthesis GEMM passes (SL=5440, 2 chunks of 2720)
  for (int c = 0; c < 2; c++) {
    int slOff = c*2720;
    k_scat<17,34,80,256><<<561, 256, 0, stream>>>(yh2t, dT2p, toff2p, RX, c*80, 160);
    k_dftA<33,17,34,1,34,2720,256><<<187, 256, 0, stream>>>(RX, WA2p, RY);
    k_dftB<17,34,9,2720,256><<<374, 256, 0, stream>>>(RY, Wn2p, Wg2p, RX);
    k_dftC<17,9,34,2720,256><<<99, 256, 0, stream>>>(RX, WC2p, xt3, slOff, 5440);
  }
  k_coef_t<9,34,9,256><<<cdiv_h(160*Q9,256), 256, 0, stream>>>(xt3, dAT3p, xh3, Q9, 160, 5440);
  k_yh_t<<<cdiv_h(Q9*384,256), 256, 0, stream>>>(xh3, kh3, yh3t, 9, 5, 12, Q9);

  // stage 3 (old fused path, transposed yh read)
  k_synth3<9,18,5,9,64,384><<<384*18, 64, 0, stream>>>(yh3t, dS3p, tw18p, xt4);
  k_coef<<<cdiv_h(384*Q5,256), 256, 0, stream>>>(xt4, dA4p, xh4, 5, 18, 5, 9, Q5, 384);
  k_yh_t<<<cdiv_h(Q5*896,256), 256, 0, stream>>>(xh4, kh4, yh4t, 5, 12, 28, Q5);

  // stage 4
  k_synth2<5,10,3,5,0,1,64,896><<<896*10, 64, 0, stream>>>(yh4t, dS4p, tw10p, Wn4p, Wg4p, xt5, nullptr, nullptr);
  k_coef<<<cdiv_h(896*Q3,256), 256, 0, stream>>>(xt5, dA5p, xh5, 3, 10, 3, 5, Q3, 896);
  k_yh_t<<<cdiv_h(Q3*2048,256), 256, 0, stream>>>(xh5, kh5, yh5t, 3, 28, 64, Q3);

  // stage 5: synthesis fused with so3_integrate
  k_synth2<3,6,3,5,1,1,64,2048><<<2048*6, 64, 0, stream>>>(yh5t, dS5p, tw6p, Wn5p, nullptr, nullptr, s5p, wIntp);

  // head
  k_mlp<<<1, 256, 0, stream>>>(s5p, g1, be1, w1, b1, g2, be2, w2, b2, g3, be3, w3, b3, out);
}

// Round 5
// 928.640 us; speedup vs baseline: 1.1580x; 1.1580x over previous
//
#include <hip/hip_runtime.h>
#include <cmath>
#include <cstring>
#include <vector>

// ============================================================================
// Spherical CNN (s2conv -> 4x so3conv -> integrate -> MLP), MI355X gfx950.
// Round 5: dispatch-count reduction (44 -> 24), fused scatter+alpha-iDFT with
// on-the-fly rank-1 yh for stage 1, radix-2 GEMM chain, pidx-block LDS coef.
// ============================================================================

#define DPI 3.14159265358979323846

static constexpr int OQh(int l) { return l*(4*l*l - 1)/3; }
static_assert(OQh(30) == 35990, "oq30");
static_assert(OQh(17) == 6545,  "oq17");
static_assert(OQh(9)  == 969,   "oq9");
static_assert(OQh(5)  == 165,   "oq5");
static_assert(OQh(3)  == 35,    "oq3");

static constexpr int T1SUM = 18445;   // packed synth terms, stage 1 (BQ=30)
static constexpr int T2SUM = 3417;    // packed synth terms, stage 2 (BQ=17)

// ---------------- workspace layout (bytes) ----------------
static constexpr size_t al256(size_t x){ return (x + 255) & ~(size_t)255; }
static constexpr size_t WS_XF1  = 0;
static constexpr size_t WS_XH1  = WS_XF1  + al256(32ull*60*30*8);
static constexpr size_t WS_KH1  = WS_XH1  + al256(32ull*900*8);
static constexpr size_t WS_XT2  = WS_KH1  + al256(1800ull*8);
static constexpr size_t WS_XH2  = WS_XT2  + al256(561ull*3840*8);
static constexpr size_t WS_KH2  = WS_XH2  + al256(64ull*6545*8);
static constexpr size_t WS_YH2T = WS_KH2  + al256(6545ull*10*8);
static constexpr size_t WS_XT3  = WS_YH2T + al256(6545ull*160*8);
static constexpr size_t WS_XH3  = WS_XT3  + al256(153ull*5440*8);
static constexpr size_t WS_KH3  = WS_XH3  + al256(160ull*969*8);
static constexpr size_t WS_YH3T = WS_KH3  + al256(969ull*60*8);
static constexpr size_t WS_XT4  = WS_YH3T + al256(969ull*384*8);
static constexpr size_t WS_XH4  = WS_XT4  + al256(384ull*18*45*8);
static constexpr size_t WS_KH4  = WS_XH4  + al256(384ull*165*8);
static constexpr size_t WS_YH4T = WS_KH4  + al256(165ull*336*8);
static constexpr size_t WS_XT5  = WS_YH4T + al256(165ull*896*8);
static constexpr size_t WS_XH5  = WS_XT5  + al256(896ull*10*15*8);
static constexpr size_t WS_KH5  = WS_XH5  + al256(896ull*35*8);
static constexpr size_t WS_YH5T = WS_KH5  + al256(35ull*1792*8);
static constexpr size_t WS_S5P  = WS_YH5T + al256(35ull*2048*8);
static constexpr size_t WS_RTM  = WS_S5P  + al256(2048ull*6*4);
static constexpr size_t WS_RU   = WS_RTM  + al256(60ull*30*1920*8);  // 27.6MB (>= st2 25.2MB)
static constexpr size_t WS_TOTAL= WS_RU   + al256(60ull*17*1920*8);  // 15.7MB (>= st2 13.3MB)
// total ~= 92 MB (R4's 95.1MB passed, so ws_size >= 95.1MB)

// ---------------- constant-table offsets ----------------
struct ConstOffs {
  size_t A1, dAT2, dAT3, A4, A5;
  size_t dT1, dT2;
  size_t S3, S4, S5;
  size_t WInt;
  size_t nF;
  size_t Fs2, Fso3;
  size_t Tw60, Tw34, Tw18, Tw10, Tw6;
  size_t Wn1, Wn2o, Wn4, Wn5;
  size_t Wg1, Wg2, Wg4;
  size_t WC1, WC2;
  size_t nC;
};
static ConstOffs CO;
static float*  g_devF = nullptr;
static float2* g_devC = nullptr;
static int*    g_devI = nullptr;
// int-table layout
static constexpr int IO_TOFF1 = 0;          // 1770
static constexpr int IO_TOFF2 = 1770;       // 561
static constexpr int IO_QOFF2 = 2331;       // 562
static constexpr int IO_QLST2 = 2893;       // 6545
static constexpr int IO_QOFF3 = 9438;       // 154
static constexpr int IO_QLST3 = 9592;       // 969
static constexpr int IO_TOTAL = 10561;

// ============================================================================
// Host: symmetric-tridiagonal eigensolver + Wigner-d builder
// ============================================================================
static void tqli(double* d, double* e, int n, double* z) {
  e[n-1] = 0.0;
  for (int l = 0; l < n; l++) {
    int iter = 0;
    int m;
    do {
      for (m = l; m < n-1; m++) {
        double dd = fabs(d[m]) + fabs(d[m+1]);
        if (fabs(e[m]) <= 1e-300 + 1e-14*dd) break;
      }
      if (m != l) {
        if (iter++ == 80) break;
        double g = (d[l+1]-d[l])/(2.0*e[l]);
        double r = hypot(g, 1.0);
        g = d[m]-d[l]+e[l]/(g + (g >= 0.0 ? fabs(r) : -fabs(r)));
        double s = 1.0, c = 1.0, p = 0.0;
        int i;
        r = 1.0;
        for (i = m-1; i >= l; i--) {
          double f = s*e[i], b = c*e[i];
          r = hypot(f, g);
          e[i+1] = r;
          if (r == 0.0) { d[i+1] -= p; e[m] = 0.0; break; }
          s = f/r; c = g/r;
          g = d[i+1]-p;
          r = (d[i]-g)*s + 2.0*c*b;
          p = s*r;
          d[i+1] = g+p;
          g = c*r-b;
          for (int k = 0; k < n; k++) {
            f = z[(size_t)k*n+i+1];
            z[(size_t)k*n+i+1] = s*z[(size_t)k*n+i] + c*f;
            z[(size_t)k*n+i]   = c*z[(size_t)k*n+i] - s*f;
          }
        }
        if (r == 0.0 && i >= l) continue;
        d[l] -= p; e[l] = g; e[m] = 0.0;
      }
    } while (m != l);
  }
}

struct Builder {
  std::vector<std::vector<double>> V, Lam;
  bool useExpm[30];

  Builder() {
    V.resize(30); Lam.resize(30);
    for (int l = 0; l < 30; l++) {
      int n = 2*l+1;
      std::vector<double> d(n, 0.0), e(n, 0.0), z((size_t)n*n, 0.0);
      for (int i = 0; i < n; i++) z[(size_t)i*n+i] = 1.0;
      for (int i = 0; i+1 < n; i++) {
        double m = (double)i - l;
        e[i] = -0.5*sqrt((double)l*(l+1) - m*(m+1.0));
      }
      if (n > 1) tqli(d.data(), e.data(), n, z.data());
      V[l] = std::move(z); Lam[l] = std::move(d);
    }
    std::vector<double> t((size_t)59*59);
    for (int l = 0; l < 30; l++) {
      useExpm[l] = false;
      if (l == 0) continue;
      int n = 2*l+1;
      eigD(l, 0.77, t.data());
      double corner = pow(cos(0.385), 2.0*l);
      double err = fabs(t[0] - corner) + fabs(t[(size_t)(n-1)*n + (n-1)] - corner);
      double s = 0.0;
      for (int c = 0; c < n; c++) s += t[c]*t[c];
      err += fabs(s - 1.0);
      if (!(err < 1e-8)) useExpm[l] = true;
    }
  }

  void eigD(int l, double beta, double* out) {
    int n = 2*l+1;
    const double* Vp = V[l].data();
    const double* lam = Lam[l].data();
    double ck[64], sk[64];
    for (int k = 0; k < n; k++) { ck[k] = cos(beta*lam[k]); sk[k] = sin(beta*lam[k]); }
    for (int a = 0; a < n; a++) {
      const double* va = Vp + (size_t)a*n;
      for (int c = 0; c < n; c++) {
        const double* vc = Vp + (size_t)c*n;
        int r = ((a - c) % 4 + 4) % 4;
        const double* f = (r & 1) ? sk : ck;
        double s = 0.0;
        for (int k = 0; k < n; k++) s += va[k]*vc[k]*f[k];
        out[(size_t)a*n + c] = (r >= 2) ? -s : s;
      }
    }
  }

  void expmD(int l, double beta, double* out) {
    int n = 2*l+1;
    int s = 0; double bl = fabs(beta)*(double)l + 1e-12;
    while (bl > 0.25) { bl *= 0.5; s++; }
    double sc = ldexp(beta, -s);
    std::vector<double> sup(n > 1 ? n-1 : 0);
    for (int i = 0; i+1 < n; i++) {
      double m = (double)i - l;
      sup[i] = 0.5*sqrt((double)l*(l+1) - m*(m+1.0))*sc;
    }
    std::vector<double> term((size_t)n*n, 0.0), acc((size_t)n*n, 0.0), t2((size_t)n*n);
    for (int i = 0; i < n; i++) { term[(size_t)i*n+i] = 1.0; acc[(size_t)i*n+i] = 1.0; }
    for (int k = 1; k <= 16; k++) {
      for (int r = 0; r < n; r++)
        for (int c = 0; c < n; c++) {
          double v = 0.0;
          if (c > 0)   v += term[(size_t)r*n + c-1]*sup[c-1];
          if (c+1 < n) v -= term[(size_t)r*n + c+1]*sup[c];
          t2[(size_t)r*n+c] = v/(double)k;
        }
      term.swap(t2);
      for (size_t i2 = 0; i2 < (size_t)n*n; i2++) acc[i2] += term[i2];
    }
    for (int t = 0; t < s; t++) {
      for (int r = 0; r < n; r++)
        for (int c = 0; c < n; c++) {
          double v = 0.0;
          for (int k = 0; k < n; k++) v += acc[(size_t)r*n+k]*acc[(size_t)k*n+c];
          t2[(size_t)r*n+c] = v;
        }
      acc.swap(t2);
    }
    std::memcpy(out, acc.data(), sizeof(double)*(size_t)n*n);
  }

  void buildD(int l, double beta, double* out) {
    if (useExpm[l]) expmD(l, beta, out); else eigD(l, beta, out);
  }
};

static std::vector<double> quadw_h(int b) {
  std::vector<double> w(2*b);
  for (int j = 0; j < 2*b; j++) {
    double s = 0;
    for (int k = 0; k < b; k++)
      s += sin(DPI*(2*j+1)*(2*k+1)/(4.0*b))/(double)(2*k+1);
    w[j] = (2.0/b)*sin(DPI*(2*j+1)/(4.0*b))*s;
  }
  return w;
}

static void build_all() {
  size_t o = 0;
  CO.A1   = o; o += 60ull*900;
  CO.dAT2 = o; o += (size_t)OQh(17)*60;
  CO.dAT3 = o; o += (size_t)OQh(9)*34;
  CO.A4   = o; o += 18ull*OQh(5);
  CO.A5   = o; o += 10ull*OQh(3);
  CO.dT1  = o; o += (size_t)T1SUM*60;
  CO.dT2  = o; o += (size_t)T2SUM*34;
  CO.S3   = o; o += 18ull*OQh(9);
  CO.S4   = o; o += 10ull*OQh(5);
  CO.S5   = o; o +=  6ull*OQh(3);
  CO.WInt = o; o += 8;
  CO.nF = o;
  size_t c = 0;
  CO.Fs2  = c; c += 6ull*900;
  CO.Fso3 = c; c += 36ull*OQh(17);
  CO.Tw60 = c; c += 60; CO.Tw34 = c; c += 34;
  CO.Tw18 = c; c += 18; CO.Tw10 = c; c += 10; CO.Tw6 = c; c += 6;
  CO.Wn1  = c; c += 30*60; CO.Wn2o = c; c += 17*34;
  CO.Wn4  = c; c += 5*10;  CO.Wn5  = c; c += 3*6;
  CO.Wg1  = c; c += 60*17; CO.Wg2  = c; c += 34*9; CO.Wg4 = c; c += 10*3;
  CO.WC1  = c; c += 33*60;
  CO.WC2  = c; c += 17*34;
  CO.nC = c;

  std::vector<float> HF(CO.nF, 0.f);
  std::vector<float> HC(2*CO.nC, 0.f);
  std::vector<int> HI(IO_TOTAL, 0);

  // packed-term prefix offsets for synth scatter
  { int acc = 0;
    for (int pm = 0; pm < 59; pm++) for (int n = 0; n < 30; n++) {
      int m = pm - 29, am = m < 0 ? -m : m;
      int lm = am > n ? am : n;
      HI[IO_TOFF1 + pm*30 + n] = acc; acc += 30 - lm;
    } }
  { int acc = 0;
    for (int pm = 0; pm < 33; pm++) for (int n = 0; n < 17; n++) {
      int m = pm - 16, am = m < 0 ? -m : m;
      int lm = am > n ? am : n;
      HI[IO_TOFF2 + pm*17 + n] = acc; acc += 17 - lm;
    } }
  // q-lists for pidx-block coef (stage 2: rows (m+16)*17+k, KT=17, L=17)
  { int pos = 0;
    for (int mh = -16; mh <= 16; mh++)
      for (int kh = 0; kh < 17; kh++) {
        HI[IO_QOFF2 + (mh+16)*17 + kh] = pos;
        int am = mh < 0 ? -mh : mh;
        int lmin = am > kh ? am : kh;
        for (int l = lmin; l < 17; l++) {
          int q = OQh(l) + (mh+l)*(2*l+1) + (kh+l);
          HI[IO_QLST2 + pos++] = q*2;
        }
        if (kh > 0)
          for (int l = lmin; l < 17; l++) {
            int q = OQh(l) + (-mh+l)*(2*l+1) + (-kh+l);
            HI[IO_QLST2 + pos++] = q*2 + 1;
          }
      }
    HI[IO_QOFF2 + 561] = pos;   // == Q17
  }
  // stage 3: rows (m+8)*9+k, KT=9, L=9
  { int pos = 0;
    for (int mh = -8; mh <= 8; mh++)
      for (int kh = 0; kh < 9; kh++) {
        HI[IO_QOFF3 + (mh+8)*9 + kh] = pos;
        int am = mh < 0 ? -mh : mh;
        int lmin = am > kh ? am : kh;
        for (int l = lmin; l < 9; l++) {
          int q = OQh(l) + (mh+l)*(2*l+1) + (kh+l);
          HI[IO_QLST3 + pos++] = q*2;
        }
        if (kh > 0)
          for (int l = lmin; l < 9; l++) {
            int q = OQh(l) + (-mh+l)*(2*l+1) + (-kh+l);
            HI[IO_QLST3 + pos++] = q*2 + 1;
          }
      }
    HI[IO_QOFF3 + 153] = pos;   // == Q9
  }

  Builder B;
  auto betas = [](int b){ std::vector<double> v(2*b);
    for (int j = 0; j < 2*b; j++) v[j] = DPI*(2*j+1)/(4.0*b); return v; };
  auto w30 = quadw_h(30), w17 = quadw_h(17), w9 = quadw_h(9), w5 = quadw_h(5), w3 = quadw_h(3);
  std::vector<double> tmp((size_t)59*59);

  { auto bs = betas(30);
    for (int l = 0; l < 30; l++) { int W = 2*l+1;
      for (int j = 0; j < 60; j++) {
        B.buildD(l, bs[j], tmp.data());
        for (int mm = -l; mm <= l; mm++)
          for (int nn = 0; nn <= l; nn++) {
            int am = mm < 0 ? -mm : mm;
            int lmin = am > nn ? am : nn;
            int term = HI[IO_TOFF1 + (mm+29)*30 + nn] + (l - lmin);
            HF[CO.dT1 + (size_t)term*60 + j] =
              (float)((2*l+1)*tmp[(size_t)(mm+l)*W + (nn+l)]);
          }
        if (l < 17) {
          for (int rem = 0; rem < W*W; rem++)
            HF[CO.dAT2 + (size_t)(OQh(l)+rem)*60 + j] = (float)(tmp[rem]*w30[j]);
        }
        float* dA1 = HF.data() + CO.A1 + 60ull*l*l + (size_t)j*W;
        for (int mi = 0; mi < W; mi++) dA1[mi] = (float)(tmp[(size_t)mi*W + l]*w30[j]);
      } } }
  { auto bs = betas(17);
    for (int l = 0; l < 17; l++) { int W = 2*l+1;
      for (int j = 0; j < 34; j++) {
        B.buildD(l, bs[j], tmp.data());
        for (int mm = -l; mm <= l; mm++)
          for (int nn = 0; nn <= l; nn++) {
            int am = mm < 0 ? -mm : mm;
            int lmin = am > nn ? am : nn;
            int term = HI[IO_TOFF2 + (mm+16)*17 + nn] + (l - lmin);
            HF[CO.dT2 + (size_t)term*34 + j] =
              (float)((2*l+1)*tmp[(size_t)(mm+l)*W + (nn+l)]);
          }
        if (l < 9) {
          for (int rem = 0; rem < W*W; rem++)
            HF[CO.dAT3 + (size_t)(OQh(l)+rem)*34 + j] = (float)(tmp[rem]*w17[j]);
        } } } }
  { auto bs = betas(9);
    for (int l = 0; l < 9; l++) { int W = 2*l+1;
      for (int j = 0; j < 18; j++) {
        B.buildD(l, bs[j], tmp.data());
        float* dst = HF.data() + CO.S3 + 18ull*OQh(l) + (size_t)j*W*W;
        for (int i2 = 0; i2 < W*W; i2++) dst[i2] = (float)((2*l+1)*tmp[i2]);
        if (l < 5) {
          float* dA = HF.data() + CO.A4 + 18ull*OQh(l) + (size_t)j*W*W;
          for (int i2 = 0; i2 < W*W; i2++) dA[i2] = (float)(tmp[i2]*w9[j]);
        } } } }
  { auto bs = betas(5);
    for (int l = 0; l < 5; l++) { int W = 2*l+1;
      for (int j = 0; j < 10; j++) {
        B.buildD(l, bs[j], tmp.data());
        float* dst = HF.data() + CO.S4 + 10ull*OQh(l) + (size_t)j*W*W;
        for (int i2 = 0; i2 < W*W; i2++) dst[i2] = (float)((2*l+1)*tmp[i2]);
        if (l < 3) {
          float* dA = HF.data() + CO.A5 + 10ull*OQh(l) + (size_t)j*W*W;
          for (int i2 = 0; i2 < W*W; i2++) dA[i2] = (float)(tmp[i2]*w5[j]);
        } } } }
  { auto bs = betas(3);
    for (int l = 0; l < 3; l++) { int W = 2*l+1;
      for (int j = 0; j < 6; j++) {
        B.buildD(l, bs[j], tmp.data());
        float* dst = HF.data() + CO.S5 + 6ull*OQh(l) + (size_t)j*W*W;
        for (int i2 = 0; i2 < W*W; i2++) dst[i2] = (float)((2*l+1)*tmp[i2]);
      } } }
  { double beta = DPI/16.0;
    for (int l = 0; l < 30; l++) { int n = 2*l+1;
      B.buildD(l, beta, tmp.data());
      for (int p = 0; p < 6; p++) {
        double al = 2.0*DPI*p/6.0;
        for (int mi = 0; mi < n; mi++) {
          double ph = al*(double)(mi - l);
          double dr = tmp[(size_t)mi*n + l];
          size_t off = CO.Fs2 + 6ull*l*l + (size_t)p*n + mi;
          HC[2*off]   = (float)(dr*cos(ph));
          HC[2*off+1] = (float)(dr*sin(ph));
        } }
      if (l < 17) {
        for (int p = 0; p < 36; p++) {
          double al = 2.0*DPI*(p/6)/6.0, ga = 2.0*DPI*(p%6)/6.0;
          for (int mi = 0; mi < n; mi++)
            for (int ni = 0; ni < n; ni++) {
              double ph = al*(double)(mi - l) + ga*(double)(ni - l);
              double dr = tmp[(size_t)mi*n + ni];
              size_t off = CO.Fso3 + 36ull*OQh(l) + (size_t)p*n*n + (size_t)mi*n + ni;
              HC[2*off]   = (float)(dr*cos(ph));
              HC[2*off+1] = (float)(dr*sin(ph));
            } } } } }
  auto fillTw = [&](size_t ofs, int N){
    for (int t = 0; t < N; t++) {
      HC[2*(ofs+t)]   = (float)cos(2.0*DPI*t/N);
      HC[2*(ofs+t)+1] = (float)sin(2.0*DPI*t/N);
    } };
  fillTw(CO.Tw60, 60); fillTw(CO.Tw34, 34);
  fillTw(CO.Tw18, 18); fillTw(CO.Tw10, 10); fillTw(CO.Tw6, 6);
  auto fillWn = [&](size_t ofs, int BQ, int N){
    for (int n = 0; n < BQ; n++)
      for (int cc2 = 0; cc2 < N; cc2++) {
        double f = (n == 0) ? 1.0 : 2.0;
        HC[2*(ofs + (size_t)n*N + cc2)]   = (float)(f*cos(2.0*DPI*n*cc2/N));
        HC[2*(ofs + (size_t)n*N + cc2)+1] = (float)(f*sin(2.0*DPI*n*cc2/N));
      } };
  auto fillWg = [&](size_t ofs, int N, int KT){
    for (int cc2 = 0; cc2 < N; cc2++)
      for (int k = 0; k < KT; k++) {
        HC[2*(ofs + (size_t)cc2*KT + k)]   = (float)cos(2.0*DPI*k*cc2/N);
        HC[2*(ofs + (size_t)cc2*KT + k)+1] = (float)(-sin(2.0*DPI*k*cc2/N));
      } };
  fillWn(CO.Wn1, 30, 60); fillWn(CO.Wn2o, 17, 34);
  fillWn(CO.Wn4, 5, 10);  fillWn(CO.Wn5, 3, 6);
  fillWg(CO.Wg1, 60, 17); fillWg(CO.Wg2, 34, 9); fillWg(CO.Wg4, 10, 3);
  for (int p = 0; p < 33; p++)
    for (int a = 0; a < 60; a++) {
      double th = 2.0*DPI*(p-16)*a/60.0;
      HC[2*(CO.WC1 + (size_t)p*60 + a)]   = (float)cos(th);
      HC[2*(CO.WC1 + (size_t)p*60 + a)+1] = (float)sin(th);
    }
  for (int p = 0; p < 17; p++)
    for (int a = 0; a < 34; a++) {
      double th = 2.0*DPI*(p-8)*a/34.0;
      HC[2*(CO.WC2 + (size_t)p*34 + a)]   = (float)cos(th);
      HC[2*(CO.WC2 + (size_t)p*34 + a)+1] = (float)sin(th);
    }
  for (int j = 0; j < 6; j++) HF[CO.WInt + j] = (float)(w3[j]/36.0);

  size_t fb  = CO.nF * sizeof(float);
  size_t fbA = al256(fb);
  size_t cb  = CO.nC * sizeof(float2);
  size_t cbA = al256(cb);
  size_t ib  = HI.size() * sizeof(int);
  void* base = nullptr;
  if (hipMalloc(&base, fbA + cbA + ib) != hipSuccess || !base) return;
  if (hipMemcpy(base, HF.data(), fb, hipMemcpyHostToDevice) != hipSuccess) return;
  if (hipMemcpy((char*)base + fbA, HC.data(), cb, hipMemcpyHostToDevice) != hipSuccess) return;
  if (hipMemcpy((char*)base + fbA + cbA, HI.data(), ib, hipMemcpyHostToDevice) != hipSuccess) return;
  (void)hipDeviceSynchronize();
  g_devF = (float*)base;
  g_devC = (float2*)((char*)base + fbA);
  g_devI = (int*)((char*)base + fbA + cbA);
}
namespace { struct InitOnce { InitOnce(){ build_all(); } } g_once; }

// ============================================================================
// Device helpers
// ============================================================================
__device__ __forceinline__ int OQ(int l) { return l*(4*l*l - 1)/3; }
__device__ __forceinline__ int lFromQ(int q, int L) {
  int l = 0;
  while (l+1 < L && OQ(l+1) <= q) l++;
  return l;
}
__device__ __forceinline__ int lsq(int q) {
  int l = (int)sqrtf((float)q);
  while ((l+1)*(l+1) <= q) l++;
  while (l*l > q) l--;
  return l;
}
__device__ __forceinline__ void rotf(float2& r, float2 s) {
  float t = r.x*s.x - r.y*s.y;
  r.y = r.x*s.y + r.y*s.x;
  r.x = t;
}

// ---------------- fused kernel-FT (all 5 layers, one dispatch) -------------
__device__ __forceinline__ void kh_so3_one(int id, int L, int fi, int fo,
    const float* __restrict__ kk, const float2* __restrict__ F, float2* __restrict__ kh)
{
  int ff = fi*fo;
  int q = id / ff, r = id - q*ff;
  int i = r / fo, o = r - i*fo;
  int l = lFromQ(q, L); int W = 2*l+1; int W21 = W*W;
  int rem = q - OQ(l);
  const float2* Fb = F + 36ull*OQ(l) + rem;
  const float* kb = kk + (size_t)(i*fo + o)*36;
  float ax = 0.f, ay = 0.f;
  for (int p = 0; p < 36; p++) {
    float kv = kb[p];
    float2 f = Fb[(size_t)p*W21];
    ax += kv*f.x; ay += kv*f.y;
  }
  kh[(size_t)q*ff + r] = make_float2(ax, ay);
}

__global__ __launch_bounds__(256) void k_kh_all(
    const float* __restrict__ ks2, const float* __restrict__ k1,
    const float* __restrict__ k2,  const float* __restrict__ k3,
    const float* __restrict__ k4,
    const float2* __restrict__ Fs2, const float2* __restrict__ Fso3,
    float2* __restrict__ kh1, float2* __restrict__ kh2, float2* __restrict__ kh3,
    float2* __restrict__ kh4, float2* __restrict__ kh5)
{
  int id = blockIdx.x*256 + threadIdx.x;
  if (id < 1800) {
    int q = id >> 1, o = id & 1;
    int l = lsq(q); int W = 2*l+1; int mi = q - l*l;
    const float2* Fb = Fs2 + 6ull*l*l;
    float ax = 0.f, ay = 0.f;
    for (int p = 0; p < 6; p++) {
      float kv = ks2[o*6 + p];
      float2 f = Fb[p*W + mi];
      ax += kv*f.x; ay += kv*f.y;
    }
    kh1[(size_t)q*2 + o] = make_float2(ax, ay);
    return;
  }
  id -= 1800;
  if (id < OQh(17)*10) { kh_so3_one(id, 17, 2, 5, k1, Fso3, kh2); return; }
  id -= OQh(17)*10;
  if (id < OQh(9)*60) { kh_so3_one(id, 9, 5, 12, k2, Fso3, kh3); return; }
  id -= OQh(9)*60;
  if (id < OQh(5)*336) { kh_so3_one(id, 5, 12, 28, k3, Fso3, kh4); return; }
  id -= OQh(5)*336;
  if (id < OQh(3)*1792) { kh_so3_one(id, 3, 28, 64, k4, Fso3, kh5); return; }
}

// ---------------- stage-1 analysis: alpha DFT ----------------
__global__ __launch_bounds__(64) void k_s1_fftA(
    const float* __restrict__ x, const float2* __restrict__ tw, float2* __restrict__ XF1)
{
  __shared__ float row[60];
  int b = blockIdx.x / 60, j = blockIdx.x - b*60;
  int t = threadIdx.x;
  if (t < 60) row[t] = x[((size_t)b*60 + j)*60 + t];
  __syncthreads();
  if (t < 30) {
    float ax = 0.f, ay = 0.f;
    int ti = 0;
    for (int a = 0; a < 60; a++) {
      float2 w = tw[ti];
      ax += row[a]*w.x; ay -= row[a]*w.y;
      ti += t; if (ti >= 60) ti -= 60;
    }
    XF1[((size_t)b*60 + j)*30 + t] = make_float2(ax, ay);
  }
}

// ---------------- stage-1 beta contraction ----------------
__global__ __launch_bounds__(256) void k_s1_coef(
    const float2* __restrict__ XF1, const float* __restrict__ dA1, float2* __restrict__ xh1)
{
  int id = blockIdx.x*blockDim.x + threadIdx.x;
  if (id >= 32*900) return;
  int b = id / 900, q = id - b*900;
  int l = lsq(q); int W = 2*l+1; int mi = q - l*l; int m = mi - l;
  const float* dp = dA1 + 60ull*l*l + mi;
  const float2* xb = XF1 + (size_t)b*60*30;
  int ma = m >= 0 ? m : -m;
  float sg = m >= 0 ? 1.f : -1.f;
  float ax = 0.f, ay = 0.f;
  for (int j = 0; j < 60; j++) {
    float2 xf = xb[j*30 + ma];
    float d = dp[(size_t)j*W];
    ax += d*xf.x; ay += sg*d*xf.y;
  }
  xh1[id] = make_float2(ax, ay);
}

// ---------------- generic spectral product -> transposed yh ----------------
__global__ __launch_bounds__(256) void k_yh_t(
    const float2* __restrict__ xh, const float2* __restrict__ kh,
    float2* __restrict__ yht, int L, int fi, int fo, int Qtot)
{
  int id = blockIdx.x*256 + threadIdx.x;
  int BOF = 32*fo;
  if (id >= Qtot*BOF) return;
  int q = id / BOF, bo = id - q*BOF;
  int b = bo / fo, o = bo - b*fo;
  int l = lFromQ(q, L); int W = 2*l+1;
  int rem = q - OQ(l); int mi = rem / W, ni = rem - mi*W;
  int ff = fi*fo;
  const float2* xb = xh + ((size_t)b*fi)*Qtot + OQ(l) + mi*W;
  const float2* kb = kh + ((size_t)(OQ(l) + ni*W))*ff + o;
  float ax = 0.f, ay = 0.f;
  for (int i = 0; i < fi; i++) {
    const float2* xrow = xb + (size_t)i*Qtot;
    const float2* krow = kb + (size_t)i*fo;
    for (int k = 0; k < W; k++) {
      float2 xv = xrow[k];
      float2 kv = krow[(size_t)k*ff];
      ax += xv.x*kv.x + xv.y*kv.y;
      ay += xv.y*kv.x - xv.x*kv.y;
    }
  }
  yht[id] = make_float2(ax, ay);
}

// ============================================================================
// k_scatA: fused Wigner scatter + radix-2 alpha-iDFT.
// Stage 1 computes yh on the fly (rank-1: xh1 x conj(kh1)); stage 2 reads yht.
// One wave per block; P tile + twiddles in LDS.
// ============================================================================
template<int BQ, int NJ, int BO, int CHSL, int STAGE1>
__global__ __launch_bounds__(64) void k_scatA(
    const float2* __restrict__ src,     // STAGE1: xh1 ; else yht [e][BO]
    const float2* __restrict__ khp,     // STAGE1 only
    const float* __restrict__ dT, const int* __restrict__ toff,
    const float2* __restrict__ twN, float2* __restrict__ Tm, int slBase)
{
  constexpr int W2 = 2*BQ - 1;
  constexpr int N  = 2*BQ;
  constexpr int NAH = BQ;             // N/2
  __shared__ float2 P[W2*64];
  __shared__ float2 twl[N];
  __shared__ float2 kc[STAGE1 ? 2*BQ : 2];
  const int lane = threadIdx.x;
  constexpr int TILES = CHSL/64;
  int n = blockIdx.x / TILES, ts = blockIdx.x - n*TILES;
  int slL = ts*64 + lane;
  int slG = slBase + slL;
  int bo = slG / NJ;
  int j  = slG - bo*NJ;

  if (lane < N) twl[lane] = twN[lane];
  if constexpr (STAGE1) {
    int cnt = 2*(BQ - n);
    if (lane < cnt) {
      int l = n + (lane >> 1), o = lane & 1;
      kc[2*l + o] = khp[(size_t)(l*l + n + l)*2 + o];
    }
  }
  __syncthreads();

  // ---- phase A: scatter (n >= 0 Hermitian half)
  for (int pm = 0; pm < W2; pm++) {
    int m = pm - (BQ-1);
    int am = m < 0 ? -m : m;
    int lmin = am > n ? am : n;
    int K = BQ - lmin;
    int tof = toff[pm*BQ + n];
    const float* dp = dT + (size_t)tof*NJ + j;
    float ax = 0.f, ay = 0.f;
    if constexpr (STAGE1) {
      int b = bo >> 1, o = bo & 1;
      const float2* xb = src + (size_t)b*900;
      for (int li = 0; li < K; li++) {
        int l = lmin + li;
        float d = dp[(size_t)li*NJ];
        float2 xv = xb[l*l + m + l];
        float2 kv = kc[2*l + o];
        float yx = xv.x*kv.x + xv.y*kv.y;
        float yy = xv.y*kv.x - xv.x*kv.y;
        ax = fmaf(d, yx, ax); ay = fmaf(d, yy, ay);
      }
    } else {
      for (int li = 0; li < K; li++) {
        int l = lmin + li;
        int e = OQ(l) + (m+l)*(2*l+1) + (n+l);
        float d = dp[(size_t)li*NJ];
        float2 y = src[(size_t)e*BO + bo];
        ax = fmaf(d, y.x, ax); ay = fmaf(d, y.y, ay);
      }
    }
    P[pm*64 + lane] = make_float2(ax, ay);
  }
  __syncthreads();

  // ---- phase B: radix-2 alpha-iDFT, T[a] = E+O, T[a+NAH] = +/-(E-O)
  float2 E[NAH], Od[NAH];
  #pragma unroll
  for (int a = 0; a < NAH; a++) { E[a] = make_float2(0.f,0.f); Od[a] = make_float2(0.f,0.f); }
  for (int t2 = 0; t2 < BQ; t2++) {            // even pm = 2*t2
    int pm = 2*t2;
    float2 p = P[pm*64 + lane];
    int s = pm - (BQ-1); if (s < 0) s += N;
    int idx = 0;
    #pragma unroll
    for (int a = 0; a < NAH; a++) {
      float2 w = twl[idx];
      E[a].x = fmaf(p.x, w.x, fmaf(-p.y, w.y, E[a].x));
      E[a].y = fmaf(p.x, w.y, fmaf( p.y, w.x, E[a].y));
      idx += s; if (idx >= N) idx -= N;
    }
  }
  for (int t2 = 0; t2 < BQ-1; t2++) {          // odd pm = 2*t2+1
    int pm = 2*t2 + 1;
    float2 p = P[pm*64 + lane];
    int s = pm - (BQ-1); if (s < 0) s += N;
    int idx = 0;
    #pragma unroll
    for (int a = 0; a < NAH; a++) {
      float2 w = twl[idx];
      Od[a].x = fmaf(p.x, w.x, fmaf(-p.y, w.y, Od[a].x));
      Od[a].y = fmaf(p.x, w.y, fmaf( p.y, w.x, Od[a].y));
      idx += s; if (idx >= N) idx -= N;
    }
  }
  constexpr bool QS = ((BQ-1) & 1) != 0;   // true (st1): T[a+NAH]=O-E ; false (st2): E-O
  #pragma unroll
  for (int a = 0; a < NAH; a++) {
    float2 tp = make_float2(E[a].x + Od[a].x, E[a].y + Od[a].y);
    float2 tq = QS ? make_float2(Od[a].x - E[a].x, Od[a].y - E[a].y)
                   : make_float2(E[a].x - Od[a].x, E[a].y - Od[a].y);
    Tm[((size_t)a*BQ + n)*CHSL + slL] = tp;
    Tm[((size_t)(a+NAH)*BQ + n)*CHSL + slL] = tq;
  }
}

// ============================================================================
// k_dftB: Hermitian gamma fold (radix-2 over c) + ReLU + gamma fwd DFT
// (radix-2 over k parity). Block owns (a, sl-tile).
// ============================================================================
template<int BQ, int KT, int CHSL>
__global__ __launch_bounds__(64) void k_dftB(
    const float2* __restrict__ Tm, const float2* __restrict__ Wn,
    const float2* __restrict__ Wg, float2* __restrict__ U)
{
  constexpr int N = 2*BQ;
  constexpr int NH = BQ;
  __shared__ float2 WnL[BQ*NH];     // [n][c<NH]
  __shared__ float2 WgL[NH*KT];     // [c<NH][k]
  constexpr int TILES = CHSL/64;
  int a = blockIdx.x / TILES, ts = blockIdx.x - a*TILES;
  int lane = threadIdx.x;
  for (int i = lane; i < BQ*NH; i += 64) { int nn = i/NH, c = i - nn*NH; WnL[i] = Wn[(size_t)nn*N + c]; }
  for (int i = lane; i < NH*KT; i += 64) WgL[i] = Wg[i];
  __syncthreads();
  int sl = ts*64 + lane;
  float SE[NH], SO[NH];
  #pragma unroll
  for (int c = 0; c < NH; c++) { SE[c] = 0.f; SO[c] = 0.f; }
  const float2* Tb = Tm + (size_t)a*BQ*CHSL + sl;
  for (int t2 = 0; 2*t2 < BQ; t2++) {          // even n
    int nn = 2*t2;
    float2 tv = Tb[(size_t)nn*CHSL];
    #pragma unroll
    for (int c = 0; c < NH; c++) {
      float2 w = WnL[nn*NH + c];
      SE[c] = fmaf(tv.x, w.x, fmaf(-tv.y, w.y, SE[c]));
    }
  }
  for (int t2 = 0; 2*t2+1 < BQ; t2++) {        // odd n
    int nn = 2*t2 + 1;
    float2 tv = Tb[(size_t)nn*CHSL];
    #pragma unroll
    for (int c = 0; c < NH; c++) {
      float2 w = WnL[nn*NH + c];
      SO[c] = fmaf(tv.x, w.x, fmaf(-tv.y, w.y, SO[c]));
    }
  }
  #pragma unroll
  for (int c = 0; c < NH; c++) {
    float s0 = fmaxf(SE[c] + SO[c], 0.f);      // S[c]
    float s1 = fmaxf(SE[c] - SO[c], 0.f);      // S[c+NH]
    SE[c] = s0 + s1;                            // P+
    SO[c] = s0 - s1;                            // P-
  }
  float2* Ub = U + (size_t)a*KT*CHSL + sl;
  for (int k = 0; k < KT; k += 2) {            // even k
    float ux = 0.f, uy = 0.f;
    #pragma unroll
    for (int c = 0; c < NH; c++) {
      float2 w = WgL[c*KT + k];
      ux = fmaf(SE[c], w.x, ux); uy = fmaf(SE[c], w.y, uy);
    }
    Ub[(size_t)k*CHSL] = make_float2(ux, uy);
  }
  for (int k = 1; k < KT; k += 2) {            // odd k
    float ux = 0.f, uy = 0.f;
    #pragma unroll
    for (int c = 0; c < NH; c++) {
      float2 w = WgL[c*KT + k];
      ux = fmaf(SO[c], w.x, ux); uy = fmaf(SO[c], w.y, uy);
    }
    Ub[(size_t)k*CHSL] = make_float2(ux, uy);
  }
}

// ============================================================================
// k_dftC: alpha fwd DFT (radix-2 over a). Block owns (k, sl-tile).
// ============================================================================
template<int MT, int KT, int NH, int CHSL>
__global__ __launch_bounds__(64) void k_dftC(
    const float2* __restrict__ U, const float2* __restrict__ WC,
    float2* __restrict__ xt, int slOff, int SLfull)
{
  constexpr int NA = 2*NH;
  __shared__ float2 WcL[NH*MT];      // [a<NH][p]
  constexpr int TILES = CHSL/64;
  int k = blockIdx.x / TILES, ts = blockIdx.x - k*TILES;
  int lane = threadIdx.x;
  for (int i = lane; i < NH*MT; i += 64) { int aa = i/MT, p = i - aa*MT; WcL[i] = WC[(size_t)p*NA + aa]; }
  __syncthreads();
  int sl = ts*64 + lane;
  float2 acc[MT];
  #pragma unroll
  for (int p = 0; p < MT; p++) acc[p] = make_float2(0.f, 0.f);
  const float2* Ubk = U + (size_t)k*CHSL + sl;
  for (int aa = 0; aa < NH; aa++) {
    float2 u  = Ubk[(size_t)aa*KT*CHSL];
    float2 u2 = Ubk[(size_t)(aa+NH)*KT*CHSL];
    float2 vp = make_float2(u.x + u2.x, u.y + u2.y);
    float2 vm = make_float2(u.x - u2.x, u.y - u2.y);
    const float2* wr = &WcL[aa*MT];
    #pragma unroll
    for (int p = 0; p < MT; p++) {
      float2 w = wr[p];
      float2 v = (p & 1) ? vm : vp;
      acc[p].x = fmaf(v.x, w.x, fmaf( v.y, w.y, acc[p].x));
      acc[p].y = fmaf(v.y, w.x, fmaf(-v.x, w.y, acc[p].y));
    }
  }
  #pragma unroll
  for (int p = 0; p < MT; p++)
    xt[((size_t)(p*KT + k))*SLfull + slOff + sl] = acc[p];
}

// ============================================================================
// k_coefg: beta contraction as pidx-row-block GEMM with LDS-staged xt row.
// ============================================================================
template<int NBI, int NJ, int PAD, int QTOT>
__global__ __launch_bounds__(256) void k_coefg(
    const float2* __restrict__ xt, const float* __restrict__ dAT,
    const int* __restrict__ qoff, const int* __restrict__ qlist,
    float2* __restrict__ xh, int SLfull)
{
  __shared__ float re[NBI*PAD], im[NBI*PAD];
  int pr = blockIdx.x;
  const float2* row = xt + (size_t)pr*SLfull;
  for (int idx = threadIdx.x; idx < NBI*NJ; idx += 256) {
    int bi = idx / NJ, j = idx - bi*NJ;
    float2 v = row[idx];
    re[bi*PAD + j] = v.x; im[bi*PAD + j] = v.y;
  }
  __syncthreads();
  int o0 = qoff[pr], nq = qoff[pr+1] - o0;
  int w = threadIdx.x >> 6, lane = threadIdx.x & 63;
  for (int i = w; i < nq; i += 4) {
    int e = qlist[o0 + i];
    int q = e >> 1;
    float sg = (e & 1) ? -1.f : 1.f;
    const float* dp = dAT + (size_t)q*NJ;
    for (int bi = lane; bi < NBI; bi += 64) {
      float ax = 0.f, ay = 0.f;
      const float* rr = &re[bi*PAD];
      const float* ii = &im[bi*PAD];
      #pragma unroll 4
      for (int j = 0; j < NJ; j++) {
        float d = dp[j];
        ax = fmaf(d, rr[j], ax);
        ay = fmaf(d, ii[j], ay);
      }
      xh[(size_t)bi*QTOT + q] = make_float2(ax, sg*ay);
    }
  }
}

// ---------------- old-layout beta contraction (stages 4,5) -----------------
__global__ __launch_bounds__(256) void k_coef(
    const float2* __restrict__ xt, const float* __restrict__ dA,
    float2* __restrict__ xh, int L, int nj, int KT, int MT, int Qtot, int nbi)
{
  int id = blockIdx.x*blockDim.x + threadIdx.x;
  if (id >= nbi*Qtot) return;
  int bi = id / Qtot, q = id - bi*Qtot;
  int l = lFromQ(q, L); int W = 2*l+1; int W21 = W*W;
  int rem = q - OQ(l); int mi = rem / W, ki = rem - mi*W;
  int m = mi - l, ks = ki - l;
  const float* dAp = dA + (size_t)nj*OQ(l) + rem;
  int MTKT = MT*KT;
  int pidx; float sgn;
  if (ks >= 0) { pidx = (m + (KT-1))*KT + ks;  sgn =  1.f; }
  else         { pidx = (-m + (KT-1))*KT - ks; sgn = -1.f; }
  const float2* xb = xt + (size_t)bi*nj*MTKT + pidx;
  float ax = 0.f, ay = 0.f;
  for (int j = 0; j < nj; j++) {
    float2 xv = xb[(size_t)j*MTKT];
    float d = dAp[(size_t)j*W21];
    ax += d*xv.x; ay += sgn*d*xv.y;
  }
  xh[id] = make_float2(ax, ay);
}

// ============================================================================
// Old fused synthesis (stages 3-5; tiny FLOP). yh read is transposed [e][bo].
// ============================================================================
template<int BQ, int N, int KT, int MT, int TPB, int BO>
__global__ __launch_bounds__(TPB) void k_synth3(
    const float2* __restrict__ yh, const float* __restrict__ dS,
    const float2* __restrict__ twN, float2* __restrict__ xt)
{
  constexpr int W2  = 2*BQ - 1;
  constexpr int NH  = N/2;
  constexpr int CP  = (BQ+3) & ~3;
  constexpr int KTP = (KT+1) & ~1;
  constexpr int R3  = (N%4 == 0) ? 4 : 2;
  constexpr int RP  = (NH%2 == 0) ? 2 : 1;
  constexpr int SZA0 = (W2*CP*8 > 2*N*NH*4) ? W2*CP*8 : 2*N*NH*4;
  constexpr int SZA  = (SZA0 + 15) & ~15;
  constexpr int SZB0 = (N*CP*8 > 2*NH*KTP*8) ? N*CP*8 : 2*NH*KTP*8;
  constexpr int SZB  = (SZB0 + 15) & ~15;
  __shared__ __align__(16) char smem[SZA + SZB + N*8];
  float2* P   = (float2*)smem;
  float*  SS  = (float*)smem;
  float*  SD  = SS + N*NH;
  float2* Tm  = (float2*)(smem + SZA);
  float2* USS = (float2*)(smem + SZA);
  float2* USD = USS + NH*KTP;
  float2* twl = (float2*)(smem + SZA + SZB);

  const int tid = threadIdx.x;
  int nwg = gridDim.x, bidx = blockIdx.x;
  int per = nwg >> 3;
  int swz = (bidx & 7)*per + (bidx >> 3);
  int bo = swz / N, j = swz - bo*N;

  for (int t = tid; t < N; t += TPB) twl[t] = twN[t];

  for (int idx = tid; idx < W2*CP; idx += TPB) {
    int pm = idx / CP, n = idx - pm*CP;
    float ax = 0.f, ay = 0.f;
    if (n < BQ) {
      int m = pm - (BQ-1);
      int am = m < 0 ? -m : m;
      int lmin = am > n ? am : n;
      int base = lmin*(4*lmin*lmin - 1)/3;
      for (int l = lmin; l < BQ; l++) {
        int Wl = 2*l+1;
        int e = base + (m+l)*Wl + (n+l);
        float2 y = yh[(size_t)e*BO + bo];
        float d = dS[(size_t)N*base + (size_t)j*Wl*Wl + (m+l)*Wl + (n+l)];
        ax += d*y.x; ay += d*y.y;
        base += Wl*Wl;
      }
    }
    P[idx] = make_float2(ax, ay);
  }
  __syncthreads();

  {
    constexpr int CG = CP/4;
    constexpr float SGN = ((BQ-1) & 1) ? -1.f : 1.f;
    const float4* P4 = (const float4*)P;
    for (int it = tid; it < NH*CG; it += TPB) {
      int a = it / CG, cg = it - a*CG;
      float2 s2 = twl[2*a];
      float2 r = make_float2(1.f, 0.f);
      float4 E0 = {0,0,0,0}, E1 = {0,0,0,0}, O0 = {0,0,0,0}, O1 = {0,0,0,0};
      for (int jj = 0; jj < BQ-1; jj++) {
        float4 e0 = P4[(2*jj)*(CP/2) + 2*cg];
        float4 e1 = P4[(2*jj)*(CP/2) + 2*cg + 1];
        float4 o0 = P4[(2*jj+1)*(CP/2) + 2*cg];
        float4 o1 = P4[(2*jj+1)*(CP/2) + 2*cg + 1];
        E0.x += e0.x*r.x - e0.y*r.y; E0.y += e0.x*r.y + e0.y*r.x;
        E0.z += e0.z*r.x - e0.w*r.y; E0.w += e0.z*r.y + e0.w*r.x;
        E1.x += e1.x*r.x - e1.y*r.y; E1.y += e1.x*r.y + e1.y*r.x;
        E1.z += e1.z*r.x - e1.w*r.y; E1.w += e1.z*r.y + e1.w*r.x;
        O0.x += o0.x*r.x - o0.y*r.y; O0.y += o0.x*r.y + o0.y*r.x;
        O0.z += o0.z*r.x - o0.w*r.y; O0.w += o0.z*r.y + o0.w*r.x;
        O1.x += o1.x*r.x - o1.y*r.y; O1.y += o1.x*r.y + o1.y*r.x;
        O1.z += o1.z*r.x - o1.w*r.y; O1.w += o1.z*r.y + o1.w*r.x;
        rotf(r, s2);
      }
      {
        float4 e0 = P4[(2*(BQ-1))*(CP/2) + 2*cg];
        float4 e1 = P4[(2*(BQ-1))*(CP/2) + 2*cg + 1];
        E0.x += e0.x*r.x - e0.y*r.y; E0.y += e0.x*r.y + e0.y*r.x;
        E0.z += e0.z*r.x - e0.w*r.y; E0.w += e0.z*r.y + e0.w*r.x;
        E1.x += e1.x*r.x - e1.y*r.y; E1.y += e1.x*r.y + e1.y*r.x;
        E1.z += e1.z*r.x - e1.w*r.y; E1.w += e1.z*r.y + e1.w*r.x;
      }
      float2 wa = twl[a];
      int pidx = (N - (a*(BQ-1)) % N) % N;
      float2 ph = twl[pidx];
      int c0 = 4*cg;
      auto doCol = [&](float ex, float ey, float ox, float oy, int col) {
        float gx = ox*wa.x - oy*wa.y, gy = ox*wa.y + oy*wa.x;
        float px = ex + gx, py = ey + gy;
        float qx = ex - gx, qy = ey - gy;
        Tm[a*CP + col]        = make_float2(px*ph.x - py*ph.y, px*ph.y + py*ph.x);
        Tm[(a+NH)*CP + col]   = make_float2(SGN*(qx*ph.x - qy*ph.y), SGN*(qx*ph.y + qy*ph.x));
      };
      doCol(E0.x, E0.y, O0.x, O0.y, c0+0);
      doCol(E0.z, E0.w, O0.z, O0.w, c0+1);
      doCol(E1.x, E1.y, O1.x, O1.y, c0+2);
      doCol(E1.z, E1.w, O1.z, O1.w, c0+3);
    }
  }
  __syncthreads();

  {
    constexpr int NO3 = BQ/2;
    constexpr int NRG = N/R3;
    for (int it = tid; it < NRG*NH; it += TPB) {
      int rg = it / NH, c = it - rg*NH;
      int a0 = rg*R3;
      float2 se = twl[2*c];
      float2 re = make_float2(1.f, 0.f);
      float2 ro = twl[c];
      float er[R3], orr[R3];
      #pragma unroll
      for (int rr = 0; rr < R3; rr++) { er[rr] = 0.f; orr[rr] = 0.f; }
      for (int jj = 0; jj < NO3; jj++) {
        #pragma unroll
        for (int rr = 0; rr < R3; rr++) {
          float4 tv = *(const float4*)&Tm[(a0+rr)*CP + 2*jj];
          er[rr]  += tv.x*re.x - tv.y*re.y;
          orr[rr] += tv.z*ro.x - tv.w*ro.y;
        }
        rotf(re, se); rotf(ro, se);
      }
      if constexpr ((BQ & 1) != 0) {
        #pragma unroll
        for (int rr = 0; rr < R3; rr++) {
          float2 tv = Tm[(a0+rr)*CP + (BQ-1)];
          er[rr] += tv.x*re.x - tv.y*re.y;
        }
      }
      #pragma unroll
      for (int rr = 0; rr < R3; rr++) {
        float t0x = Tm[(a0+rr)*CP].x;
        float s0 = fmaxf(2.f*(er[rr] + orr[rr]) - t0x, 0.f);
        float s1 = fmaxf(2.f*(er[rr] - orr[rr]) - t0x, 0.f);
        SS[(a0+rr)*NH + c] = s0 + s1;
        SD[(a0+rr)*NH + c] = s0 - s1;
      }
    }
  }
  __syncthreads();

  {
    for (int it = tid; it < (NH/RP)*KT; it += TPB) {
      int g = it / KT, k = it - g*KT;
      int a0 = g*RP;
      const float* Sp = (k & 1) ? SD : SS;
      float2 st = twl[k]; st.y = -st.y;
      float2 r = make_float2(1.f, 0.f);
      float ux[2*RP], uy[2*RP];
      #pragma unroll
      for (int q2 = 0; q2 < 2*RP; q2++) { ux[q2] = 0.f; uy[q2] = 0.f; }
      for (int c = 0; c < NH; c++) {
        #pragma unroll
        for (int pp = 0; pp < RP; pp++) {
          float sl = Sp[(a0+pp)*NH + c];
          float sh = Sp[(a0+pp+NH)*NH + c];
          ux[2*pp]   += sl*r.x; uy[2*pp]   += sl*r.y;
          ux[2*pp+1] += sh*r.x; uy[2*pp+1] += sh*r.y;
        }
        rotf(r, st);
      }
      #pragma unroll
      for (int pp = 0; pp < RP; pp++) {
        USS[(a0+pp)*KTP + k] = make_float2(ux[2*pp] + ux[2*pp+1], uy[2*pp] + uy[2*pp+1]);
        USD[(a0+pp)*KTP + k] = make_float2(ux[2*pp] - ux[2*pp+1], uy[2*pp] - uy[2*pp+1]);
      }
    }
  }
  __syncthreads();

  {
    float2* xtb = xt + ((size_t)bo*N + j)*(MT*KT);
    constexpr int KG = KTP/2;
    for (int it = tid; it < MT*KG; it += TPB) {
      int pm2 = it / KG, kg = it - pm2*KG;
      int m = pm2 - (KT-1);
      int mm = m < 0 ? m + N : m;
      const float2* Up = (m & 1) ? USD : USS;
      float2 st = twl[mm];
      float2 r = make_float2(1.f, 0.f);
      float a0x = 0.f, a0y = 0.f, a1x = 0.f, a1y = 0.f;
      for (int a = 0; a < NH; a++) {
        float4 u = *(const float4*)&Up[a*KTP + 2*kg];
        a0x += u.x*r.x + u.y*r.y;  a0y += u.y*r.x - u.x*r.y;
        a1x += u.z*r.x + u.w*r.y;  a1y += u.w*r.x - u.z*r.y;
        rotf(r, st);
      }
      int k0 = 2*kg;
      xtb[pm2*KT + k0] = make_float2(a0x, a0y);
      if (k0 + 1 < KT) xtb[pm2*KT + k0 + 1] = make_float2(a1x, a1y);
    }
  }
}

template<int BQ, int N, int KT, int MT, int INTEG, int NPAIR, int TPB, int BO>
__global__ __launch_bounds__(TPB) void k_synth2(
    const float2* __restrict__ yh, const float* __restrict__ dS,
    const float2* __restrict__ twN, const float2* __restrict__ Wn2,
    const float2* __restrict__ Wg, float2* __restrict__ xt,
    float* __restrict__ s5p, const float* __restrict__ wInt)
{
  constexpr int W2 = 2*BQ - 1;
  constexpr int SZA = (((W2*BQ*8 > N*N*4) ? W2*BQ*8 : N*N*4) + 15) & ~15;
  constexpr int SZB0 = (N*BQ*8 > N*KT*8) ? N*BQ*8 : N*KT*8;
  constexpr int SZB1 = (SZB0 > TPB*4) ? SZB0 : TPB*4;
  constexpr int SZB = (SZB1 + 15) & ~15;
  __shared__ __align__(16) char smem[SZA + SZB + N*8];
  float2* P   = (float2*)smem;
  float*  S   = (float*)smem;
  float2* Tm  = (float2*)(smem + SZA);
  float2* U   = (float2*)(smem + SZA);
  float*  red = (float*)(smem + SZA);
  float2* twl = (float2*)(smem + SZA + SZB);

  const int tid = threadIdx.x;
  int bidx = blockIdx.x, nwg = gridDim.x;
  int per = nwg >> 3;
  int swz = (bidx & 7)*per + (bidx >> 3);
  int bo = swz / N, j = swz - bo*N;

  for (int t = tid; t < N; t += TPB) twl[t] = twN[t];
  __syncthreads();

  for (int idx = tid; idx < W2*BQ; idx += TPB) {
    int pm = idx / BQ, n = idx - pm*BQ;
    int m = pm - (BQ-1);
    int am = m < 0 ? -m : m;
    int lmin = am > n ? am : n;
    int base = lmin*(4*lmin*lmin - 1)/3;
    float ax = 0.f, ay = 0.f;
    for (int l = lmin; l < BQ; l++) {
      int Wl = 2*l+1;
      int e = base + (m+l)*Wl + (n+l);
      float2 y = yh[(size_t)e*BO + bo];
      float d = dS[(size_t)N*base + (size_t)j*Wl*Wl + (m+l)*Wl + (n+l)];
      ax += d*y.x; ay += d*y.y;
      base += Wl*Wl;
    }
    P[idx] = make_float2(ax, ay);
  }
  __syncthreads();

  for (int idx = tid; idx < (N/2)*BQ; idx += TPB) {
    int ag = idx / BQ, n = idx - ag*BQ;
    int a0 = 2*ag, a1 = a0 + 1;
    int t0 = (N - (a0*(BQ-1)) % N) % N;
    int t1 = (N - (a1*(BQ-1)) % N) % N;
    float2 A0 = {0,0}, A1 = {0,0};
    for (int pm = 0; pm < W2; pm++) {
      float2 p = P[pm*BQ + n];
      float2 w0 = twl[t0], w1 = twl[t1];
      A0.x += p.x*w0.x - p.y*w0.y; A0.y += p.x*w0.y + p.y*w0.x;
      A1.x += p.x*w1.x - p.y*w1.y; A1.y += p.x*w1.y + p.y*w1.x;
      t0 += a0; if (t0 >= N) t0 -= N;
      t1 += a1; if (t1 >= N) t1 -= N;
    }
    Tm[a0*BQ + n] = A0;
    Tm[a1*BQ + n] = A1;
  }
  __syncthreads();

  {
    constexpr int CG = N/2;
    const float4* WnR = (const float4*)Wn2;
    for (int idx = tid; idx < N*CG; idx += TPB) {
      int a = idx / CG, cg = idx - a*CG;
      float s0 = 0.f, s1 = 0.f;
      const float2* TmA = Tm + a*BQ;
      for (int n = 0; n < BQ; n++) {
        float2 T = TmA[n];
        float4 w = WnR[n*CG + cg];
        s0 += T.x*w.x - T.y*w.y;
        s1 += T.x*w.z - T.y*w.w;
      }
      s0 = fmaxf(s0, 0.f); s1 = fmaxf(s1, 0.f);
      *(float2*)&S[a*N + 2*cg] = make_float2(s0, s1);
    }
  }
  __syncthreads();

  if constexpr (!INTEG) {
    for (int idx = tid; idx < (N/2)*KT; idx += TPB) {
      int ag = idx / KT, k = idx - ag*KT;
      int a0 = 2*ag, a1 = a0 + 1;
      float u0x=0.f,u0y=0.f,u1x=0.f,u1y=0.f;
      const float* S0 = S + a0*N;
      const float* S1 = S + a1*N;
      for (int c = 0; c < N; c++) {
        float2 w = Wg[c*KT + k];
        u0x += S0[c]*w.x; u0y += S0[c]*w.y;
        u1x += S1[c]*w.x; u1y += S1[c]*w.y;
      }
      U[a0*KT + k] = make_float2(u0x, u0y);
      U[a1*KT + k] = make_float2(u1x, u1y);
    }
    __syncthreads();

    float2* xtb = xt + ((size_t)bo*N + j)*(MT*KT);
    for (int idx = tid; idx < MT*KT; idx += TPB) {
      int pm2 = idx / KT, k = idx - pm2*KT;
      int m = pm2 - (KT-1);
      float ax = 0.f, ay = 0.f;
      int t = 0;
      for (int a = 0; a < N; a++) {
        float2 u = U[a*KT + k];
        float2 w = twl[t];
        ax += u.x*w.x + u.y*w.y;
        ay += u.y*w.x - u.x*w.y;
        t += m; if (t < 0) t += N; else if (t >= N) t -= N;
      }
      xtb[idx] = make_float2(ax, ay);
    }
  } else {
    float part = 0.f;
    for (int idx = tid; idx < N*N; idx += TPB) part += S[idx];
    red[tid] = part;
    __syncthreads();
    for (int off2 = TPB >> 1; off2 > 0; off2 >>= 1) {
      if (tid < off2) red[tid] += red[tid + off2];
      __syncthreads();
    }
    if (tid == 0) s5p[bo*N + j] = red[0]*wInt[j];
  }
}

// ---------------- head: integrate-reduce + 3x (batchnorm, linear) ----------
__global__ __launch_bounds__(256) void k_mlp(
    const float* __restrict__ s5p,
    const float* __restrict__ g1, const float* __restrict__ be1,
    const float* __restrict__ w1, const float* __restrict__ b1,
    const float* __restrict__ g2, const float* __restrict__ be2,
    const float* __restrict__ w2, const float* __restrict__ b2,
    const float* __restrict__ g3, const float* __restrict__ be3,
    const float* __restrict__ w3, const float* __restrict__ b3,
    float* __restrict__ out)
{
  __shared__ float A[2048], Bs[2048], C[1024], mu[64], iv[64];
  int tid = threadIdx.x;
  for (int idx = tid; idx < 2048; idx += 256) {
    float s = 0.f;
    #pragma unroll
    for (int j = 0; j < 6; j++) s += s5p[idx*6 + j];
    A[idx] = s;
  }
  __syncthreads();
  if (tid < 64) {
    float m = 0.f; for (int b = 0; b < 32; b++) m += A[b*64 + tid]; m *= (1.f/32);
    float v = 0.f; for (int b = 0; b < 32; b++) { float d = A[b*64+tid]-m; v += d*d; } v *= (1.f/32);
    mu[tid] = m; iv[tid] = rsqrtf(v + 1e-5f)*g1[tid];
  }
  __syncthreads();
  for (int idx = tid; idx < 2048; idx += 256) {
    int f = idx & 63;
    A[idx] = (A[idx]-mu[f])*iv[f] + be1[f];
  }
  __syncthreads();
  for (int idx = tid; idx < 2048; idx += 256) {
    int b = idx >> 6, fo = idx & 63;
    float s = b1[fo];
    for (int f = 0; f < 64; f++) s += A[b*64+f]*w1[f*64+fo];
    Bs[idx] = fmaxf(s, 0.f);
  }
  __syncthreads();
  if (tid < 64) {
    float m = 0.f; for (int b = 0; b < 32; b++) m += Bs[b*64+tid]; m *= (1.f/32);
    float v = 0.f; for (int b = 0; b < 32; b++) { float d = Bs[b*64+tid]-m; v += d*d; } v *= (1.f/32);
    mu[tid] = m; iv[tid] = rsqrtf(v + 1e-5f)*g2[tid];
  }
  __syncthreads();
  for (int idx = tid; idx < 2048; idx += 256) {
    int f = idx & 63;
    Bs[idx] = (Bs[idx]-mu[f])*iv[f] + be2[f];
  }
  __syncthreads();
  for (int idx = tid; idx < 1024; idx += 256) {
    int b = idx >> 5, fo = idx & 31;
    float s = b2[fo];
    for (int f = 0; f < 64; f++) s += Bs[b*64+f]*w2[f*32+fo];
    C[idx] = fmaxf(s, 0.f);
  }
  __syncthreads();
  if (tid < 32) {
    float m = 0.f; for (int b = 0; b < 32; b++) m += C[b*32+tid]; m *= (1.f/32);
    float v = 0.f; for (int b = 0; b < 32; b++) { float d = C[b*32+tid]-m; v += d*d; } v *= (1.f/32);
    mu[tid] = m; iv[tid] = rsqrtf(v + 1e-5f)*g3[tid];
  }
  __syncthreads();
  for (int idx = tid; idx < 1024; idx += 256) {
    int f = idx & 31;
    C[idx] = (C[idx]-mu[f])*iv[f] + be3[f];
  }
  __syncthreads();
  for (int idx = tid; idx < 320; idx += 256) {
    int b = idx/10, cc = idx - b*10;
    float s = b3[cc];
    for (int f = 0; f < 32; f++) s += C[b*32+f]*w3[f*10+cc];
    out[idx] = s;
  }
}

// ============================================================================
// launch
// ============================================================================
static inline int cdiv_h(int a, int b) { return (a + b - 1)/b; }

extern "C" void kernel_launch(void* const* d_in, const int* in_sizes, int n_in,
                              void* d_out, int out_size, void* d_ws, size_t ws_size,
                              hipStream_t stream) {
  (void)in_sizes; (void)n_in; (void)out_size;
  if (!g_devF || !g_devC || !g_devI || ws_size < WS_TOTAL) return;

  const float* x    = (const float*)d_in[0];
  const float* ks2  = (const float*)d_in[1];
  const float* k1   = (const float*)d_in[2];
  const float* k2   = (const float*)d_in[3];
  const float* k3   = (const float*)d_in[4];
  const float* k4   = (const float*)d_in[5];
  const float* g1   = (const float*)d_in[6],  *be1 = (const float*)d_in[7];
  const float* w1   = (const float*)d_in[8],  *b1  = (const float*)d_in[9];
  const float* g2   = (const float*)d_in[10], *be2 = (const float*)d_in[11];
  const float* w2   = (const float*)d_in[12], *b2  = (const float*)d_in[13];
  const float* g3   = (const float*)d_in[14], *be3 = (const float*)d_in[15];
  const float* w3   = (const float*)d_in[16], *b3  = (const float*)d_in[17];
  float* out = (float*)d_out;
  char* ws = (char*)d_ws;

  float2* XF1  = (float2*)(ws + WS_XF1);
  float2* xh1  = (float2*)(ws + WS_XH1);
  float2* kh1  = (float2*)(ws + WS_KH1);
  float2* xt2  = (float2*)(ws + WS_XT2);
  float2* xh2  = (float2*)(ws + WS_XH2);
  float2* kh2  = (float2*)(ws + WS_KH2);
  float2* yh2t = (float2*)(ws + WS_YH2T);
  float2* xt3  = (float2*)(ws + WS_XT3);
  float2* xh3  = (float2*)(ws + WS_XH3);
  float2* kh3  = (float2*)(ws + WS_KH3);
  float2* yh3t = (float2*)(ws + WS_YH3T);
  float2* xt4  = (float2*)(ws + WS_XT4);
  float2* xh4  = (float2*)(ws + WS_XH4);
  float2* kh4  = (float2*)(ws + WS_KH4);
  float2* yh4t = (float2*)(ws + WS_YH4T);
  float2* xt5  = (float2*)(ws + WS_XT5);
  float2* xh5  = (float2*)(ws + WS_XH5);
  float2* kh5  = (float2*)(ws + WS_KH5);
  float2* yh5t = (float2*)(ws + WS_YH5T);
  float*  s5p  = (float*) (ws + WS_S5P);
  float2* RTm  = (float2*)(ws + WS_RTM);
  float2* RU   = (float2*)(ws + WS_RU);

  const float* dA1p  = g_devF + CO.A1;
  const float* dAT2p = g_devF + CO.dAT2;
  const float* dAT3p = g_devF + CO.dAT3;
  const float* dA4p  = g_devF + CO.A4;
  const float* dA5p  = g_devF + CO.A5;
  const float* dT1p  = g_devF + CO.dT1;
  const float* dT2p  = g_devF + CO.dT2;
  const float* dS3p  = g_devF + CO.S3;
  const float* dS4p  = g_devF + CO.S4;
  const float* dS5p  = g_devF + CO.S5;
  const float* wIntp = g_devF + CO.WInt;
  const float2* Fs2p  = g_devC + CO.Fs2;
  const float2* Fso3p = g_devC + CO.Fso3;
  const float2* tw60p = g_devC + CO.Tw60;
  const float2* tw34p = g_devC + CO.Tw34;
  const float2* tw18p = g_devC + CO.Tw18;
  const float2* tw10p = g_devC + CO.Tw10;
  const float2* tw6p  = g_devC + CO.Tw6;
  const float2* Wn1p  = g_devC + CO.Wn1;
  const float2* Wn2p  = g_devC + CO.Wn2o;
  const float2* Wn4p  = g_devC + CO.Wn4;
  const float2* Wn5p  = g_devC + CO.Wn5;
  const float2* Wg1p  = g_devC + CO.Wg1;
  const float2* Wg2p  = g_devC + CO.Wg2;
  const float2* Wg4p  = g_devC + CO.Wg4;
  const float2* WC1p  = g_devC + CO.WC1;
  const float2* WC2p  = g_devC + CO.WC2;
  const int* toff1p  = g_devI + IO_TOFF1;
  const int* toff2p  = g_devI + IO_TOFF2;
  const int* qoff2p  = g_devI + IO_QOFF2;
  const int* qlist2p = g_devI + IO_QLST2;
  const int* qoff3p  = g_devI + IO_QOFF3;
  const int* qlist3p = g_devI + IO_QLST3;

  constexpr int Q17 = OQh(17), Q9 = OQh(9), Q5 = OQh(5), Q3 = OQh(3);

  // 1: all kernel FTs (243550 work items)
  k_kh_all<<<952, 256, 0, stream>>>(ks2, k1, k2, k3, k4, Fs2p, Fso3p,
                                    kh1, kh2, kh3, kh4, kh5);

  // 2-3: stage-1 analysis
  k_s1_fftA<<<32*60, 64, 0, stream>>>(x, tw60p, XF1);
  k_s1_coef<<<cdiv_h(32*900,256), 256, 0, stream>>>(XF1, dA1p, xh1);

  // 4-9: stage-1 synthesis chain (2 chunks of SL=1920; yh computed on-the-fly)
  for (int c = 0; c < 2; c++) {
    int base = c*1920;
    k_scatA<30,60,64,1920,1><<<30*30, 64, 0, stream>>>(xh1, kh1, dT1p, toff1p, tw60p, RTm, base);
    k_dftB<30,17,1920><<<60*30, 64, 0, stream>>>(RTm, Wn1p, Wg1p, RU);
    k_dftC<33,17,30,1920><<<17*30, 64, 0, stream>>>(RU, WC1p, xt2, base, 3840);
  }
  // 10-11: stage-2 analysis
  k_coefg<64,60,61,Q17><<<561, 256, 0, stream>>>(xt2, dAT2p, qoff2p, qlist2p, xh2, 3840);
  k_yh_t<<<cdiv_h(Q17*160,256), 256, 0, stream>>>(xh2, kh2, yh2t, 17, 2, 5, Q17);

  // 12-14: stage-2 synthesis chain (single chunk SL=5440)
  k_scatA<17,34,160,5440,0><<<17*85, 64, 0, stream>>>(yh2t, nullptr, dT2p, toff2p, tw34p, RTm, 0);
  k_dftB<17,9,5440><<<34*85, 64, 0, stream>>>(RTm, Wn2p, Wg2p, RU);
  k_dftC<17,9,17,5440><<<9*85, 64, 0, stream>>>(RU, WC2p, xt3, 0, 5440);

  // 15-16: stage-3 analysis
  k_coefg<160,34,35,Q9><<<153, 256, 0, stream>>>(xt3, dAT3p, qoff3p, qlist3p, xh3, 5440);
  k_yh_t<<<cdiv_h(Q9*384,256), 256, 0, stream>>>(xh3, kh3, yh3t, 9, 5, 12, Q9);

  // 17-19: stage 3 (old fused path)
  k_synth3<9,18,5,9,64,384><<<384*18, 64, 0, stream>>>(yh3t, dS3p, tw18p, xt4);
  k_coef<<<cdiv_h(384*Q5,256), 256, 0, stream>>>(xt4, dA4p, xh4, 5, 18, 5, 9, Q5, 384);
  k_yh_t<<<cdiv_h(Q5*896,256), 256, 0, stream>>>(xh4, kh4, yh4t, 5, 12, 28, Q5);

  // 20-22: stage 4
  k_synth2<5,10,3,5,0,1,64,896><<<896*10, 64, 0, stream>>>(yh4t, dS4p, tw10p, Wn4p, Wg4p, xt5, nullptr, nullptr);
  k_coef<<<cdiv_h(896*Q3,256), 256, 0, stream>>>(xt5, dA5p, xh5, 3, 10, 3, 5, Q3, 896);
  k_yh_t<<<cdiv_h(Q3*2048,256), 256, 0, stream>>>(xh5, kh5, yh5t, 3, 28, 64, Q3);

  // 23: stage 5 synthesis fused with so3_integrate
  k_synth2<3,6,3,5,1,1,64,2048><<<2048*6, 64, 0, stream>>>(yh5t, dS5p, tw6p, Wn5p, nullptr, nullptr, s5p, wIntp);

  // 24: head
  k_mlp<<<1, 256, 0, stream>>>(s5p, g1, be1, w1, b1, g2, be2, w2, b2, g3, be3, w3, b3, out);
}

// Round 6
// 825.566 us; speedup vs baseline: 1.3025x; 1.1249x over previous
//
#include <hip/hip_runtime.h>
#include <cmath>
#include <cstring>
#include <vector>

// ============================================================================
// Spherical CNN (s2conv -> 4x so3conv -> integrate -> MLP), MI355X gfx950.
// Round 6: re-parallelized synthesis chain. Same math as R5 (verified), but
// 256-thread blocks: scatB (LDS P + WEO table, 4 pm/a groups), dftB2 (4 a's
// per block), dftC2 (LDS-staged U, 4 p-groups). Fixes 8% occupancy of R5.
// ============================================================================

#define DPI 3.14159265358979323846

static constexpr int OQh(int l) { return l*(4*l*l - 1)/3; }
static_assert(OQh(30) == 35990, "oq30");
static_assert(OQh(17) == 6545,  "oq17");
static_assert(OQh(9)  == 969,   "oq9");
static_assert(OQh(5)  == 165,   "oq5");
static_assert(OQh(3)  == 35,    "oq3");

static constexpr int T1SUM = 18445;
static constexpr int T2SUM = 3417;

// ---------------- workspace layout (bytes) ----------------
static constexpr size_t al256(size_t x){ return (x + 255) & ~(size_t)255; }
static constexpr size_t WS_XF1  = 0;
static constexpr size_t WS_XH1  = WS_XF1  + al256(32ull*60*30*8);
static constexpr size_t WS_KH1  = WS_XH1  + al256(32ull*900*8);
static constexpr size_t WS_XT2  = WS_KH1  + al256(1800ull*8);
static constexpr size_t WS_XH2  = WS_XT2  + al256(561ull*3840*8);
static constexpr size_t WS_KH2  = WS_XH2  + al256(64ull*6545*8);
static constexpr size_t WS_YH2T = WS_KH2  + al256(6545ull*10*8);
static constexpr size_t WS_XT3  = WS_YH2T + al256(6545ull*160*8);
static constexpr size_t WS_XH3  = WS_XT3  + al256(153ull*5440*8);
static constexpr size_t WS_KH3  = WS_XH3  + al256(160ull*969*8);
static constexpr size_t WS_YH3T = WS_KH3  + al256(969ull*60*8);
static constexpr size_t WS_XT4  = WS_YH3T + al256(969ull*384*8);
static constexpr size_t WS_XH4  = WS_XT4  + al256(384ull*18*45*8);
static constexpr size_t WS_KH4  = WS_XH4  + al256(384ull*165*8);
static constexpr size_t WS_YH4T = WS_KH4  + al256(165ull*336*8);
static constexpr size_t WS_XT5  = WS_YH4T + al256(165ull*896*8);
static constexpr size_t WS_XH5  = WS_XT5  + al256(896ull*10*15*8);
static constexpr size_t WS_KH5  = WS_XH5  + al256(896ull*35*8);
static constexpr size_t WS_YH5T = WS_KH5  + al256(35ull*1792*8);
static constexpr size_t WS_S5P  = WS_YH5T + al256(35ull*2048*8);
static constexpr size_t WS_RTM  = WS_S5P  + al256(2048ull*6*4);
static constexpr size_t WS_RU   = WS_RTM  + al256(60ull*30*1920*8);
static constexpr size_t WS_TOTAL= WS_RU   + al256(60ull*17*1920*8);

// ---------------- constant-table offsets ----------------
struct ConstOffs {
  size_t A1, dAT2, dAT3, A4, A5;
  size_t dT1, dT2;
  size_t S3, S4, S5;
  size_t WInt;
  size_t nF;
  size_t Fs2, Fso3;
  size_t Tw60, Tw34, Tw18, Tw10, Tw6;
  size_t Wn1, Wn2o, Wn4, Wn5;
  size_t Wg1, Wg2, Wg4;
  size_t WC1, WC2;
  size_t WEO1, WEO2;
  size_t nC;
};
static ConstOffs CO;
static float*  g_devF = nullptr;
static float2* g_devC = nullptr;
static int*    g_devI = nullptr;
static constexpr int IO_TOFF1 = 0;          // 1770
static constexpr int IO_TOFF2 = 1770;       // 561
static constexpr int IO_QOFF2 = 2331;       // 562
static constexpr int IO_QLST2 = 2893;       // 6545
static constexpr int IO_QOFF3 = 9438;       // 154
static constexpr int IO_QLST3 = 9592;       // 969
static constexpr int IO_TOTAL = 10561;

// ============================================================================
// Host: symmetric-tridiagonal eigensolver + Wigner-d builder
// ============================================================================
static void tqli(double* d, double* e, int n, double* z) {
  e[n-1] = 0.0;
  for (int l = 0; l < n; l++) {
    int iter = 0;
    int m;
    do {
      for (m = l; m < n-1; m++) {
        double dd = fabs(d[m]) + fabs(d[m+1]);
        if (fabs(e[m]) <= 1e-300 + 1e-14*dd) break;
      }
      if (m != l) {
        if (iter++ == 80) break;
        double g = (d[l+1]-d[l])/(2.0*e[l]);
        double r = hypot(g, 1.0);
        g = d[m]-d[l]+e[l]/(g + (g >= 0.0 ? fabs(r) : -fabs(r)));
        double s = 1.0, c = 1.0, p = 0.0;
        int i;
        r = 1.0;
        for (i = m-1; i >= l; i--) {
          double f = s*e[i], b = c*e[i];
          r = hypot(f, g);
          e[i+1] = r;
          if (r == 0.0) { d[i+1] -= p; e[m] = 0.0; break; }
          s = f/r; c = g/r;
          g = d[i+1]-p;
          r = (d[i]-g)*s + 2.0*c*b;
          p = s*r;
          d[i+1] = g+p;
          g = c*r-b;
          for (int k = 0; k < n; k++) {
            f = z[(size_t)k*n+i+1];
            z[(size_t)k*n+i+1] = s*z[(size_t)k*n+i] + c*f;
            z[(size_t)k*n+i]   = c*z[(size_t)k*n+i] - s*f;
          }
        }
        if (r == 0.0 && i >= l) continue;
        d[l] -= p; e[l] = g; e[m] = 0.0;
      }
    } while (m != l);
  }
}

struct Builder {
  std::vector<std::vector<double>> V, Lam;
  bool useExpm[30];

  Builder() {
    V.resize(30); Lam.resize(30);
    for (int l = 0; l < 30; l++) {
      int n = 2*l+1;
      std::vector<double> d(n, 0.0), e(n, 0.0), z((size_t)n*n, 0.0);
      for (int i = 0; i < n; i++) z[(size_t)i*n+i] = 1.0;
      for (int i = 0; i+1 < n; i++) {
        double m = (double)i - l;
        e[i] = -0.5*sqrt((double)l*(l+1) - m*(m+1.0));
      }
      if (n > 1) tqli(d.data(), e.data(), n, z.data());
      V[l] = std::move(z); Lam[l] = std::move(d);
    }
    std::vector<double> t((size_t)59*59);
    for (int l = 0; l < 30; l++) {
      useExpm[l] = false;
      if (l == 0) continue;
      int n = 2*l+1;
      eigD(l, 0.77, t.data());
      double corner = pow(cos(0.385), 2.0*l);
      double err = fabs(t[0] - corner) + fabs(t[(size_t)(n-1)*n + (n-1)] - corner);
      double s = 0.0;
      for (int c = 0; c < n; c++) s += t[c]*t[c];
      err += fabs(s - 1.0);
      if (!(err < 1e-8)) useExpm[l] = true;
    }
  }

  void eigD(int l, double beta, double* out) {
    int n = 2*l+1;
    const double* Vp = V[l].data();
    const double* lam = Lam[l].data();
    double ck[64], sk[64];
    for (int k = 0; k < n; k++) { ck[k] = cos(beta*lam[k]); sk[k] = sin(beta*lam[k]); }
    for (int a = 0; a < n; a++) {
      const double* va = Vp + (size_t)a*n;
      for (int c = 0; c < n; c++) {
        const double* vc = Vp + (size_t)c*n;
        int r = ((a - c) % 4 + 4) % 4;
        const double* f = (r & 1) ? sk : ck;
        double s = 0.0;
        for (int k = 0; k < n; k++) s += va[k]*vc[k]*f[k];
        out[(size_t)a*n + c] = (r >= 2) ? -s : s;
      }
    }
  }

  void expmD(int l, double beta, double* out) {
    int n = 2*l+1;
    int s = 0; double bl = fabs(beta)*(double)l + 1e-12;
    while (bl > 0.25) { bl *= 0.5; s++; }
    double sc = ldexp(beta, -s);
    std::vector<double> sup(n > 1 ? n-1 : 0);
    for (int i = 0; i+1 < n; i++) {
      double m = (double)i - l;
      sup[i] = 0.5*sqrt((double)l*(l+1) - m*(m+1.0))*sc;
    }
    std::vector<double> term((size_t)n*n, 0.0), acc((size_t)n*n, 0.0), t2((size_t)n*n);
    for (int i = 0; i < n; i++) { term[(size_t)i*n+i] = 1.0; acc[(size_t)i*n+i] = 1.0; }
    for (int k = 1; k <= 16; k++) {
      for (int r = 0; r < n; r++)
        for (int c = 0; c < n; c++) {
          double v = 0.0;
          if (c > 0)   v += term[(size_t)r*n + c-1]*sup[c-1];
          if (c+1 < n) v -= term[(size_t)r*n + c+1]*sup[c];
          t2[(size_t)r*n+c] = v/(double)k;
        }
      term.swap(t2);
      for (size_t i2 = 0; i2 < (size_t)n*n; i2++) acc[i2] += term[i2];
    }
    for (int t = 0; t < s; t++) {
      for (int r = 0; r < n; r++)
        for (int c = 0; c < n; c++) {
          double v = 0.0;
          for (int k = 0; k < n; k++) v += acc[(size_t)r*n+k]*acc[(size_t)k*n+c];
          t2[(size_t)r*n+c] = v;
        }
      acc.swap(t2);
    }
    std::memcpy(out, acc.data(), sizeof(double)*(size_t)n*n);
  }

  void buildD(int l, double beta, double* out) {
    if (useExpm[l]) expmD(l, beta, out); else eigD(l, beta, out);
  }
};

static std::vector<double> quadw_h(int b) {
  std::vector<double> w(2*b);
  for (int j = 0; j < 2*b; j++) {
    double s = 0;
    for (int k = 0; k < b; k++)
      s += sin(DPI*(2*j+1)*(2*k+1)/(4.0*b))/(double)(2*k+1);
    w[j] = (2.0/b)*sin(DPI*(2*j+1)/(4.0*b))*s;
  }
  return w;
}

static void build_all() {
  size_t o = 0;
  CO.A1   = o; o += 60ull*900;
  CO.dAT2 = o; o += (size_t)OQh(17)*60;
  CO.dAT3 = o; o += (size_t)OQh(9)*34;
  CO.A4   = o; o += 18ull*OQh(5);
  CO.A5   = o; o += 10ull*OQh(3);
  CO.dT1  = o; o += (size_t)T1SUM*60;
  CO.dT2  = o; o += (size_t)T2SUM*34;
  CO.S3   = o; o += 18ull*OQh(9);
  CO.S4   = o; o += 10ull*OQh(5);
  CO.S5   = o; o +=  6ull*OQh(3);
  CO.WInt = o; o += 8;
  CO.nF = o;
  size_t c = 0;
  CO.Fs2  = c; c += 6ull*900;
  CO.Fso3 = c; c += 36ull*OQh(17);
  CO.Tw60 = c; c += 60; CO.Tw34 = c; c += 34;
  CO.Tw18 = c; c += 18; CO.Tw10 = c; c += 10; CO.Tw6 = c; c += 6;
  CO.Wn1  = c; c += 30*60; CO.Wn2o = c; c += 17*34;
  CO.Wn4  = c; c += 5*10;  CO.Wn5  = c; c += 3*6;
  CO.Wg1  = c; c += 60*17; CO.Wg2  = c; c += 34*9; CO.Wg4 = c; c += 10*3;
  CO.WC1  = c; c += 33*60;
  CO.WC2  = c; c += 17*34;
  CO.WEO1 = c; c += 59*30;
  CO.WEO2 = c; c += 33*17;
  CO.nC = c;

  std::vector<float> HF(CO.nF, 0.f);
  std::vector<float> HC(2*CO.nC, 0.f);
  std::vector<int> HI(IO_TOTAL, 0);

  { int acc = 0;
    for (int pm = 0; pm < 59; pm++) for (int n = 0; n < 30; n++) {
      int m = pm - 29, am = m < 0 ? -m : m;
      int lm = am > n ? am : n;
      HI[IO_TOFF1 + pm*30 + n] = acc; acc += 30 - lm;
    } }
  { int acc = 0;
    for (int pm = 0; pm < 33; pm++) for (int n = 0; n < 17; n++) {
      int m = pm - 16, am = m < 0 ? -m : m;
      int lm = am > n ? am : n;
      HI[IO_TOFF2 + pm*17 + n] = acc; acc += 17 - lm;
    } }
  { int pos = 0;
    for (int mh = -16; mh <= 16; mh++)
      for (int kh = 0; kh < 17; kh++) {
        HI[IO_QOFF2 + (mh+16)*17 + kh] = pos;
        int am = mh < 0 ? -mh : mh;
        int lmin = am > kh ? am : kh;
        for (int l = lmin; l < 17; l++) {
          int q = OQh(l) + (mh+l)*(2*l+1) + (kh+l);
          HI[IO_QLST2 + pos++] = q*2;
        }
        if (kh > 0)
          for (int l = lmin; l < 17; l++) {
            int q = OQh(l) + (-mh+l)*(2*l+1) + (-kh+l);
            HI[IO_QLST2 + pos++] = q*2 + 1;
          }
      }
    HI[IO_QOFF2 + 561] = pos;
  }
  { int pos = 0;
    for (int mh = -8; mh <= 8; mh++)
      for (int kh = 0; kh < 9; kh++) {
        HI[IO_QOFF3 + (mh+8)*9 + kh] = pos;
        int am = mh < 0 ? -mh : mh;
        int lmin = am > kh ? am : kh;
        for (int l = lmin; l < 9; l++) {
          int q = OQh(l) + (mh+l)*(2*l+1) + (kh+l);
          HI[IO_QLST3 + pos++] = q*2;
        }
        if (kh > 0)
          for (int l = lmin; l < 9; l++) {
            int q = OQh(l) + (-mh+l)*(2*l+1) + (-kh+l);
            HI[IO_QLST3 + pos++] = q*2 + 1;
          }
      }
    HI[IO_QOFF3 + 153] = pos;
  }

  Builder B;
  auto betas = [](int b){ std::vector<double> v(2*b);
    for (int j = 0; j < 2*b; j++) v[j] = DPI*(2*j+1)/(4.0*b); return v; };
  auto w30 = quadw_h(30), w17 = quadw_h(17), w9 = quadw_h(9), w5 = quadw_h(5), w3 = quadw_h(3);
  std::vector<double> tmp((size_t)59*59);

  { auto bs = betas(30);
    for (int l = 0; l < 30; l++) { int W = 2*l+1;
      for (int j = 0; j < 60; j++) {
        B.buildD(l, bs[j], tmp.data());
        for (int mm = -l; mm <= l; mm++)
          for (int nn = 0; nn <= l; nn++) {
            int am = mm < 0 ? -mm : mm;
            int lmin = am > nn ? am : nn;
            int term = HI[IO_TOFF1 + (mm+29)*30 + nn] + (l - lmin);
            HF[CO.dT1 + (size_t)term*60 + j] =
              (float)((2*l+1)*tmp[(size_t)(mm+l)*W + (nn+l)]);
          }
        if (l < 17) {
          for (int rem = 0; rem < W*W; rem++)
            HF[CO.dAT2 + (size_t)(OQh(l)+rem)*60 + j] = (float)(tmp[rem]*w30[j]);
        }
        float* dA1 = HF.data() + CO.A1 + 60ull*l*l + (size_t)j*W;
        for (int mi = 0; mi < W; mi++) dA1[mi] = (float)(tmp[(size_t)mi*W + l]*w30[j]);
      } } }
  { auto bs = betas(17);
    for (int l = 0; l < 17; l++) { int W = 2*l+1;
      for (int j = 0; j < 34; j++) {
        B.buildD(l, bs[j], tmp.data());
        for (int mm = -l; mm <= l; mm++)
          for (int nn = 0; nn <= l; nn++) {
            int am = mm < 0 ? -mm : mm;
            int lmin = am > nn ? am : nn;
            int term = HI[IO_TOFF2 + (mm+16)*17 + nn] + (l - lmin);
            HF[CO.dT2 + (size_t)term*34 + j] =
              (float)((2*l+1)*tmp[(size_t)(mm+l)*W + (nn+l)]);
          }
        if (l < 9) {
          for (int rem = 0; rem < W*W; rem++)
            HF[CO.dAT3 + (size_t)(OQh(l)+rem)*34 + j] = (float)(tmp[rem]*w17[j]);
        } } } }
  { auto bs = betas(9);
    for (int l = 0; l < 9; l++) { int W = 2*l+1;
      for (int j = 0; j < 18; j++) {
        B.buildD(l, bs[j], tmp.data());
        float* dst = HF.data() + CO.S3 + 18ull*OQh(l) + (size_t)j*W*W;
        for (int i2 = 0; i2 < W*W; i2++) dst[i2] = (float)((2*l+1)*tmp[i2]);
        if (l < 5) {
          float* dA = HF.data() + CO.A4 + 18ull*OQh(l) + (size_t)j*W*W;
          for (int i2 = 0; i2 < W*W; i2++) dA[i2] = (float)(tmp[i2]*w9[j]);
        } } } }
  { auto bs = betas(5);
    for (int l = 0; l < 5; l++) { int W = 2*l+1;
      for (int j = 0; j < 10; j++) {
        B.buildD(l, bs[j], tmp.data());
        float* dst = HF.data() + CO.S4 + 10ull*OQh(l) + (size_t)j*W*W;
        for (int i2 = 0; i2 < W*W; i2++) dst[i2] = (float)((2*l+1)*tmp[i2]);
        if (l < 3) {
          float* dA = HF.data() + CO.A5 + 10ull*OQh(l) + (size_t)j*W*W;
          for (int i2 = 0; i2 < W*W; i2++) dA[i2] = (float)(tmp[i2]*w5[j]);
        } } } }
  { auto bs = betas(3);
    for (int l = 0; l < 3; l++) { int W = 2*l+1;
      for (int j = 0; j < 6; j++) {
        B.buildD(l, bs[j], tmp.data());
        float* dst = HF.data() + CO.S5 + 6ull*OQh(l) + (size_t)j*W*W;
        for (int i2 = 0; i2 < W*W; i2++) dst[i2] = (float)((2*l+1)*tmp[i2]);
      } } }
  { double beta = DPI/16.0;
    for (int l = 0; l < 30; l++) { int n = 2*l+1;
      B.buildD(l, beta, tmp.data());
      for (int p = 0; p < 6; p++) {
        double al = 2.0*DPI*p/6.0;
        for (int mi = 0; mi < n; mi++) {
          double ph = al*(double)(mi - l);
          double dr = tmp[(size_t)mi*n + l];
          size_t off = CO.Fs2 + 6ull*l*l + (size_t)p*n + mi;
          HC[2*off]   = (float)(dr*cos(ph));
          HC[2*off+1] = (float)(dr*sin(ph));
        } }
      if (l < 17) {
        for (int p = 0; p < 36; p++) {
          double al = 2.0*DPI*(p/6)/6.0, ga = 2.0*DPI*(p%6)/6.0;
          for (int mi = 0; mi < n; mi++)
            for (int ni = 0; ni < n; ni++) {
              double ph = al*(double)(mi - l) + ga*(double)(ni - l);
              double dr = tmp[(size_t)mi*n + ni];
              size_t off = CO.Fso3 + 36ull*OQh(l) + (size_t)p*n*n + (size_t)mi*n + ni;
              HC[2*off]   = (float)(dr*cos(ph));
              HC[2*off+1] = (float)(dr*sin(ph));
            } } } } }
  auto fillTw = [&](size_t ofs, int N){
    for (int t = 0; t < N; t++) {
      HC[2*(ofs+t)]   = (float)cos(2.0*DPI*t/N);
      HC[2*(ofs+t)+1] = (float)sin(2.0*DPI*t/N);
    } };
  fillTw(CO.Tw60, 60); fillTw(CO.Tw34, 34);
  fillTw(CO.Tw18, 18); fillTw(CO.Tw10, 10); fillTw(CO.Tw6, 6);
  auto fillWn = [&](size_t ofs, int BQ, int N){
    for (int n = 0; n < BQ; n++)
      for (int cc2 = 0; cc2 < N; cc2++) {
        double f = (n == 0) ? 1.0 : 2.0;
        HC[2*(ofs + (size_t)n*N + cc2)]   = (float)(f*cos(2.0*DPI*n*cc2/N));
        HC[2*(ofs + (size_t)n*N + cc2)+1] = (float)(f*sin(2.0*DPI*n*cc2/N));
      } };
  auto fillWg = [&](size_t ofs, int N, int KT){
    for (int cc2 = 0; cc2 < N; cc2++)
      for (int k = 0; k < KT; k++) {
        HC[2*(ofs + (size_t)cc2*KT + k)]   = (float)cos(2.0*DPI*k*cc2/N);
        HC[2*(ofs + (size_t)cc2*KT + k)+1] = (float)(-sin(2.0*DPI*k*cc2/N));
      } };
  fillWn(CO.Wn1, 30, 60); fillWn(CO.Wn2o, 17, 34);
  fillWn(CO.Wn4, 5, 10);  fillWn(CO.Wn5, 3, 6);
  fillWg(CO.Wg1, 60, 17); fillWg(CO.Wg2, 34, 9); fillWg(CO.Wg4, 10, 3);
  for (int p = 0; p < 33; p++)
    for (int a = 0; a < 60; a++) {
      double th = 2.0*DPI*(p-16)*a/60.0;
      HC[2*(CO.WC1 + (size_t)p*60 + a)]   = (float)cos(th);
      HC[2*(CO.WC1 + (size_t)p*60 + a)+1] = (float)sin(th);
    }
  for (int p = 0; p < 17; p++)
    for (int a = 0; a < 34; a++) {
      double th = 2.0*DPI*(p-8)*a/34.0;
      HC[2*(CO.WC2 + (size_t)p*34 + a)]   = (float)cos(th);
      HC[2*(CO.WC2 + (size_t)p*34 + a)+1] = (float)sin(th);
    }
  // radix-2 alpha-iDFT tables: WEO[pm][a] = cis(2 pi a ((pm-(BQ-1)) mod N)/N)
  for (int pm = 0; pm < 59; pm++)
    for (int a = 0; a < 30; a++) {
      int s = ((pm - 29) % 60 + 60) % 60;
      double th = 2.0*DPI*a*s/60.0;
      HC[2*(CO.WEO1 + (size_t)pm*30 + a)]   = (float)cos(th);
      HC[2*(CO.WEO1 + (size_t)pm*30 + a)+1] = (float)sin(th);
    }
  for (int pm = 0; pm < 33; pm++)
    for (int a = 0; a < 17; a++) {
      int s = ((pm - 16) % 34 + 34) % 34;
      double th = 2.0*DPI*a*s/34.0;
      HC[2*(CO.WEO2 + (size_t)pm*17 + a)]   = (float)cos(th);
      HC[2*(CO.WEO2 + (size_t)pm*17 + a)+1] = (float)sin(th);
    }
  for (int j = 0; j < 6; j++) HF[CO.WInt + j] = (float)(w3[j]/36.0);

  size_t fb  = CO.nF * sizeof(float);
  size_t fbA = al256(fb);
  size_t cb  = CO.nC * sizeof(float2);
  size_t cbA = al256(cb);
  size_t ib  = HI.size() * sizeof(int);
  void* base = nullptr;
  if (hipMalloc(&base, fbA + cbA + ib) != hipSuccess || !base) return;
  if (hipMemcpy(base, HF.data(), fb, hipMemcpyHostToDevice) != hipSuccess) return;
  if (hipMemcpy((char*)base + fbA, HC.data(), cb, hipMemcpyHostToDevice) != hipSuccess) return;
  if (hipMemcpy((char*)base + fbA + cbA, HI.data(), ib, hipMemcpyHostToDevice) != hipSuccess) return;
  (void)hipDeviceSynchronize();
  g_devF = (float*)base;
  g_devC = (float2*)((char*)base + fbA);
  g_devI = (int*)((char*)base + fbA + cbA);
}
namespace { struct InitOnce { InitOnce(){ build_all(); } } g_once; }

// ============================================================================
// Device helpers
// ============================================================================
__device__ __forceinline__ int OQ(int l) { return l*(4*l*l - 1)/3; }
__device__ __forceinline__ int lFromQ(int q, int L) {
  int l = 0;
  while (l+1 < L && OQ(l+1) <= q) l++;
  return l;
}
__device__ __forceinline__ int lsq(int q) {
  int l = (int)sqrtf((float)q);
  while ((l+1)*(l+1) <= q) l++;
  while (l*l > q) l--;
  return l;
}
__device__ __forceinline__ void rotf(float2& r, float2 s) {
  float t = r.x*s.x - r.y*s.y;
  r.y = r.x*s.y + r.y*s.x;
  r.x = t;
}

// ---------------- fused kernel-FT (all 5 layers, one dispatch) -------------
__device__ __forceinline__ void kh_so3_one(int id, int L, int fi, int fo,
    const float* __restrict__ kk, const float2* __restrict__ F, float2* __restrict__ kh)
{
  int ff = fi*fo;
  int q = id / ff, r = id - q*ff;
  int i = r / fo, o = r - i*fo;
  int l = lFromQ(q, L); int W = 2*l+1; int W21 = W*W;
  int rem = q - OQ(l);
  const float2* Fb = F + 36ull*OQ(l) + rem;
  const float* kb = kk + (size_t)(i*fo + o)*36;
  float ax = 0.f, ay = 0.f;
  for (int p = 0; p < 36; p++) {
    float kv = kb[p];
    float2 f = Fb[(size_t)p*W21];
    ax += kv*f.x; ay += kv*f.y;
  }
  kh[(size_t)q*ff + r] = make_float2(ax, ay);
}

__global__ __launch_bounds__(256) void k_kh_all(
    const float* __restrict__ ks2, const float* __restrict__ k1,
    const float* __restrict__ k2,  const float* __restrict__ k3,
    const float* __restrict__ k4,
    const float2* __restrict__ Fs2, const float2* __restrict__ Fso3,
    float2* __restrict__ kh1, float2* __restrict__ kh2, float2* __restrict__ kh3,
    float2* __restrict__ kh4, float2* __restrict__ kh5)
{
  int id = blockIdx.x*256 + threadIdx.x;
  if (id < 1800) {
    int q = id >> 1, o = id & 1;
    int l = lsq(q); int W = 2*l+1; int mi = q - l*l;
    const float2* Fb = Fs2 + 6ull*l*l;
    float ax = 0.f, ay = 0.f;
    for (int p = 0; p < 6; p++) {
      float kv = ks2[o*6 + p];
      float2 f = Fb[p*W + mi];
      ax += kv*f.x; ay += kv*f.y;
    }
    kh1[(size_t)q*2 + o] = make_float2(ax, ay);
    return;
  }
  id -= 1800;
  if (id < OQh(17)*10) { kh_so3_one(id, 17, 2, 5, k1, Fso3, kh2); return; }
  id -= OQh(17)*10;
  if (id < OQh(9)*60) { kh_so3_one(id, 9, 5, 12, k2, Fso3, kh3); return; }
  id -= OQh(9)*60;
  if (id < OQh(5)*336) { kh_so3_one(id, 5, 12, 28, k3, Fso3, kh4); return; }
  id -= OQh(5)*336;
  if (id < OQh(3)*1792) { kh_so3_one(id, 3, 28, 64, k4, Fso3, kh5); return; }
}

// ---------------- stage-1 analysis: alpha DFT ----------------
__global__ __launch_bounds__(64) void k_s1_fftA(
    const float* __restrict__ x, const float2* __restrict__ tw, float2* __restrict__ XF1)
{
  __shared__ float row[60];
  int b = blockIdx.x / 60, j = blockIdx.x - b*60;
  int t = threadIdx.x;
  if (t < 60) row[t] = x[((size_t)b*60 + j)*60 + t];
  __syncthreads();
  if (t < 30) {
    float ax = 0.f, ay = 0.f;
    int ti = 0;
    for (int a = 0; a < 60; a++) {
      float2 w = tw[ti];
      ax += row[a]*w.x; ay -= row[a]*w.y;
      ti += t; if (ti >= 60) ti -= 60;
    }
    XF1[((size_t)b*60 + j)*30 + t] = make_float2(ax, ay);
  }
}

// ---------------- stage-1 beta contraction ----------------
__global__ __launch_bounds__(256) void k_s1_coef(
    const float2* __restrict__ XF1, const float* __restrict__ dA1, float2* __restrict__ xh1)
{
  int id = blockIdx.x*blockDim.x + threadIdx.x;
  if (id >= 32*900) return;
  int b = id / 900, q = id - b*900;
  int l = lsq(q); int W = 2*l+1; int mi = q - l*l; int m = mi - l;
  const float* dp = dA1 + 60ull*l*l + mi;
  const float2* xb = XF1 + (size_t)b*60*30;
  int ma = m >= 0 ? m : -m;
  float sg = m >= 0 ? 1.f : -1.f;
  float ax = 0.f, ay = 0.f;
  for (int j = 0; j < 60; j++) {
    float2 xf = xb[j*30 + ma];
    float d = dp[(size_t)j*W];
    ax += d*xf.x; ay += sg*d*xf.y;
  }
  xh1[id] = make_float2(ax, ay);
}

// ---------------- generic spectral product -> transposed yh ----------------
__global__ __launch_bounds__(256) void k_yh_t(
    const float2* __restrict__ xh, const float2* __restrict__ kh,
    float2* __restrict__ yht, int L, int fi, int fo, int Qtot)
{
  int id = blockIdx.x*256 + threadIdx.x;
  int BOF = 32*fo;
  if (id >= Qtot*BOF) return;
  int q = id / BOF, bo = id - q*BOF;
  int b = bo / fo, o = bo - b*fo;
  int l = lFromQ(q, L); int W = 2*l+1;
  int rem = q - OQ(l); int mi = rem / W, ni = rem - mi*W;
  int ff = fi*fo;
  const float2* xb = xh + ((size_t)b*fi)*Qtot + OQ(l) + mi*W;
  const float2* kb = kh + ((size_t)(OQ(l) + ni*W))*ff + o;
  float ax = 0.f, ay = 0.f;
  for (int i = 0; i < fi; i++) {
    const float2* xrow = xb + (size_t)i*Qtot;
    const float2* krow = kb + (size_t)i*fo;
    for (int k = 0; k < W; k++) {
      float2 xv = xrow[k];
      float2 kv = krow[(size_t)k*ff];
      ax += xv.x*kv.x + xv.y*kv.y;
      ay += xv.y*kv.x - xv.x*kv.y;
    }
  }
  yht[id] = make_float2(ax, ay);
}

// ============================================================================
// k_scatB: fused Wigner scatter + radix-2 alpha-iDFT, 256-thread blocks.
// Block = (n, sl-tile of 64). 4 x 64-lane groups stripe pm rows (phase A)
// then own PG a-pairs each (phase B). Same math as R5's k_scatA (verified).
// ============================================================================
template<int BQ, int NJ, int BO, int CHSL, int STAGE1>
__global__ __launch_bounds__(256) void k_scatB(
    const float2* __restrict__ src,     // STAGE1: xh1 ; else yht [e][BO]
    const float2* __restrict__ khp,     // STAGE1 only
    const float* __restrict__ dT, const int* __restrict__ toff,
    const float2* __restrict__ WEO, float2* __restrict__ Tm, int slBase)
{
  constexpr int W2 = 2*BQ - 1;
  constexpr int TILES = CHSL/64;
  constexpr int PG = (BQ + 3)/4;
  __shared__ float2 P[W2*64];
  __shared__ float2 Wl[W2*BQ];
  __shared__ float2 kcl[STAGE1 ? 2*BQ : 2];
  const int tid = threadIdx.x;
  const int g = tid >> 6, lane = tid & 63;
  int n = blockIdx.x / TILES, ts = blockIdx.x - n*TILES;
  int slL = ts*64 + lane;
  int slG = slBase + slL;
  int bo = slG / NJ;
  int j  = slG - bo*NJ;

  for (int i = tid; i < W2*BQ; i += 256) Wl[i] = WEO[i];
  if constexpr (STAGE1) {
    int cnt = 2*(BQ - n);
    if (tid < cnt) {
      int l = n + (tid >> 1), o = tid & 1;
      kcl[2*l + o] = khp[(size_t)(l*l + n + l)*2 + o];
    }
  }
  __syncthreads();

  // ---- phase A: scatter (n >= 0 Hermitian half), groups stripe pm
  for (int pm = g; pm < W2; pm += 4) {
    int m = pm - (BQ-1);
    int am = m < 0 ? -m : m;
    int lmin = am > n ? am : n;
    int K = BQ - lmin;
    int tof = toff[pm*BQ + n];
    const float* dp = dT + (size_t)tof*NJ + j;
    float ax = 0.f, ay = 0.f;
    if constexpr (STAGE1) {
      int b = bo >> 1, o = bo & 1;
      const float2* xb = src + (size_t)b*900;
      for (int li = 0; li < K; li++) {
        int l = lmin + li;
        float d = dp[(size_t)li*NJ];
        float2 xv = xb[l*l + m + l];
        float2 kv = kcl[2*l + o];
        float yx = xv.x*kv.x + xv.y*kv.y;
        float yy = xv.y*kv.x - xv.x*kv.y;
        ax = fmaf(d, yx, ax); ay = fmaf(d, yy, ay);
      }
    } else {
      for (int li = 0; li < K; li++) {
        int l = lmin + li;
        int e = OQ(l) + (m+l)*(2*l+1) + (n+l);
        float d = dp[(size_t)li*NJ];
        float2 y = src[(size_t)e*BO + bo];
        ax = fmaf(d, y.x, ax); ay = fmaf(d, y.y, ay);
      }
    }
    P[pm*64 + lane] = make_float2(ax, ay);
  }
  __syncthreads();

  // ---- phase B: radix-2 alpha-iDFT; group g owns a-pairs a0..a0+cnt-1
  int a0 = g*PG;
  int cnt = BQ - a0; if (cnt > PG) cnt = PG; if (cnt < 0) cnt = 0;
  float2 E[PG], Od[PG];
  #pragma unroll
  for (int i = 0; i < PG; i++) { E[i] = make_float2(0.f,0.f); Od[i] = make_float2(0.f,0.f); }
  for (int t2 = 0; t2 < BQ; t2++) {            // even pm = 2*t2
    float2 p = P[(2*t2)*64 + lane];
    const float2* wr = &Wl[(2*t2)*BQ + a0];
    #pragma unroll
    for (int i = 0; i < PG; i++) {
      float2 w = wr[i];
      E[i].x = fmaf(p.x, w.x, fmaf(-p.y, w.y, E[i].x));
      E[i].y = fmaf(p.x, w.y, fmaf( p.y, w.x, E[i].y));
    }
  }
  for (int t2 = 0; t2 < BQ-1; t2++) {          // odd pm = 2*t2+1
    float2 p = P[(2*t2+1)*64 + lane];
    const float2* wr = &Wl[(2*t2+1)*BQ + a0];
    #pragma unroll
    for (int i = 0; i < PG; i++) {
      float2 w = wr[i];
      Od[i].x = fmaf(p.x, w.x, fmaf(-p.y, w.y, Od[i].x));
      Od[i].y = fmaf(p.x, w.y, fmaf( p.y, w.x, Od[i].y));
    }
  }
  constexpr bool QS = ((BQ-1) & 1) != 0;
  for (int i = 0; i < cnt; i++) {
    int a = a0 + i;
    float2 tp = make_float2(E[i].x + Od[i].x, E[i].y + Od[i].y);
    float2 tq = QS ? make_float2(Od[i].x - E[i].x, Od[i].y - E[i].y)
                   : make_float2(E[i].x - Od[i].x, E[i].y - Od[i].y);
    Tm[((size_t)a*BQ + n)*CHSL + slL] = tp;
    Tm[((size_t)(a+BQ)*BQ + n)*CHSL + slL] = tq;
  }
}

// ============================================================================
// k_dftB2: Hermitian gamma fold + ReLU + gamma fwd DFT; 4 a-units per block.
// ============================================================================
template<int BQ, int KT, int CHSL>
__global__ __launch_bounds__(256) void k_dftB2(
    const float2* __restrict__ Tm, const float2* __restrict__ Wn,
    const float2* __restrict__ Wg, float2* __restrict__ U)
{
  constexpr int N = 2*BQ;
  constexpr int NH = BQ;
  constexpr int TILES = CHSL/64;
  __shared__ float2 WnL[BQ*NH];
  __shared__ float2 WgL[NH*KT];
  int a4 = blockIdx.x / TILES, ts = blockIdx.x - a4*TILES;
  int tid = threadIdx.x;
  int g = tid >> 6, lane = tid & 63;
  int a = a4*4 + g;
  for (int i = tid; i < BQ*NH; i += 256) { int nn = i/NH, c = i - nn*NH; WnL[i] = Wn[(size_t)nn*N + c]; }
  for (int i = tid; i < NH*KT; i += 256) WgL[i] = Wg[i];
  __syncthreads();
  if (a >= N) return;
  int sl = ts*64 + lane;
  float SE[NH], SO[NH];
  #pragma unroll
  for (int c = 0; c < NH; c++) { SE[c] = 0.f; SO[c] = 0.f; }
  const float2* Tb = Tm + (size_t)a*BQ*CHSL + sl;
  for (int t2 = 0; 2*t2 < BQ; t2++) {
    int nn = 2*t2;
    float2 tv = Tb[(size_t)nn*CHSL];
    #pragma unroll
    for (int c = 0; c < NH; c++) {
      float2 w = WnL[nn*NH + c];
      SE[c] = fmaf(tv.x, w.x, fmaf(-tv.y, w.y, SE[c]));
    }
  }
  for (int t2 = 0; 2*t2+1 < BQ; t2++) {
    int nn = 2*t2 + 1;
    float2 tv = Tb[(size_t)nn*CHSL];
    #pragma unroll
    for (int c = 0; c < NH; c++) {
      float2 w = WnL[nn*NH + c];
      SO[c] = fmaf(tv.x, w.x, fmaf(-tv.y, w.y, SO[c]));
    }
  }
  #pragma unroll
  for (int c = 0; c < NH; c++) {
    float s0 = fmaxf(SE[c] + SO[c], 0.f);
    float s1 = fmaxf(SE[c] - SO[c], 0.f);
    SE[c] = s0 + s1;
    SO[c] = s0 - s1;
  }
  float2* Ub = U + (size_t)a*KT*CHSL + sl;
  for (int k = 0; k < KT; k += 2) {
    float ux = 0.f, uy = 0.f;
    #pragma unroll
    for (int c = 0; c < NH; c++) {
      float2 w = WgL[c*KT + k];
      ux = fmaf(SE[c], w.x, ux); uy = fmaf(SE[c], w.y, uy);
    }
    Ub[(size_t)k*CHSL] = make_float2(ux, uy);
  }
  for (int k = 1; k < KT; k += 2) {
    float ux = 0.f, uy = 0.f;
    #pragma unroll
    for (int c = 0; c < NH; c++) {
      float2 w = WgL[c*KT + k];
      ux = fmaf(SO[c], w.x, ux); uy = fmaf(SO[c], w.y, uy);
    }
    Ub[(size_t)k*CHSL] = make_float2(ux, uy);
  }
}

// ============================================================================
// k_dftC2: alpha fwd DFT; LDS-staged U column, 4 p-groups per block.
// ============================================================================
template<int MT, int KT, int NH, int CHSL>
__global__ __launch_bounds__(256) void k_dftC2(
    const float2* __restrict__ U, const float2* __restrict__ WC,
    float2* __restrict__ xt, int slOff, int SLfull)
{
  constexpr int NA = 2*NH;
  constexpr int TILES = CHSL/64;
  constexpr int PGp = (MT + 3)/4;
  __shared__ float2 Us[NA*64];
  __shared__ float2 WcL[NH*MT];
  int k = blockIdx.x / TILES, ts = blockIdx.x - k*TILES;
  int tid = threadIdx.x;
  int g = tid >> 6, lane = tid & 63;
  for (int i = tid; i < NA*64; i += 256) {
    int aa = i >> 6, ll = i & 63;
    Us[i] = U[((size_t)aa*KT + k)*CHSL + ts*64 + ll];
  }
  for (int i = tid; i < NH*MT; i += 256) { int aa = i/MT, p = i - aa*MT; WcL[i] = WC[(size_t)p*NA + aa]; }
  __syncthreads();
  int p0 = g*PGp;
  int cnt = MT - p0; if (cnt > PGp) cnt = PGp; if (cnt < 0) cnt = 0;
  float2 acc[PGp];
  #pragma unroll
  for (int i = 0; i < PGp; i++) acc[i] = make_float2(0.f, 0.f);
  for (int aa = 0; aa < NH; aa++) {
    float2 u  = Us[aa*64 + lane];
    float2 u2 = Us[(aa+NH)*64 + lane];
    float2 vp = make_float2(u.x + u2.x, u.y + u2.y);
    float2 vm = make_float2(u.x - u2.x, u.y - u2.y);
    const float2* wr = &WcL[aa*MT + p0];
    #pragma unroll
    for (int i = 0; i < PGp; i++) {
      float2 w = wr[i];
      float2 v = ((p0 + i) & 1) ? vm : vp;
      acc[i].x = fmaf(v.x, w.x, fmaf( v.y, w.y, acc[i].x));
      acc[i].y = fmaf(v.y, w.x, fmaf(-v.x, w.y, acc[i].y));
    }
  }
  int sl = ts*64 + lane;
  for (int i = 0; i < cnt; i++) {
    int p = p0 + i;
    xt[((size_t)(p*KT + k))*SLfull + slOff + sl] = acc[i];
  }
}

// ============================================================================
// k_coefg: beta contraction as pidx-row-block GEMM with LDS-staged xt row.
// ============================================================================
template<int NBI, int NJ, int PAD, int QTOT>
__global__ __launch_bounds__(256) void k_coefg(
    const float2* __restrict__ xt, const float* __restrict__ dAT,
    const int* __restrict__ qoff, const int* __restrict__ qlist,
    float2* __restrict__ xh, int SLfull)
{
  __shared__ float re[NBI*PAD], im[NBI*PAD];
  int pr = blockIdx.x;
  const float2* row = xt + (size_t)pr*SLfull;
  for (int idx = threadIdx.x; idx < NBI*NJ; idx += 256) {
    int bi = idx / NJ, j = idx - bi*NJ;
    float2 v = row[idx];
    re[bi*PAD + j] = v.x; im[bi*PAD + j] = v.y;
  }
  __syncthreads();
  int o0 = qoff[pr], nq = qoff[pr+1] - o0;
  int w = threadIdx.x >> 6, lane = threadIdx.x & 63;
  for (int i = w; i < nq; i += 4) {
    int e = qlist[o0 + i];
    int q = e >> 1;
    float sg = (e & 1) ? -1.f : 1.f;
    const float* dp = dAT + (size_t)q*NJ;
    for (int bi = lane; bi < NBI; bi += 64) {
      float ax = 0.f, ay = 0.f;
      const float* rr = &re[bi*PAD];
      const float* ii = &im[bi*PAD];
      #pragma unroll 4
      for (int j = 0; j < NJ; j++) {
        float d = dp[j];
        ax = fmaf(d, rr[j], ax);
        ay = fmaf(d, ii[j], ay);
      }
      xh[(size_t)bi*QTOT + q] = make_float2(ax, sg*ay);
    }
  }
}

// ---------------- old-layout beta contraction (stages 4,5) -----------------
__global__ __launch_bounds__(256) void k_coef(
    const float2* __restrict__ xt, const float* __restrict__ dA,
    float2* __restrict__ xh, int L, int nj, int KT, int MT, int Qtot, int nbi)
{
  int id = blockIdx.x*blockDim.x + threadIdx.x;
  if (id >= nbi*Qtot) return;
  int bi = id / Qtot, q = id - bi*Qtot;
  int l = lFromQ(q, L); int W = 2*l+1; int W21 = W*W;
  int rem = q - OQ(l); int mi = rem / W, ki = rem - mi*W;
  int m = mi - l, ks = ki - l;
  const float* dAp = dA + (size_t)nj*OQ(l) + rem;
  int MTKT = MT*KT;
  int pidx; float sgn;
  if (ks >= 0) { pidx = (m + (KT-1))*KT + ks;  sgn =  1.f; }
  else         { pidx = (-m + (KT-1))*KT - ks; sgn = -1.f; }
  const float2* xb = xt + (size_t)bi*nj*MTKT + pidx;
  float ax = 0.f, ay = 0.f;
  for (int j = 0; j < nj; j++) {
    float2 xv = xb[(size_t)j*MTKT];
    float d = dAp[(size_t)j*W21];
    ax += d*xv.x; ay += sgn*d*xv.y;
  }
  xh[id] = make_float2(ax, ay);
}

// ============================================================================
// Old fused synthesis (stages 3-5; tiny FLOP). yh read is transposed [e][bo].
// ============================================================================
template<int BQ, int N, int KT, int MT, int TPB, int BO>
__global__ __launch_bounds__(TPB) void k_synth3(
    const float2* __restrict__ yh, const float* __restrict__ dS,
    const float2* __restrict__ twN, float2* __restrict__ xt)
{
  constexpr int W2  = 2*BQ - 1;
  constexpr int NH  = N/2;
  constexpr int CP  = (BQ+3) & ~3;
  constexpr int KTP = (KT+1) & ~1;
  constexpr int R3  = (N%4 == 0) ? 4 : 2;
  constexpr int RP  = (NH%2 == 0) ? 2 : 1;
  constexpr int SZA0 = (W2*CP*8 > 2*N*NH*4) ? W2*CP*8 : 2*N*NH*4;
  constexpr int SZA  = (SZA0 + 15) & ~15;
  constexpr int SZB0 = (N*CP*8 > 2*NH*KTP*8) ? N*CP*8 : 2*NH*KTP*8;
  constexpr int SZB  = (SZB0 + 15) & ~15;
  __shared__ __align__(16) char smem[SZA + SZB + N*8];
  float2* P   = (float2*)smem;
  float*  SS  = (float*)smem;
  float*  SD  = SS + N*NH;
  float2* Tm  = (float2*)(smem + SZA);
  float2* USS = (float2*)(smem + SZA);
  float2* USD = USS + NH*KTP;
  float2* twl = (float2*)(smem + SZA + SZB);

  const int tid = threadIdx.x;
  int nwg = gridDim.x, bidx = blockIdx.x;
  int per = nwg >> 3;
  int swz = (bidx & 7)*per + (bidx >> 3);
  int bo = swz / N, j = swz - bo*N;

  for (int t = tid; t < N; t += TPB) twl[t] = twN[t];

  for (int idx = tid; idx < W2*CP; idx += TPB) {
    int pm = idx / CP, n = idx - pm*CP;
    float ax = 0.f, ay = 0.f;
    if (n < BQ) {
      int m = pm - (BQ-1);
      int am = m < 0 ? -m : m;
      int lmin = am > n ? am : n;
      int base = lmin*(4*lmin*lmin - 1)/3;
      for (int l = lmin; l < BQ; l++) {
        int Wl = 2*l+1;
        int e = base + (m+l)*Wl + (n+l);
        float2 y = yh[(size_t)e*BO + bo];
        float d = dS[(size_t)N*base + (size_t)j*Wl*Wl + (m+l)*Wl + (n+l)];
        ax += d*y.x; ay += d*y.y;
        base += Wl*Wl;
      }
    }
    P[idx] = make_float2(ax, ay);
  }
  __syncthreads();

  {
    constexpr int CG = CP/4;
    constexpr float SGN = ((BQ-1) & 1) ? -1.f : 1.f;
    const float4* P4 = (const float4*)P;
    for (int it = tid; it < NH*CG; it += TPB) {
      int a = it / CG, cg = it - a*CG;
      float2 s2 = twl[2*a];
      float2 r = make_float2(1.f, 0.f);
      float4 E0 = {0,0,0,0}, E1 = {0,0,0,0}, O0 = {0,0,0,0}, O1 = {0,0,0,0};
      for (int jj = 0; jj < BQ-1; jj++) {
        float4 e0 = P4[(2*jj)*(CP/2) + 2*cg];
        float4 e1 = P4[(2*jj)*(CP/2) + 2*cg + 1];
        float4 o0 = P4[(2*jj+1)*(CP/2) + 2*cg];
        float4 o1 = P4[(2*jj+1)*(CP/2) + 2*cg + 1];
        E0.x += e0.x*r.x - e0.y*r.y; E0.y += e0.x*r.y + e0.y*r.x;
        E0.z += e0.z*r.x - e0.w*r.y; E0.w += e0.z*r.y + e0.w*r.x;
        E1.x += e1.x*r.x - e1.y*r.y; E1.y += e1.x*r.y + e1.y*r.x;
        E1.z += e1.z*r.x - e1.w*r.y; E1.w += e1.z*r.y + e1.w*r.x;
        O0.x += o0.x*r.x - o0.y*r.y; O0.y += o0.x*r.y + o0.y*r.x;
        O0.z += o0.z*r.x - o0.w*r.y; O0.w += o0.z*r.y + o0.w*r.x;
        O1.x += o1.x*r.x - o1.y*r.y; O1.y += o1.x*r.y + o1.y*r.x;
        O1.z += o1.z*r.x - o1.w*r.y; O1.w += o1.z*r.y + o1.w*r.x;
        rotf(r, s2);
      }
      {
        float4 e0 = P4[(2*(BQ-1))*(CP/2) + 2*cg];
        float4 e1 = P4[(2*(BQ-1))*(CP/2) + 2*cg + 1];
        E0.x += e0.x*r.x - e0.y*r.y; E0.y += e0.x*r.y + e0.y*r.x;
        E0.z += e0.z*r.x - e0.w*r.y; E0.w += e0.z*r.y + e0.w*r.x;
        E1.x += e1.x*r.x - e1.y*r.y; E1.y += e1.x*r.y + e1.y*r.x;
        E1.z += e1.z*r.x - e1.w*r.y; E1.w += e1.z*r.y + e1.w*r.x;
      }
      float2 wa = twl[a];
      int pidx = (N - (a*(BQ-1)) % N) % N;
      float2 ph = twl[pidx];
      int c0 = 4*cg;
      auto doCol = [&](float ex, float ey, float ox, float oy, int col) {
        float gx = ox*wa.x - oy*wa.y, gy = ox*wa.y + oy*wa.x;
        float px = ex + gx, py = ey + gy;
        float qx = ex - gx, qy = ey - gy;
        Tm[a*CP + col]        = make_float2(px*ph.x - py*ph.y, px*ph.y + py*ph.x);
        Tm[(a+NH)*CP + col]   = make_float2(SGN*(qx*ph.x - qy*ph.y), SGN*(qx*ph.y + qy*ph.x));
      };
      doCol(E0.x, E0.y, O0.x, O0.y, c0+0);
      doCol(E0.z, E0.w, O0.z, O0.w, c0+1);
      doCol(E1.x, E1.y, O1.x, O1.y, c0+2);
      doCol(E1.z, E1.w, O1.z, O1.w, c0+3);
    }
  }
  __syncthreads();

  {
    constexpr int NO3 = BQ/2;
    constexpr int NRG = N/R3;
    for (int it = tid; it < NRG*NH; it += TPB) {
      int rg = it / NH, c = it - rg*NH;
      int a0 = rg*R3;
      float2 se = twl[2*c];
      float2 re = make_float2(1.f, 0.f);
      float2 ro = twl[c];
      float er[R3], orr[R3];
      #pragma unroll
      for (int rr = 0; rr < R3; rr++) { er[rr] = 0.f; orr[rr] = 0.f; }
      for (int jj = 0; jj < NO3; jj++) {
        #pragma unroll
        for (int rr = 0; rr < R3; rr++) {
          float4 tv = *(const float4*)&Tm[(a0+rr)*CP + 2*jj];
          er[rr]  += tv.x*re.x - tv.y*re.y;
          orr[rr] += tv.z*ro.x - tv.w*ro.y;
        }
        rotf(re, se); rotf(ro, se);
      }
      if constexpr ((BQ & 1) != 0) {
        #pragma unroll
        for (int rr = 0; rr < R3; rr++) {
          float2 tv = Tm[(a0+rr)*CP + (BQ-1)];
          er[rr] += tv.x*re.x - tv.y*re.y;
        }
      }
      #pragma unroll
      for (int rr = 0; rr < R3; rr++) {
        float t0x = Tm[(a0+rr)*CP].x;
        float s0 = fmaxf(2.f*(er[rr] + orr[rr]) - t0x, 0.f);
        float s1 = fmaxf(2.f*(er[rr] - orr[rr]) - t0x, 0.f);
        SS[(a0+rr)*NH + c] = s0 + s1;
        SD[(a0+rr)*NH + c] = s0 - s1;
      }
    }
  }
  __syncthreads();

  {
    for (int it = tid; it < (NH/RP)*KT; it += TPB) {
      int g = it / KT, k = it - g*KT;
      int a0 = g*RP;
      const float* Sp = (k & 1) ? SD : SS;
      float2 st = twl[k]; st.y = -st.y;
      float2 r = make_float2(1.f, 0.f);
      float ux[2*RP], uy[2*RP];
      #pragma unroll
      for (int q2 = 0; q2 < 2*RP; q2++) { ux[q2] = 0.f; uy[q2] = 0.f; }
      for (int c = 0; c < NH; c++) {
        #pragma unroll
        for (int pp = 0; pp < RP; pp++) {
          float sl = Sp[(a0+pp)*NH + c];
          float sh = Sp[(a0+pp+NH)*NH + c];
          ux[2*pp]   += sl*r.x; uy[2*pp]   += sl*r.y;
          ux[2*pp+1] += sh*r.x; uy[2*pp+1] += sh*r.y;
        }
        rotf(r, st);
      }
      #pragma unroll
      for (int pp = 0; pp < RP; pp++) {
        USS[(a0+pp)*KTP + k] = make_float2(ux[2*pp] + ux[2*pp+1], uy[2*pp] + uy[2*pp+1]);
        USD[(a0+pp)*KTP + k] = make_float2(ux[2*pp] - ux[2*pp+1], uy[2*pp] - uy[2*pp+1]);
      }
    }
  }
  __syncthreads();

  {
    float2* xtb = xt + ((size_t)bo*N + j)*(MT*KT);
    constexpr int KG = KTP/2;
    for (int it = tid; it < MT*KG; it += TPB) {
      int pm2 = it / KG, kg = it - pm2*KG;
      int m = pm2 - (KT-1);
      int mm = m < 0 ? m + N : m;
      const float2* Up = (m & 1) ? USD : USS;
      float2 st = twl[mm];
      float2 r = make_float2(1.f, 0.f);
      float a0x = 0.f, a0y = 0.f, a1x = 0.f, a1y = 0.f;
      for (int a = 0; a < NH; a++) {
        float4 u = *(const float4*)&Up[a*KTP + 2*kg];
        a0x += u.x*r.x + u.y*r.y;  a0y += u.y*r.x - u.x*r.y;
        a1x += u.z*r.x + u.w*r.y;  a1y += u.w*r.x - u.z*r.y;
        rotf(r, st);
      }
      int k0 = 2*kg;
      xtb[pm2*KT + k0] = make_float2(a0x, a0y);
      if (k0 + 1 < KT) xtb[pm2*KT + k0 + 1] = make_float2(a1x, a1y);
    }
  }
}

template<int BQ, int N, int KT, int MT, int INTEG, int NPAIR, int TPB, int BO>
__global__ __launch_bounds__(TPB) void k_synth2(
    const float2* __restrict__ yh, const float* __restrict__ dS,
    const float2* __restrict__ twN, const float2* __restrict__ Wn2,
    const float2* __restrict__ Wg, float2* __restrict__ xt,
    float* __restrict__ s5p, const float* __restrict__ wInt)
{
  constexpr int W2 = 2*BQ - 1;
  constexpr int SZA = (((W2*BQ*8 > N*N*4) ? W2*BQ*8 : N*N*4) + 15) & ~15;
  constexpr int SZB0 = (N*BQ*8 > N*KT*8) ? N*BQ*8 : N*KT*8;
  constexpr int SZB1 = (SZB0 > TPB*4) ? SZB0 : TPB*4;
  constexpr int SZB = (SZB1 + 15) & ~15;
  __shared__ __align__(16) char smem[SZA + SZB + N*8];
  float2* P   = (float2*)smem;
  float*  S   = (float*)smem;
  float2* Tm  = (float2*)(smem + SZA);
  float2* U   = (float2*)(smem + SZA);
  float*  red = (float*)(smem + SZA);
  float2* twl = (float2*)(smem + SZA + SZB);

  const int tid = threadIdx.x;
  int bidx = blockIdx.x, nwg = gridDim.x;
  int per = nwg >> 3;
  int swz = (bidx & 7)*per + (bidx >> 3);
  int bo = swz / N, j = swz - bo*N;

  for (int t = tid; t < N; t += TPB) twl[t] = twN[t];
  __syncthreads();

  for (int idx = tid; idx < W2*BQ; idx += TPB) {
    int pm = idx / BQ, n = idx - pm*BQ;
    int m = pm - (BQ-1);
    int am = m < 0 ? -m : m;
    int lmin = am > n ? am : n;
    int base = lmin*(4*lmin*lmin - 1)/3;
    float ax = 0.f, ay = 0.f;
    for (int l = lmin; l < BQ; l++) {
      int Wl = 2*l+1;
      int e = base + (m+l)*Wl + (n+l);
      float2 y = yh[(size_t)e*BO + bo];
      float d = dS[(size_t)N*base + (size_t)j*Wl*Wl + (m+l)*Wl + (n+l)];
      ax += d*y.x; ay += d*y.y;
      base += Wl*Wl;
    }
    P[idx] = make_float2(ax, ay);
  }
  __syncthreads();

  for (int idx = tid; idx < (N/2)*BQ; idx += TPB) {
    int ag = idx / BQ, n = idx - ag*BQ;
    int a0 = 2*ag, a1 = a0 + 1;
    int t0 = (N - (a0*(BQ-1)) % N) % N;
    int t1 = (N - (a1*(BQ-1)) % N) % N;
    float2 A0 = {0,0}, A1 = {0,0};
    for (int pm = 0; pm < W2; pm++) {
      float2 p = P[pm*BQ + n];
      float2 w0 = twl[t0], w1 = twl[t1];
      A0.x += p.x*w0.x - p.y*w0.y; A0.y += p.x*w0.y + p.y*w0.x;
      A1.x += p.x*w1.x - p.y*w1.y; A1.y += p.x*w1.y + p.y*w1.x;
      t0 += a0; if (t0 >= N) t0 -= N;
      t1 += a1; if (t1 >= N) t1 -= N;
    }
    Tm[a0*BQ + n] = A0;
    Tm[a1*BQ + n] = A1;
  }
  __syncthreads();

  {
    constexpr int CG = N/2;
    const float4* WnR = (const float4*)Wn2;
    for (int idx = tid; idx < N*CG; idx += TPB) {
      int a = idx / CG, cg = idx - a*CG;
      float s0 = 0.f, s1 = 0.f;
      const float2* TmA = Tm + a*BQ;
      for (int n = 0; n < BQ; n++) {
        float2 T = TmA[n];
        float4 w = WnR[n*CG + cg];
        s0 += T.x*w.x - T.y*w.y;
        s1 += T.x*w.z - T.y*w.w;
      }
      s0 = fmaxf(s0, 0.f); s1 = fmaxf(s1, 0.f);
      *(float2*)&S[a*N + 2*cg] = make_float2(s0, s1);
    }
  }
  __syncthreads();

  if constexpr (!INTEG) {
    for (int idx = tid; idx < (N/2)*KT; idx += TPB) {
      int ag = idx / KT, k = idx - ag*KT;
      int a0 = 2*ag, a1 = a0 + 1;
      float u0x=0.f,u0y=0.f,u1x=0.f,u1y=0.f;
      const float* S0 = S + a0*N;
      const float* S1 = S + a1*N;
      for (int c = 0; c < N; c++) {
        float2 w = Wg[c*KT + k];
        u0x += S0[c]*w.x; u0y += S0[c]*w.y;
        u1x += S1[c]*w.x; u1y += S1[c]*w.y;
      }
      U[a0*KT + k] = make_float2(u0x, u0y);
      U[a1*KT + k] = make_float2(u1x, u1y);
    }
    __syncthreads();

    float2* xtb = xt + ((size_t)bo*N + j)*(MT*KT);
    for (int idx = tid; idx < MT*KT; idx += TPB) {
      int pm2 = idx / KT, k = idx - pm2*KT;
      int m = pm2 - (KT-1);
      float ax = 0.f, ay = 0.f;
      int t = 0;
      for (int a = 0; a < N; a++) {
        float2 u = U[a*KT + k];
        float2 w = twl[t];
        ax += u.x*w.x + u.y*w.y;
        ay += u.y*w.x - u.x*w.y;
        t += m; if (t < 0) t += N; else if (t >= N) t -= N;
      }
      xtb[idx] = make_float2(ax, ay);
    }
  } else {
    float part = 0.f;
    for (int idx = tid; idx < N*N; idx += TPB) part += S[idx];
    red[tid] = part;
    __syncthreads();
    for (int off2 = TPB >> 1; off2 > 0; off2 >>= 1) {
      if (tid < off2) red[tid] += red[tid + off2];
      __syncthreads();
    }
    if (tid == 0) s5p[bo*N + j] = red[0]*wInt[j];
  }
}

// ---------------- head: integrate-reduce + 3x (batchnorm, linear) ----------
__global__ __launch_bounds__(256) void k_mlp(
    const float* __restrict__ s5p,
    const float* __restrict__ g1, const float* __restrict__ be1,
    const float* __restrict__ w1, const float* __restrict__ b1,
    const float* __restrict__ g2, const float* __restrict__ be2,
    const float* __restrict__ w2, const float* __restrict__ b2,
    const float* __restrict__ g3, const float* __restrict__ be3,
    const float* __restrict__ w3, const float* __restrict__ b3,
    float* __restrict__ out)
{
  __shared__ float A[2048], Bs[2048], C[1024], mu[64], iv[64];
  int tid = threadIdx.x;
  for (int idx = tid; idx < 2048; idx += 256) {
    float s = 0.f;
    #pragma unroll
    for (int j = 0; j < 6; j++) s += s5p[idx*6 + j];
    A[idx] = s;
  }
  __syncthreads();
  if (tid < 64) {
    float m = 0.f; for (int b = 0; b < 32; b++) m += A[b*64 + tid]; m *= (1.f/32);
    float v = 0.f; for (int b = 0; b < 32; b++) { float d = A[b*64+tid]-m; v += d*d; } v *= (1.f/32);
    mu[tid] = m; iv[tid] = rsqrtf(v + 1e-5f)*g1[tid];
  }
  __syncthreads();
  for (int idx = tid; idx < 2048; idx += 256) {
    int f = idx & 63;
    A[idx] = (A[idx]-mu[f])*iv[f] + be1[f];
  }
  __syncthreads();
  for (int idx = tid; idx < 2048; idx += 256) {
    int b = idx >> 6, fo = idx & 63;
    float s = b1[fo];
    for (int f = 0; f < 64; f++) s += A[b*64+f]*w1[f*64+fo];
    Bs[idx] = fmaxf(s, 0.f);
  }
  __syncthreads();
  if (tid < 64) {
    float m = 0.f; for (int b = 0; b < 32; b++) m += Bs[b*64+tid]; m *= (1.f/32);
    float v = 0.f; for (int b = 0; b < 32; b++) { float d = Bs[b*64+tid]-m; v += d*d; } v *= (1.f/32);
    mu[tid] = m; iv[tid] = rsqrtf(v + 1e-5f)*g2[tid];
  }
  __syncthreads();
  for (int idx = tid; idx < 2048; idx += 256) {
    int f = idx & 63;
    Bs[idx] = (Bs[idx]-mu[f])*iv[f] + be2[f];
  }
  __syncthreads();
  for (int idx = tid; idx < 1024; idx += 256) {
    int b = idx >> 5, fo = idx & 31;
    float s = b2[fo];
    for (int f = 0; f < 64; f++) s += Bs[b*64+f]*w2[f*32+fo];
    C[idx] = fmaxf(s, 0.f);
  }
  __syncthreads();
  if (tid < 32) {
    float m = 0.f; for (int b = 0; b < 32; b++) m += C[b*32+tid]; m *= (1.f/32);
    float v = 0.f; for (int b = 0; b < 32; b++) { float d = C[b*32+tid]-m; v += d*d; } v *= (1.f/32);
    mu[tid] = m; iv[tid] = rsqrtf(v + 1e-5f)*g3[tid];
  }
  __syncthreads();
  for (int idx = tid; idx < 1024; idx += 256) {
    int f = idx & 31;
    C[idx] = (C[idx]-mu[f])*iv[f] + be3[f];
  }
  __syncthreads();
  for (int idx = tid; idx < 320; idx += 256) {
    int b = idx/10, cc = idx - b*10;
    float s = b3[cc];
    for (int f = 0; f < 32; f++) s += C[b*32+f]*w3[f*10+cc];
    out[idx] = s;
  }
}

// ============================================================================
// launch
// ============================================================================
static inline int cdiv_h(int a, int b) { return (a + b - 1)/b; }

extern "C" void kernel_launch(void* const* d_in, const int* in_sizes, int n_in,
                              void* d_out, int out_size, void* d_ws, size_t ws_size,
                              hipStream_t stream) {
  (void)in_sizes; (void)n_in; (void)out_size;
  if (!g_devF || !g_devC || !g_devI || ws_size < WS_TOTAL) return;

  const float* x    = (const float*)d_in[0];
  const float* ks2  = (const float*)d_in[1];
  const float* k1   = (const float*)d_in[2];
  const float* k2   = (const float*)d_in[3];
  const float* k3   = (const float*)d_in[4];
  const float* k4   = (const float*)d_in[5];
  const float* g1   = (const float*)d_in[6],  *be1 = (const float*)d_in[7];
  const float* w1   = (const float*)d_in[8],  *b1  = (const float*)d_in[9];
  const float* g2   = (const float*)d_in[10], *be2 = (const float*)d_in[11];
  const float* w2   = (const float*)d_in[12], *b2  = (const float*)d_in[13];
  const float* g3   = (const float*)d_in[14], *be3 = (const float*)d_in[15];
  const float* w3   = (const float*)d_in[16], *b3  = (const float*)d_in[17];
  float* out = (float*)d_out;
  char* ws = (char*)d_ws;

  float2* XF1  = (float2*)(ws + WS_XF1);
  float2* xh1  = (float2*)(ws + WS_XH1);
  float2* kh1  = (float2*)(ws + WS_KH1);
  float2* xt2  = (float2*)(ws + WS_XT2);
  float2* xh2  = (float2*)(ws + WS_XH2);
  float2* kh2  = (float2*)(ws + WS_KH2);
  float2* yh2t = (float2*)(ws + WS_YH2T);
  float2* xt3  = (float2*)(ws + WS_XT3);
  float2* xh3  = (float2*)(ws + WS_XH3);
  float2* kh3  = (float2*)(ws + WS_KH3);
  float2* yh3t = (float2*)(ws + WS_YH3T);
  float2* xt4  = (float2*)(ws + WS_XT4);
  float2* xh4  = (float2*)(ws + WS_XH4);
  float2* kh4  = (float2*)(ws + WS_KH4);
  float2* yh4t = (float2*)(ws + WS_YH4T);
  float2* xt5  = (float2*)(ws + WS_XT5);
  float2* xh5  = (float2*)(ws + WS_XH5);
  float2* kh5  = (float2*)(ws + WS_KH5);
  float2* yh5t = (float2*)(ws + WS_YH5T);
  float*  s5p  = (float*) (ws + WS_S5P);
  float2* RTm  = (float2*)(ws + WS_RTM);
  float2* RU   = (float2*)(ws + WS_RU);

  const float* dA1p  = g_devF + CO.A1;
  const float* dAT2p = g_devF + CO.dAT2;
  const float* dAT3p = g_devF + CO.dAT3;
  const float* dA4p  = g_devF + CO.A4;
  const float* dA5p  = g_devF + CO.A5;
  const float* dT1p  = g_devF + CO.dT1;
  const float* dT2p  = g_devF + CO.dT2;
  const float* dS3p  = g_devF + CO.S3;
  const float* dS4p  = g_devF + CO.S4;
  const float* dS5p  = g_devF + CO.S5;
  const float* wIntp = g_devF + CO.WInt;
  const float2* Fs2p  = g_devC + CO.Fs2;
  const float2* Fso3p = g_devC + CO.Fso3;
  const float2* tw60p = g_devC + CO.Tw60;
  const float2* tw18p = g_devC + CO.Tw18;
  const float2* tw10p = g_devC + CO.Tw10;
  const float2* tw6p  = g_devC + CO.Tw6;
  const float2* Wn1p  = g_devC + CO.Wn1;
  const float2* Wn2p  = g_devC + CO.Wn2o;
  const float2* Wn4p  = g_devC + CO.Wn4;
  const float2* Wn5p  = g_devC + CO.Wn5;
  const float2* Wg1p  = g_devC + CO.Wg1;
  const float2* Wg2p  = g_devC + CO.Wg2;
  const float2* Wg4p  = g_devC + CO.Wg4;
  const float2* WC1p  = g_devC + CO.WC1;
  const float2* WC2p  = g_devC + CO.WC2;
  const float2* WEO1p = g_devC + CO.WEO1;
  const float2* WEO2p = g_devC + CO.WEO2;
  const int* toff1p  = g_devI + IO_TOFF1;
  const int* toff2p  = g_devI + IO_TOFF2;
  const int* qoff2p  = g_devI + IO_QOFF2;
  const int* qlist2p = g_devI + IO_QLST2;
  const int* qoff3p  = g_devI + IO_QOFF3;
  const int* qlist3p = g_devI + IO_QLST3;

  constexpr int Q17 = OQh(17), Q9 = OQh(9), Q5 = OQh(5), Q3 = OQh(3);

  // 1: all kernel FTs
  k_kh_all<<<952, 256, 0, stream>>>(ks2, k1, k2, k3, k4, Fs2p, Fso3p,
                                    kh1, kh2, kh3, kh4, kh5);

  // 2-3: stage-1 analysis
  k_s1_fftA<<<32*60, 64, 0, stream>>>(x, tw60p, XF1);
  k_s1_coef<<<cdiv_h(32*900,256), 256, 0, stream>>>(XF1, dA1p, xh1);

  // 4-9: stage-1 synthesis chain (2 chunks of SL=1920; yh on the fly)
  for (int c = 0; c < 2; c++) {
    int base = c*1920;
    k_scatB<30,60,64,1920,1><<<30*30, 256, 0, stream>>>(xh1, kh1, dT1p, toff1p, WEO1p, RTm, base);
    k_dftB2<30,17,1920><<<15*30, 256, 0, stream>>>(RTm, Wn1p, Wg1p, RU);
    k_dftC2<33,17,30,1920><<<17*30, 256, 0, stream>>>(RU, WC1p, xt2, base, 3840);
  }
  // 10-11: stage-2 analysis
  k_coefg<64,60,61,Q17><<<561, 256, 0, stream>>>(xt2, dAT2p, qoff2p, qlist2p, xh2, 3840);
  k_yh_t<<<cdiv_h(Q17*160,256), 256, 0, stream>>>(xh2, kh2, yh2t, 17, 2, 5, Q17);

  // 12-14: stage-2 synthesis chain (single chunk SL=5440)
  k_scatB<17,34,160,5440,0><<<17*85, 256, 0, stream>>>(yh2t, nullptr, dT2p, toff2p, WEO2p, RTm, 0);
  k_dftB2<17,9,5440><<<9*85, 256, 0, stream>>>(RTm, Wn2p, Wg2p, RU);
  k_dftC2<17,9,17,5440><<<9*85, 256, 0, stream>>>(RU, WC2p, xt3, 0, 5440);

  // 15-16: stage-3 analysis
  k_coefg<160,34,35,Q9><<<153, 256, 0, stream>>>(xt3, dAT3p, qoff3p, qlist3p, xh3, 5440);
  k_yh_t<<<cdiv_h(Q9*384,256), 256, 0, stream>>>(xh3, kh3, yh3t, 9, 5, 12, Q9);

  // 17-19: stage 3 (old fused path)
  k_synth3<9,18,5,9,64,384><<<384*18, 64, 0, stream>>>(yh3t, dS3p, tw18p, xt4);
  k_coef<<<cdiv_h(384*Q5,256), 256, 0, stream>>>(xt4, dA4p, xh4, 5, 18, 5, 9, Q5, 384);
  k_yh_t<<<cdiv_h(Q5*896,256), 256, 0, stream>>>(xh4, kh4, yh4t, 5, 12, 28, Q5);

  // 20-22: stage 4
  k_synth2<5,10,3,5,0,1,64,896><<<896*10, 64, 0, stream>>>(yh4t, dS4p, tw10p, Wn4p, Wg4p, xt5, nullptr, nullptr);
  k_coef<<<cdiv_h(896*Q3,256), 256, 0, stream>>>(xt5, dA5p, xh5, 3, 10, 3, 5, Q3, 896);
  k_yh_t<<<cdiv_h(Q3*2048,256), 256, 0, stream>>>(xh5, kh5, yh5t, 3, 28, 64, Q3);

  // 23: stage 5 synthesis fused with so3_integrate
  k_synth2<3,6,3,5,1,1,64,2048><<<2048*6, 64, 0, stream>>>(yh5t, dS5p, tw6p, Wn5p, nullptr, nullptr, s5p, wIntp);

  // 24: head
  k_mlp<<<1, 256, 0, stream>>>(s5p, g1, be1, w1, b1, g2, be2, w2, b2, g3, be3, w3, b3, out);
}